// Round 6
// baseline (1446.927 us; speedup 1.0000x reference)
//
#include <hip/hip_runtime.h>

#define HW 65536

typedef short bf16x8 __attribute__((ext_vector_type(8)));
typedef float f32x4 __attribute__((ext_vector_type(4)));
typedef unsigned short u16x8 __attribute__((ext_vector_type(8)));

__device__ inline unsigned short f2bf(float v) {
    unsigned u = __float_as_uint(v);
    unsigned r = (u + 0x7FFF + ((u >> 16) & 1)) >> 16;
    return (unsigned short)r;
}
__device__ inline float ubf(unsigned short h) {
    return __uint_as_float(((unsigned)h) << 16);
}
__device__ inline uint4 pack8(const unsigned short* p) {
    uint4 u;
    u.x = (unsigned)p[0] | ((unsigned)p[1] << 16);
    u.y = (unsigned)p[2] | ((unsigned)p[3] << 16);
    u.z = (unsigned)p[4] | ((unsigned)p[5] << 16);
    u.w = (unsigned)p[6] | ((unsigned)p[7] << 16);
    return u;
}

// ---------------------------------------------------------------------------
// Merge 7/5/3 kernels into one 7x7 and write bf16 hi/lo in [tap][oc][ci] layout
// ---------------------------------------------------------------------------
__global__ void wmerge_kernel(const float* __restrict__ k7, const float* __restrict__ k5,
                              const float* __restrict__ k3, int Cin, int Cpw,
                              unsigned short* __restrict__ wTh, unsigned short* __restrict__ wTl)
{
    int idx = blockIdx.x * 256 + threadIdx.x;
    int total = 49 * 32 * Cpw;
    if (idx >= total) return;
    int ci = idx % Cpw;
    int oc = (idx / Cpw) & 31;
    int tap = idx / (Cpw * 32);
    int ky = tap / 7, kx = tap % 7;
    float v = 0.f;
    if (ci < Cin) {
        v = k7[(oc * Cin + ci) * 49 + tap];
        if (ky >= 1 && ky <= 5 && kx >= 1 && kx <= 5)
            v += k5[(oc * Cin + ci) * 25 + (ky - 1) * 5 + (kx - 1)];
        if (ky >= 2 && ky <= 4 && kx >= 2 && kx <= 4)
            v += k3[(oc * Cin + ci) * 9 + (ky - 2) * 3 + (kx - 2)];
    }
    unsigned short h = f2bf(v);
    wTh[idx] = h;
    wTl[idx] = f2bf(v - ubf(h));
}

// ---------------------------------------------------------------------------
// x [103][HW] fp32 -> xT [n][128] bf16 hi/lo (slots 0..102 = x, 103..127 = 0)
// and pfch [c][HW] bf16 hi (rows 0..102)
// ---------------------------------------------------------------------------
__global__ __launch_bounds__(256) void transpose_kernel(
    const float* __restrict__ x,
    unsigned short* __restrict__ xTh, unsigned short* __restrict__ xTl,
    unsigned short* __restrict__ pfch)
{
    __shared__ float buf[64 * 105];
    int t = threadIdx.x;
    int px0 = blockIdx.x * 64;
    for (int i = t; i < 103 * 64; i += 256) {
        int c = i >> 6, lane = i & 63;
        float v = x[(size_t)c * HW + px0 + lane];
        buf[lane * 105 + c] = v;
        pfch[(size_t)c * HW + px0 + lane] = f2bf(v);
    }
    __syncthreads();
    int px = t >> 2, seg = t & 3;
    unsigned short h[32], l[32];
#pragma unroll
    for (int j = 0; j < 32; ++j) {
        int c = seg * 32 + j;
        float v = (c < 103) ? buf[px * 105 + c] : 0.f;
        h[j] = f2bf(v);
        l[j] = f2bf(v - ubf(h[j]));
    }
    size_t base = (size_t)(px0 + px) * 128 + seg * 32;
#pragma unroll
    for (int k = 0; k < 4; ++k) {
        *(uint4*)(xTh + base + k * 8) = pack8(h + k * 8);
        *(uint4*)(xTl + base + k * 8) = pack8(l + k * 8);
    }
}

// ---------------------------------------------------------------------------
// Implicit-GEMM 7x7 conv via MFMA 16x16x32 bf16, 3-phase hi/lo with
// THREE independent accumulators (no intra-tap dependency chains).
// act: channel-last [n][Cs] hi/lo. weights: [tap][32oc][Cpw] hi/lo.
// Block: 256 thr = 4 waves; each wave: 1 y-row x 16 px x 32 oc. Grid 1024.
// LDS layout [row][q][22px][8ci] -> conflict-free 16B-stride reads/writes.
// ---------------------------------------------------------------------------
__global__ __launch_bounds__(256) void convm_kernel(
    const unsigned short* __restrict__ actH, const unsigned short* __restrict__ actL,
    int Cs,
    const unsigned short* __restrict__ wTh, const unsigned short* __restrict__ wTl,
    int Cpw, int nch,
    float* __restrict__ yraw)
{
    __shared__ __align__(16) unsigned short sH[10 * 704];
    __shared__ __align__(16) unsigned short sL[10 * 704];
    int t = threadIdx.x;
    int w = t >> 6, l = t & 63;
    int lc = l & 15, lg = l >> 4;
    int bx = blockIdx.x & 15, byy = blockIdx.x >> 4;
    int x0 = bx * 16, y0 = byy * 4;

    f32x4 a_hh[2], a_lh[2], a_hl[2];
#pragma unroll
    for (int ot = 0; ot < 2; ++ot)
#pragma unroll
        for (int r = 0; r < 4; ++r) {
            a_hh[ot][r] = 0.f; a_lh[ot][r] = 0.f; a_hl[ot][r] = 0.f;
        }

    for (int ch = 0; ch < nch; ++ch) {
        int ci0 = ch * 32;
        __syncthreads();
        for (int i = t; i < 1760; i += 256) {
            int pl = (i >= 880) ? 1 : 0;
            int j = pl ? i - 880 : i;
            int row = j / 88;
            int rem = j - row * 88;
            int px = rem >> 2, q = rem & 3;
            int gy = y0 - 3 + row, gx = x0 - 3 + px;
            uint4 v = {0u, 0u, 0u, 0u};
            if (gy >= 0 && gy < 256 && gx >= 0 && gx < 256) {
                const unsigned short* src = pl ? actL : actH;
                v = *(const uint4*)(src + (size_t)(gy * 256 + gx) * Cs + ci0 + q * 8);
            }
            unsigned short* dst = pl ? sL : sH;
            *(uint4*)(dst + row * 704 + q * 176 + px * 8) = v;
        }
        __syncthreads();

        int wfoff = lc * Cpw + ci0 + 8 * lg;
        bf16x8 ah0 = *(const bf16x8*)(wTh + wfoff);
        bf16x8 ah1 = *(const bf16x8*)(wTh + wfoff + 16 * Cpw);
        bf16x8 al0 = *(const bf16x8*)(wTl + wfoff);
        bf16x8 al1 = *(const bf16x8*)(wTl + wfoff + 16 * Cpw);

        for (int tap = 0; tap < 49; ++tap) {
            bf16x8 nh0, nh1, nl0, nl1;
            if (tap < 48) {
                int noff = (tap + 1) * 32 * Cpw + wfoff;
                nh0 = *(const bf16x8*)(wTh + noff);
                nh1 = *(const bf16x8*)(wTh + noff + 16 * Cpw);
                nl0 = *(const bf16x8*)(wTl + noff);
                nl1 = *(const bf16x8*)(wTl + noff + 16 * Cpw);
            }
            int ky = tap / 7;
            int kx = tap - ky * 7;
            int off = (w + ky) * 704 + lg * 176 + (lc + kx) * 8;
            bf16x8 bh = *(const bf16x8*)(sH + off);
            bf16x8 bl = *(const bf16x8*)(sL + off);
            a_hh[0] = __builtin_amdgcn_mfma_f32_16x16x32_bf16(ah0, bh, a_hh[0], 0, 0, 0);
            a_hh[1] = __builtin_amdgcn_mfma_f32_16x16x32_bf16(ah1, bh, a_hh[1], 0, 0, 0);
            a_lh[0] = __builtin_amdgcn_mfma_f32_16x16x32_bf16(al0, bh, a_lh[0], 0, 0, 0);
            a_lh[1] = __builtin_amdgcn_mfma_f32_16x16x32_bf16(al1, bh, a_lh[1], 0, 0, 0);
            a_hl[0] = __builtin_amdgcn_mfma_f32_16x16x32_bf16(ah0, bl, a_hl[0], 0, 0, 0);
            a_hl[1] = __builtin_amdgcn_mfma_f32_16x16x32_bf16(ah1, bl, a_hl[1], 0, 0, 0);
            if (tap < 48) { ah0 = nh0; ah1 = nh1; al0 = nl0; al1 = nl1; }
        }
    }

    int n = (y0 + w) * 256 + x0 + lc;
#pragma unroll
    for (int ot = 0; ot < 2; ++ot)
#pragma unroll
        for (int r = 0; r < 4; ++r) {
            int oc = ot * 16 + lg * 4 + r;
            yraw[(size_t)oc * HW + n] = a_hh[ot][r] + a_lh[ot][r] + a_hl[ot][r];
        }
}

// ---------------------------------------------------------------------------
// per-channel sum/sumsq of yraw
// ---------------------------------------------------------------------------
__global__ __launch_bounds__(256) void stats_kernel(
    const float* __restrict__ yraw, float* __restrict__ ssum, float* __restrict__ ssq)
{
    int c = blockIdx.x >> 5, seg = blockIdx.x & 31;
    int base = c * HW + seg * 2048 + threadIdx.x * 8;
    float4 a0 = *(const float4*)&yraw[base];
    float4 a1 = *(const float4*)&yraw[base + 4];
    float s = a0.x + a0.y + a0.z + a0.w + a1.x + a1.y + a1.z + a1.w;
    float q = a0.x * a0.x + a0.y * a0.y + a0.z * a0.z + a0.w * a0.w
            + a1.x * a1.x + a1.y * a1.y + a1.z * a1.z + a1.w * a1.w;
#pragma unroll
    for (int d = 32; d >= 1; d >>= 1) {
        s += __shfl_down(s, d);
        q += __shfl_down(q, d);
    }
    __shared__ float ls[4], lq[4];
    int w = threadIdx.x >> 6;
    if ((threadIdx.x & 63) == 0) { ls[w] = s; lq[w] = q; }
    __syncthreads();
    if (threadIdx.x == 0) {
        atomicAdd(&ssum[c], ls[0] + ls[1] + ls[2] + ls[3]);
        atomicAdd(&ssq[c], lq[0] + lq[1] + lq[2] + lq[3]);
    }
}

__global__ void bnp_kernel(const float* __restrict__ ssum, const float* __restrict__ ssq,
                           const float* __restrict__ g, const float* __restrict__ beta,
                           float* __restrict__ scl, float* __restrict__ shf)
{
    int c = threadIdx.x;
    float mu  = ssum[c] * (1.f / 65536.f);
    float var = ssq[c] * (1.f / 65536.f) - mu * mu;
    float s = g[c] * rsqrtf(var + 1e-5f);
    scl[c] = s;
    shf[c] = beta[c] - mu * s;
}

// ---------------------------------------------------------------------------
// BN + ReLU + write channel-last bf16 hi/lo
// ---------------------------------------------------------------------------
__global__ __launch_bounds__(256) void bna_kernel(
    const float* __restrict__ yraw, const float* __restrict__ scl, const float* __restrict__ shf,
    unsigned short* __restrict__ aH, unsigned short* __restrict__ aL, int Cs, int slot0)
{
    int t = threadIdx.x;
    int lane = t & 63, cg = t >> 6;
    int px = blockIdx.x * 64 + lane;
    unsigned short h[8], l[8];
#pragma unroll
    for (int j = 0; j < 8; ++j) {
        int c = cg * 8 + j;
        float v = fmaxf(yraw[(size_t)c * HW + px] * scl[c] + shf[c], 0.f);
        h[j] = f2bf(v);
        l[j] = f2bf(v - ubf(h[j]));
    }
    *(uint4*)(aH + (size_t)px * Cs + slot0 + cg * 8) = pack8(h);
    *(uint4*)(aL + (size_t)px * Cs + slot0 + cg * 8) = pack8(l);
}

// ---------------------------------------------------------------------------
// 1x1 conv (96->15) + ReLU from channel-last activations; writes pf slots
// 103..127 of xT (hi/lo) and pfch rows 103..127.
// ---------------------------------------------------------------------------
__global__ __launch_bounds__(256) void feat_kernel(
    const unsigned short* __restrict__ a12H, const unsigned short* __restrict__ a12L,
    const unsigned short* __restrict__ a3H, const unsigned short* __restrict__ a3L,
    const float* __restrict__ w, const float* __restrict__ b,
    unsigned short* __restrict__ xTh, unsigned short* __restrict__ xTl,
    unsigned short* __restrict__ pfch)
{
    int n = blockIdx.x * 256 + threadIdx.x;
    float facc[15];
#pragma unroll
    for (int oc = 0; oc < 15; ++oc) facc[oc] = b[oc];

#pragma unroll
    for (int k = 0; k < 12; ++k) {
        uint4 uh, ul;
        if (k < 8) {
            uh = *(const uint4*)(a12H + (size_t)n * 64 + k * 8);
            ul = *(const uint4*)(a12L + (size_t)n * 64 + k * 8);
        } else {
            uh = *(const uint4*)(a3H + (size_t)n * 32 + (k - 8) * 8);
            ul = *(const uint4*)(a3L + (size_t)n * 32 + (k - 8) * 8);
        }
        unsigned hw_[4] = {uh.x, uh.y, uh.z, uh.w};
        unsigned lw_[4] = {ul.x, ul.y, ul.z, ul.w};
#pragma unroll
        for (int j = 0; j < 8; ++j) {
            unsigned short hh = (unsigned short)(hw_[j >> 1] >> ((j & 1) * 16));
            unsigned short ll = (unsigned short)(lw_[j >> 1] >> ((j & 1) * 16));
            float av = ubf(hh) + ubf(ll);
#pragma unroll
            for (int oc = 0; oc < 15; ++oc)
                facc[oc] = fmaf(av, w[oc * 96 + k * 8 + j], facc[oc]);
        }
    }
    unsigned short fh[16], fl[16];
#pragma unroll
    for (int oc = 0; oc < 15; ++oc) {
        float v = fmaxf(facc[oc], 0.f);
        fh[oc] = f2bf(v);
        fl[oc] = f2bf(v - ubf(fh[oc]));
    }
    fh[15] = 0; fl[15] = 0;

    size_t base = (size_t)n * 128;
    uint4 h0 = *(const uint4*)(xTh + base + 96);
    uint4 l0 = *(const uint4*)(xTl + base + 96);
    h0.w = (h0.w & 0xFFFFu) | ((unsigned)fh[0] << 16);
    l0.w = (l0.w & 0xFFFFu) | ((unsigned)fl[0] << 16);
    *(uint4*)(xTh + base + 96) = h0;
    *(uint4*)(xTl + base + 96) = l0;
    *(uint4*)(xTh + base + 104) = pack8(fh + 1);
    *(uint4*)(xTl + base + 104) = pack8(fl + 1);
    unsigned short t2h[8], t2l[8];
#pragma unroll
    for (int j = 0; j < 8; ++j) {
        t2h[j] = (j < 6) ? fh[9 + j] : (unsigned short)0;
        t2l[j] = (j < 6) ? fl[9 + j] : (unsigned short)0;
    }
    *(uint4*)(xTh + base + 112) = pack8(t2h);
    *(uint4*)(xTl + base + 112) = pack8(t2l);
    unsigned short t3h[8] = {0, 0, 0, 0, 0, 0, 0, 0x3F80};
    unsigned short t3l[8] = {0, 0, 0, 0, 0, 0, 0, 0};
    *(uint4*)(xTh + base + 120) = pack8(t3h);
    *(uint4*)(xTl + base + 120) = pack8(t3l);

#pragma unroll
    for (int k2 = 0; k2 < 15; ++k2)
        pfch[(size_t)(103 + k2) * HW + n] = fh[k2];
    pfch[(size_t)118 * HW + n] = 0x3F80;
#pragma unroll
    for (int c = 119; c < 128; ++c)
        pfch[(size_t)c * HW + n] = 0;
}

// ---------------------------------------------------------------------------
// c0: per-superpixel channel sums -> cn_fin[s][128]
// ---------------------------------------------------------------------------
__global__ __launch_bounds__(256) void c0_kernel(
    const unsigned short* __restrict__ pfTh, const unsigned short* __restrict__ pfTl,
    float* __restrict__ cn_fin)
{
    int s = blockIdx.x;
    int sy = s >> 4, sx = s & 15;
    int t = threadIdx.x;
    int xx = t >> 4;
    int cs = (t & 15) * 8;

    float acc[8];
#pragma unroll
    for (int j = 0; j < 8; ++j) acc[j] = 0.f;

    for (int yy = 0; yy < 16; ++yy) {
        int n = (sy * 16 + yy) * 256 + sx * 16 + xx;
        u16x8 h = *(const u16x8*)(pfTh + (size_t)n * 128 + cs);
        u16x8 l = *(const u16x8*)(pfTl + (size_t)n * 128 + cs);
#pragma unroll
        for (int j = 0; j < 8; ++j)
            acc[j] += ubf(h[j]) + ubf(l[j]);
    }
#pragma unroll
    for (int j = 0; j < 8; ++j) {
        acc[j] += __shfl_xor(acc[j], 16);
        acc[j] += __shfl_xor(acc[j], 32);
    }
    __shared__ float red[4][128];
    int w = t >> 6;
    if ((t & 63) < 16) {
#pragma unroll
        for (int j = 0; j < 8; ++j)
            red[w][(t & 15) * 8 + j] = acc[j];
    }
    __syncthreads();
    if (t < 128)
        cn_fin[s * 128 + t] = red[0][t] + red[1][t] + red[2][t] + red[3][t];
}

// ---------------------------------------------------------------------------
// prep: centroids -> chiT/cloT [s][128]; slot 127 = -0.5*|c|^2; grid 256
// ---------------------------------------------------------------------------
__global__ __launch_bounds__(128) void prep_kernel(
    const float* __restrict__ cn_fin,
    unsigned short* __restrict__ chiT, unsigned short* __restrict__ cloT,
    float scale0, int use_qsum)
{
    int s = blockIdx.x, c = threadIdx.x;
    float inv = use_qsum ? 1.f / (cn_fin[s * 128 + 118] + 1e-8f) : scale0;
    float v = (c < 118) ? cn_fin[s * 128 + c] * inv : 0.f;
    float a = v * v;
#pragma unroll
    for (int d = 1; d < 64; d <<= 1) a += __shfl_xor(a, d);
    __shared__ float red[2];
    if ((c & 63) == 0) red[c >> 6] = a;
    __syncthreads();
    float tot = red[0] + red[1];
    unsigned short h, lo;
    if (c == 127) {
        float m2 = -0.5f * tot;
        h = f2bf(m2);
        lo = f2bf(m2 - ubf(h));
    } else {
        h = f2bf(v);
        lo = f2bf(v - ubf(h));
    }
    chiT[s * 128 + c] = h;
    cloT[s * 128 + c] = lo;
}

// ---------------------------------------------------------------------------
// dist: Q[s,n] = softmax_s(2*(cent.pf - 0.5|c|^2)) via MFMA, 3-phase hi/lo
// ---------------------------------------------------------------------------
__global__ __launch_bounds__(256) void dist_kernel(
    const unsigned short* __restrict__ chiT, const unsigned short* __restrict__ cloT,
    const unsigned short* __restrict__ pfTh, const unsigned short* __restrict__ pfTl,
    unsigned short* __restrict__ qh, float* __restrict__ qf, int final_mode)
{
    int t = threadIdx.x;
    int w = t >> 6, l = t & 63;
    int n0 = blockIdx.x * 64 + w * 16;
    int lc = l & 15;
    int lg = l >> 4;

    f32x4 acc[16];
#pragma unroll
    for (int i = 0; i < 16; ++i)
#pragma unroll
        for (int j = 0; j < 4; ++j) acc[i][j] = 0.f;

#pragma unroll
    for (int phse = 0; phse < 3; ++phse) {
        const unsigned short* Ap = (phse == 1) ? cloT : chiT;
        const unsigned short* Bp = (phse == 2) ? pfTl : pfTh;
#pragma unroll
        for (int ks = 0; ks < 4; ++ks) {
            int kb = ks * 32 + 8 * lg;
            bf16x8 bfr = *(const bf16x8*)(Bp + (size_t)(n0 + lc) * 128 + kb);
#pragma unroll
            for (int st = 0; st < 16; ++st) {
                bf16x8 afr = *(const bf16x8*)(Ap + (size_t)(st * 16 + lc) * 128 + kb);
                acc[st] = __builtin_amdgcn_mfma_f32_16x16x32_bf16(afr, bfr, acc[st], 0, 0, 0);
            }
        }
    }

    float m = -1e30f;
#pragma unroll
    for (int st = 0; st < 16; ++st)
#pragma unroll
        for (int r = 0; r < 4; ++r) m = fmaxf(m, acc[st][r]);
    m = fmaxf(m, __shfl_xor(m, 16));
    m = fmaxf(m, __shfl_xor(m, 32));

    float ssum = 0.f;
#pragma unroll
    for (int st = 0; st < 16; ++st)
#pragma unroll
        for (int r = 0; r < 4; ++r) {
            float e = __expf(2.f * (acc[st][r] - m));
            acc[st][r] = e;
            ssum += e;
        }
    ssum += __shfl_xor(ssum, 16);
    ssum += __shfl_xor(ssum, 32);
    float inv = 1.f / ssum;

    int n = n0 + lc;
    if (!final_mode) {
#pragma unroll
        for (int st = 0; st < 16; ++st)
#pragma unroll
            for (int r = 0; r < 4; ++r) {
                int s = st * 16 + lg * 4 + r;
                qh[(size_t)s * HW + n] = f2bf(acc[st][r] * inv);
            }
    } else {
#pragma unroll
        for (int st = 0; st < 16; ++st)
#pragma unroll
            for (int r = 0; r < 4; ++r) {
                int s = st * 16 + lg * 4 + r;
                qf[(size_t)s * HW + n] = acc[st][r] * inv;
            }
    }
}

// ---------------------------------------------------------------------------
// cn: D[s,c] = sum_n Q[s,n]*pf[c,n]; grid 256 (K-slice = 256 px)
// ---------------------------------------------------------------------------
__global__ __launch_bounds__(512) void cn_kernel(
    const unsigned short* __restrict__ qh, const unsigned short* __restrict__ pfch,
    float* __restrict__ cn_part)
{
    int t = threadIdx.x;
    int w = t >> 6, l = t & 63;
    int lc = l & 15, lg = l >> 4;
    int n0 = blockIdx.x * 256;

    f32x4 acc[16];
#pragma unroll
    for (int i = 0; i < 16; ++i)
#pragma unroll
        for (int j = 0; j < 4; ++j) acc[i][j] = 0.f;

    for (int ks = 0; ks < 8; ++ks) {
        int nb = n0 + ks * 32 + 8 * lg;
        bf16x8 bfr = *(const bf16x8*)(pfch + (size_t)(w * 16 + lc) * HW + nb);
#pragma unroll
        for (int st = 0; st < 16; ++st) {
            bf16x8 afr = *(const bf16x8*)(qh + (size_t)(st * 16 + lc) * HW + nb);
            acc[st] = __builtin_amdgcn_mfma_f32_16x16x32_bf16(afr, bfr, acc[st], 0, 0, 0);
        }
    }

    float* out = cn_part + (size_t)blockIdx.x * 32768;
#pragma unroll
    for (int st = 0; st < 16; ++st)
#pragma unroll
        for (int r = 0; r < 4; ++r) {
            int s = st * 16 + lg * 4 + r;
            out[s * 128 + w * 16 + lc] = acc[st][r];
        }
}

__global__ __launch_bounds__(128) void reduce_cn(const float* __restrict__ cn_part,
                                                 float* __restrict__ cn_fin)
{
    int o = blockIdx.x * 128 + threadIdx.x;   // 32768 outputs
    float a = 0.f;
    for (int k = 0; k < 256; ++k) a += cn_part[(size_t)k * 32768 + o];
    cn_fin[o] = a;
}

// ---------------------------------------------------------------------------
extern "C" void kernel_launch(void* const* d_in, const int* in_sizes, int n_in,
                              void* d_out, int out_size, void* d_ws, size_t ws_size,
                              hipStream_t stream)
{
    const float* x     = (const float*)d_in[0];
    const float* s1k7  = (const float*)d_in[1];
    const float* s1k5  = (const float*)d_in[2];
    const float* s1k3  = (const float*)d_in[3];
    const float* s1g   = (const float*)d_in[5];
    const float* s1be  = (const float*)d_in[6];
    const float* s2k7  = (const float*)d_in[7];
    const float* s2k5  = (const float*)d_in[8];
    const float* s2k3  = (const float*)d_in[9];
    const float* s2g   = (const float*)d_in[11];
    const float* s2be  = (const float*)d_in[12];
    const float* s3k7  = (const float*)d_in[13];
    const float* s3k5  = (const float*)d_in[14];
    const float* s3k3  = (const float*)d_in[15];
    const float* s3g   = (const float*)d_in[17];
    const float* s3be  = (const float*)d_in[18];
    const float* outw  = (const float*)d_in[19];
    const float* outb  = (const float*)d_in[20];

    float* ws = (float*)d_ws;
    size_t off = 0;
    unsigned short* wT1h = (unsigned short*)(ws + off); off += 100352;
    unsigned short* wT1l = (unsigned short*)(ws + off); off += 100352;
    unsigned short* wT2h = (unsigned short*)(ws + off); off += 25088;
    unsigned short* wT2l = (unsigned short*)(ws + off); off += 25088;
    unsigned short* wT3h = (unsigned short*)(ws + off); off += 50176;
    unsigned short* wT3l = (unsigned short*)(ws + off); off += 50176;
    float* stats = ws + off; off += 192;
    float* bn    = ws + off; off += 192;
    float* cn_fin= ws + off; off += 32768;
    unsigned short* chiT = (unsigned short*)(ws + off); off += 16384;
    unsigned short* cloT = (unsigned short*)(ws + off); off += 16384;
    unsigned short* xTh  = (unsigned short*)(ws + off); off += 4194304;
    unsigned short* xTl  = (unsigned short*)(ws + off); off += 4194304;
    unsigned short* pfch = (unsigned short*)(ws + off); off += 4194304;
    unsigned short* a12H = (unsigned short*)(ws + off); off += 2097152;
    unsigned short* a12L = (unsigned short*)(ws + off); off += 2097152;

    // d_out scratch timeline:
    //   yraw   @0, 8MB      (conv stages; dead after stage-3 bna)
    //   a3H/L  @32MB, 8MB   (written stage-3 bna, read by feat; dead after)
    //   qh     @0, 32MB     (dist iterations)
    //   cn_part@32MB, 32MB  (cn iterations; aliases dead a3)
    //   qf     @0, 64MB     (final dist overwrites everything)
    char* ob = (char*)d_out;
    float* yraw = (float*)ob;
    unsigned short* qh = (unsigned short*)ob;
    float* qf = (float*)ob;
    float* cn_part = (float*)(ob + (size_t)32 * 1024 * 1024);
    unsigned short* a3H = (unsigned short*)(ob + (size_t)32 * 1024 * 1024);
    unsigned short* a3L = a3H + (size_t)HW * 32;

    hipMemsetAsync(stats, 0, 192 * sizeof(float), stream);
    wmerge_kernel<<<(49 * 32 * 128 + 255) / 256, 256, 0, stream>>>(s1k7, s1k5, s1k3, 103, 128, wT1h, wT1l);
    wmerge_kernel<<<(49 * 32 * 32 + 255) / 256, 256, 0, stream>>>(s2k7, s2k5, s2k3, 32, 32, wT2h, wT2l);
    wmerge_kernel<<<(49 * 32 * 64 + 255) / 256, 256, 0, stream>>>(s3k7, s3k5, s3k3, 64, 64, wT3h, wT3l);

    transpose_kernel<<<1024, 256, 0, stream>>>(x, xTh, xTl, pfch);

    // stage 1
    convm_kernel<<<1024, 256, 0, stream>>>(xTh, xTl, 128, wT1h, wT1l, 128, 4, yraw);
    stats_kernel<<<1024, 256, 0, stream>>>(yraw, stats + 0, stats + 32);
    bnp_kernel<<<1, 32, 0, stream>>>(stats + 0, stats + 32, s1g, s1be, bn + 0, bn + 32);
    bna_kernel<<<1024, 256, 0, stream>>>(yraw, bn + 0, bn + 32, a12H, a12L, 64, 0);

    // stage 2
    convm_kernel<<<1024, 256, 0, stream>>>(a12H, a12L, 64, wT2h, wT2l, 32, 1, yraw);
    stats_kernel<<<1024, 256, 0, stream>>>(yraw, stats + 64, stats + 96);
    bnp_kernel<<<1, 32, 0, stream>>>(stats + 64, stats + 96, s2g, s2be, bn + 64, bn + 96);
    bna_kernel<<<1024, 256, 0, stream>>>(yraw, bn + 64, bn + 96, a12H, a12L, 64, 32);

    // stage 3
    convm_kernel<<<1024, 256, 0, stream>>>(a12H, a12L, 64, wT3h, wT3l, 64, 2, yraw);
    stats_kernel<<<1024, 256, 0, stream>>>(yraw, stats + 128, stats + 160);
    bnp_kernel<<<1, 32, 0, stream>>>(stats + 128, stats + 160, s3g, s3be, bn + 128, bn + 160);
    bna_kernel<<<1024, 256, 0, stream>>>(yraw, bn + 128, bn + 160, a3H, a3L, 32, 0);

    feat_kernel<<<256, 256, 0, stream>>>(a12H, a12L, a3H, a3L, outw, outb, xTh, xTl, pfch);
    c0_kernel<<<256, 256, 0, stream>>>(xTh, xTl, cn_fin);
    prep_kernel<<<256, 128, 0, stream>>>(cn_fin, chiT, cloT, 1.f / 256.f, 0);

    for (int it = 0; it < 5; ++it) {
        dist_kernel<<<1024, 256, 0, stream>>>(chiT, cloT, xTh, xTl, qh, qf, 0);
        cn_kernel<<<256, 512, 0, stream>>>(qh, pfch, cn_part);
        reduce_cn<<<256, 128, 0, stream>>>(cn_part, cn_fin);
        prep_kernel<<<256, 128, 0, stream>>>(cn_fin, chiT, cloT, 0.f, 1);
    }
    dist_kernel<<<1024, 256, 0, stream>>>(chiT, cloT, xTh, xTl, qh, qf, 1);
}

// Round 7
// 1266.438 us; speedup vs baseline: 1.1425x; 1.1425x over previous
//
#include <hip/hip_runtime.h>

#define HW 65536

typedef short bf16x8 __attribute__((ext_vector_type(8)));
typedef float f32x4 __attribute__((ext_vector_type(4)));
typedef unsigned short u16x8 __attribute__((ext_vector_type(8)));

__device__ inline unsigned short f2bf(float v) {
    unsigned u = __float_as_uint(v);
    unsigned r = (u + 0x7FFF + ((u >> 16) & 1)) >> 16;
    return (unsigned short)r;
}
__device__ inline float ubf(unsigned short h) {
    return __uint_as_float(((unsigned)h) << 16);
}
__device__ inline uint4 pack8(const unsigned short* p) {
    uint4 u;
    u.x = (unsigned)p[0] | ((unsigned)p[1] << 16);
    u.y = (unsigned)p[2] | ((unsigned)p[3] << 16);
    u.z = (unsigned)p[4] | ((unsigned)p[5] << 16);
    u.w = (unsigned)p[6] | ((unsigned)p[7] << 16);
    return u;
}

// ---------------------------------------------------------------------------
// Merge 7/5/3 kernels into one 7x7 and write bf16 hi/lo in [tap][oc][ci] layout
// ---------------------------------------------------------------------------
__global__ void wmerge_kernel(const float* __restrict__ k7, const float* __restrict__ k5,
                              const float* __restrict__ k3, int Cin, int Cpw,
                              unsigned short* __restrict__ wTh, unsigned short* __restrict__ wTl)
{
    int idx = blockIdx.x * 256 + threadIdx.x;
    int total = 49 * 32 * Cpw;
    if (idx >= total) return;
    int ci = idx % Cpw;
    int oc = (idx / Cpw) & 31;
    int tap = idx / (Cpw * 32);
    int ky = tap / 7, kx = tap % 7;
    float v = 0.f;
    if (ci < Cin) {
        v = k7[(oc * Cin + ci) * 49 + tap];
        if (ky >= 1 && ky <= 5 && kx >= 1 && kx <= 5)
            v += k5[(oc * Cin + ci) * 25 + (ky - 1) * 5 + (kx - 1)];
        if (ky >= 2 && ky <= 4 && kx >= 2 && kx <= 4)
            v += k3[(oc * Cin + ci) * 9 + (ky - 2) * 3 + (kx - 2)];
    }
    unsigned short h = f2bf(v);
    wTh[idx] = h;
    wTl[idx] = f2bf(v - ubf(h));
}

// ---------------------------------------------------------------------------
// x [103][HW] fp32 -> xT [n][128] bf16 hi/lo (slots 0..102 = x, 103..127 = 0)
// and pfch [c][HW] bf16 hi (rows 0..102)
// ---------------------------------------------------------------------------
__global__ __launch_bounds__(256) void transpose_kernel(
    const float* __restrict__ x,
    unsigned short* __restrict__ xTh, unsigned short* __restrict__ xTl,
    unsigned short* __restrict__ pfch)
{
    __shared__ float buf[64 * 105];
    int t = threadIdx.x;
    int px0 = blockIdx.x * 64;
    for (int i = t; i < 103 * 64; i += 256) {
        int c = i >> 6, lane = i & 63;
        float v = x[(size_t)c * HW + px0 + lane];
        buf[lane * 105 + c] = v;
        pfch[(size_t)c * HW + px0 + lane] = f2bf(v);
    }
    __syncthreads();
    int px = t >> 2, seg = t & 3;
    unsigned short h[32], l[32];
#pragma unroll
    for (int j = 0; j < 32; ++j) {
        int c = seg * 32 + j;
        float v = (c < 103) ? buf[px * 105 + c] : 0.f;
        h[j] = f2bf(v);
        l[j] = f2bf(v - ubf(h[j]));
    }
    size_t base = (size_t)(px0 + px) * 128 + seg * 32;
#pragma unroll
    for (int k = 0; k < 4; ++k) {
        *(uint4*)(xTh + base + k * 8) = pack8(h + k * 8);
        *(uint4*)(xTl + base + k * 8) = pack8(l + k * 8);
    }
}

// ---------------------------------------------------------------------------
// Implicit-GEMM 7x7 conv via MFMA 16x16x32 bf16, 3-phase hi/lo.
// Key: 4-deep weight prefetch ring (tap loop fully unrolled -> static
// indices) so ~16 weight loads stay in flight across ~4 taps of MFMA.
// Block: 256 thr = 4 waves; wave: 2 y-rows x 16 px x 32 oc. Grid 512.
// ---------------------------------------------------------------------------
__global__ __launch_bounds__(256) void convm_kernel(
    const unsigned short* __restrict__ actH, const unsigned short* __restrict__ actL,
    int Cs,
    const unsigned short* __restrict__ wTh, const unsigned short* __restrict__ wTl,
    int Cpw, int nch,
    float* __restrict__ yraw)
{
    __shared__ __align__(16) unsigned short sH[14 * 704];
    __shared__ __align__(16) unsigned short sL[14 * 704];
    int t = threadIdx.x;
    int w = t >> 6, l = t & 63;
    int lc = l & 15, lg = l >> 4;
    int bx = blockIdx.x & 15, byy = blockIdx.x >> 4;
    int x0 = bx * 16, y0 = byy * 8;

    f32x4 a_hh[2][2], a_lh[2][2], a_hl[2][2];   // [oc-tile][row]
#pragma unroll
    for (int ot = 0; ot < 2; ++ot)
#pragma unroll
        for (int rr = 0; rr < 2; ++rr)
#pragma unroll
            for (int r = 0; r < 4; ++r) {
                a_hh[ot][rr][r] = 0.f; a_lh[ot][rr][r] = 0.f; a_hl[ot][rr][r] = 0.f;
            }

    for (int ch = 0; ch < nch; ++ch) {
        int ci0 = ch * 32;
        __syncthreads();
        for (int i = t; i < 2464; i += 256) {
            int pl = (i >= 1232) ? 1 : 0;
            int j = pl ? i - 1232 : i;
            int row = j / 88;
            int rem = j - row * 88;
            int px = rem >> 2, q = rem & 3;
            int gy = y0 - 3 + row, gx = x0 - 3 + px;
            uint4 v = {0u, 0u, 0u, 0u};
            if (gy >= 0 && gy < 256 && gx >= 0 && gx < 256) {
                const unsigned short* src = pl ? actL : actH;
                v = *(const uint4*)(src + (size_t)(gy * 256 + gx) * Cs + ci0 + q * 8);
            }
            unsigned short* dst = pl ? sL : sH;
            *(uint4*)(dst + row * 704 + q * 176 + px * 8) = v;
        }
        __syncthreads();

        const unsigned short* wh = wTh + lc * Cpw + ci0 + 8 * lg;
        const unsigned short* wl = wTl + lc * Cpw + ci0 + 8 * lg;

        // prefetch ring: 4 taps deep, 4 fragments per tap
        bf16x8 wh0[4], wh1[4], wl0[4], wl1[4];
#pragma unroll
        for (int p = 0; p < 4; ++p) {
            int noff = p * 32 * Cpw;
            wh0[p] = *(const bf16x8*)(wh + noff);
            wh1[p] = *(const bf16x8*)(wh + noff + 16 * Cpw);
            wl0[p] = *(const bf16x8*)(wl + noff);
            wl1[p] = *(const bf16x8*)(wl + noff + 16 * Cpw);
        }

#pragma unroll
        for (int tap = 0; tap < 49; ++tap) {
            const int s = tap & 3;
            const int ky = tap / 7;
            const int kx = tap - ky * 7;
            bf16x8 xh[2], xl[2];
#pragma unroll
            for (int rr = 0; rr < 2; ++rr) {
                int off = (w * 2 + rr + ky) * 704 + lg * 176 + (lc + kx) * 8;
                xh[rr] = *(const bf16x8*)(sH + off);
                xl[rr] = *(const bf16x8*)(sL + off);
            }
#pragma unroll
            for (int rr = 0; rr < 2; ++rr) {
                a_hh[0][rr] = __builtin_amdgcn_mfma_f32_16x16x32_bf16(wh0[s], xh[rr], a_hh[0][rr], 0, 0, 0);
                a_hh[1][rr] = __builtin_amdgcn_mfma_f32_16x16x32_bf16(wh1[s], xh[rr], a_hh[1][rr], 0, 0, 0);
                a_lh[0][rr] = __builtin_amdgcn_mfma_f32_16x16x32_bf16(wl0[s], xh[rr], a_lh[0][rr], 0, 0, 0);
                a_lh[1][rr] = __builtin_amdgcn_mfma_f32_16x16x32_bf16(wl1[s], xh[rr], a_lh[1][rr], 0, 0, 0);
                a_hl[0][rr] = __builtin_amdgcn_mfma_f32_16x16x32_bf16(wh0[s], xl[rr], a_hl[0][rr], 0, 0, 0);
                a_hl[1][rr] = __builtin_amdgcn_mfma_f32_16x16x32_bf16(wh1[s], xl[rr], a_hl[1][rr], 0, 0, 0);
            }
            if (tap + 4 < 49) {
                int noff = (tap + 4) * 32 * Cpw;
                wh0[s] = *(const bf16x8*)(wh + noff);
                wh1[s] = *(const bf16x8*)(wh + noff + 16 * Cpw);
                wl0[s] = *(const bf16x8*)(wl + noff);
                wl1[s] = *(const bf16x8*)(wl + noff + 16 * Cpw);
            }
        }
    }

#pragma unroll
    for (int ot = 0; ot < 2; ++ot)
#pragma unroll
        for (int rr = 0; rr < 2; ++rr) {
            int n = (y0 + w * 2 + rr) * 256 + x0 + lc;
#pragma unroll
            for (int r = 0; r < 4; ++r) {
                int oc = ot * 16 + lg * 4 + r;
                yraw[(size_t)oc * HW + n] = a_hh[ot][rr][r] + a_lh[ot][rr][r] + a_hl[ot][rr][r];
            }
        }
}

// ---------------------------------------------------------------------------
// per-channel sum/sumsq of yraw
// ---------------------------------------------------------------------------
__global__ __launch_bounds__(256) void stats_kernel(
    const float* __restrict__ yraw, float* __restrict__ ssum, float* __restrict__ ssq)
{
    int c = blockIdx.x >> 5, seg = blockIdx.x & 31;
    int base = c * HW + seg * 2048 + threadIdx.x * 8;
    float4 a0 = *(const float4*)&yraw[base];
    float4 a1 = *(const float4*)&yraw[base + 4];
    float s = a0.x + a0.y + a0.z + a0.w + a1.x + a1.y + a1.z + a1.w;
    float q = a0.x * a0.x + a0.y * a0.y + a0.z * a0.z + a0.w * a0.w
            + a1.x * a1.x + a1.y * a1.y + a1.z * a1.z + a1.w * a1.w;
#pragma unroll
    for (int d = 32; d >= 1; d >>= 1) {
        s += __shfl_down(s, d);
        q += __shfl_down(q, d);
    }
    __shared__ float ls[4], lq[4];
    int w = threadIdx.x >> 6;
    if ((threadIdx.x & 63) == 0) { ls[w] = s; lq[w] = q; }
    __syncthreads();
    if (threadIdx.x == 0) {
        atomicAdd(&ssum[c], ls[0] + ls[1] + ls[2] + ls[3]);
        atomicAdd(&ssq[c], lq[0] + lq[1] + lq[2] + lq[3]);
    }
}

__global__ void bnp_kernel(const float* __restrict__ ssum, const float* __restrict__ ssq,
                           const float* __restrict__ g, const float* __restrict__ beta,
                           float* __restrict__ scl, float* __restrict__ shf)
{
    int c = threadIdx.x;
    float mu  = ssum[c] * (1.f / 65536.f);
    float var = ssq[c] * (1.f / 65536.f) - mu * mu;
    float s = g[c] * rsqrtf(var + 1e-5f);
    scl[c] = s;
    shf[c] = beta[c] - mu * s;
}

// ---------------------------------------------------------------------------
// BN + ReLU + write channel-last bf16 hi/lo
// ---------------------------------------------------------------------------
__global__ __launch_bounds__(256) void bna_kernel(
    const float* __restrict__ yraw, const float* __restrict__ scl, const float* __restrict__ shf,
    unsigned short* __restrict__ aH, unsigned short* __restrict__ aL, int Cs, int slot0)
{
    int t = threadIdx.x;
    int lane = t & 63, cg = t >> 6;
    int px = blockIdx.x * 64 + lane;
    unsigned short h[8], l[8];
#pragma unroll
    for (int j = 0; j < 8; ++j) {
        int c = cg * 8 + j;
        float v = fmaxf(yraw[(size_t)c * HW + px] * scl[c] + shf[c], 0.f);
        h[j] = f2bf(v);
        l[j] = f2bf(v - ubf(h[j]));
    }
    *(uint4*)(aH + (size_t)px * Cs + slot0 + cg * 8) = pack8(h);
    *(uint4*)(aL + (size_t)px * Cs + slot0 + cg * 8) = pack8(l);
}

// ---------------------------------------------------------------------------
// 1x1 conv (96->15) + ReLU from channel-last activations; writes pf slots
// 103..127 of xT (hi/lo) and pfch rows 103..127.
// ---------------------------------------------------------------------------
__global__ __launch_bounds__(256) void feat_kernel(
    const unsigned short* __restrict__ a12H, const unsigned short* __restrict__ a12L,
    const unsigned short* __restrict__ a3H, const unsigned short* __restrict__ a3L,
    const float* __restrict__ w, const float* __restrict__ b,
    unsigned short* __restrict__ xTh, unsigned short* __restrict__ xTl,
    unsigned short* __restrict__ pfch)
{
    int n = blockIdx.x * 256 + threadIdx.x;
    float facc[15];
#pragma unroll
    for (int oc = 0; oc < 15; ++oc) facc[oc] = b[oc];

#pragma unroll
    for (int k = 0; k < 12; ++k) {
        uint4 uh, ul;
        if (k < 8) {
            uh = *(const uint4*)(a12H + (size_t)n * 64 + k * 8);
            ul = *(const uint4*)(a12L + (size_t)n * 64 + k * 8);
        } else {
            uh = *(const uint4*)(a3H + (size_t)n * 32 + (k - 8) * 8);
            ul = *(const uint4*)(a3L + (size_t)n * 32 + (k - 8) * 8);
        }
        unsigned hw_[4] = {uh.x, uh.y, uh.z, uh.w};
        unsigned lw_[4] = {ul.x, ul.y, ul.z, ul.w};
#pragma unroll
        for (int j = 0; j < 8; ++j) {
            unsigned short hh = (unsigned short)(hw_[j >> 1] >> ((j & 1) * 16));
            unsigned short ll = (unsigned short)(lw_[j >> 1] >> ((j & 1) * 16));
            float av = ubf(hh) + ubf(ll);
#pragma unroll
            for (int oc = 0; oc < 15; ++oc)
                facc[oc] = fmaf(av, w[oc * 96 + k * 8 + j], facc[oc]);
        }
    }
    unsigned short fh[16], fl[16];
#pragma unroll
    for (int oc = 0; oc < 15; ++oc) {
        float v = fmaxf(facc[oc], 0.f);
        fh[oc] = f2bf(v);
        fl[oc] = f2bf(v - ubf(fh[oc]));
    }
    fh[15] = 0; fl[15] = 0;

    size_t base = (size_t)n * 128;
    uint4 h0 = *(const uint4*)(xTh + base + 96);
    uint4 l0 = *(const uint4*)(xTl + base + 96);
    h0.w = (h0.w & 0xFFFFu) | ((unsigned)fh[0] << 16);
    l0.w = (l0.w & 0xFFFFu) | ((unsigned)fl[0] << 16);
    *(uint4*)(xTh + base + 96) = h0;
    *(uint4*)(xTl + base + 96) = l0;
    *(uint4*)(xTh + base + 104) = pack8(fh + 1);
    *(uint4*)(xTl + base + 104) = pack8(fl + 1);
    unsigned short t2h[8], t2l[8];
#pragma unroll
    for (int j = 0; j < 8; ++j) {
        t2h[j] = (j < 6) ? fh[9 + j] : (unsigned short)0;
        t2l[j] = (j < 6) ? fl[9 + j] : (unsigned short)0;
    }
    *(uint4*)(xTh + base + 112) = pack8(t2h);
    *(uint4*)(xTl + base + 112) = pack8(t2l);
    unsigned short t3h[8] = {0, 0, 0, 0, 0, 0, 0, 0x3F80};
    unsigned short t3l[8] = {0, 0, 0, 0, 0, 0, 0, 0};
    *(uint4*)(xTh + base + 120) = pack8(t3h);
    *(uint4*)(xTl + base + 120) = pack8(t3l);

#pragma unroll
    for (int k2 = 0; k2 < 15; ++k2)
        pfch[(size_t)(103 + k2) * HW + n] = fh[k2];
    pfch[(size_t)118 * HW + n] = 0x3F80;
#pragma unroll
    for (int c = 119; c < 128; ++c)
        pfch[(size_t)c * HW + n] = 0;
}

// ---------------------------------------------------------------------------
// c0: per-superpixel channel sums -> cn_fin[s][128]
// ---------------------------------------------------------------------------
__global__ __launch_bounds__(256) void c0_kernel(
    const unsigned short* __restrict__ pfTh, const unsigned short* __restrict__ pfTl,
    float* __restrict__ cn_fin)
{
    int s = blockIdx.x;
    int sy = s >> 4, sx = s & 15;
    int t = threadIdx.x;
    int xx = t >> 4;
    int cs = (t & 15) * 8;

    float acc[8];
#pragma unroll
    for (int j = 0; j < 8; ++j) acc[j] = 0.f;

    for (int yy = 0; yy < 16; ++yy) {
        int n = (sy * 16 + yy) * 256 + sx * 16 + xx;
        u16x8 h = *(const u16x8*)(pfTh + (size_t)n * 128 + cs);
        u16x8 l = *(const u16x8*)(pfTl + (size_t)n * 128 + cs);
#pragma unroll
        for (int j = 0; j < 8; ++j)
            acc[j] += ubf(h[j]) + ubf(l[j]);
    }
#pragma unroll
    for (int j = 0; j < 8; ++j) {
        acc[j] += __shfl_xor(acc[j], 16);
        acc[j] += __shfl_xor(acc[j], 32);
    }
    __shared__ float red[4][128];
    int w = t >> 6;
    if ((t & 63) < 16) {
#pragma unroll
        for (int j = 0; j < 8; ++j)
            red[w][(t & 15) * 8 + j] = acc[j];
    }
    __syncthreads();
    if (t < 128)
        cn_fin[s * 128 + t] = red[0][t] + red[1][t] + red[2][t] + red[3][t];
}

// ---------------------------------------------------------------------------
// prep: centroids -> chiT/cloT [s][128]; slot 127 = -0.5*|c|^2; grid 256
// ---------------------------------------------------------------------------
__global__ __launch_bounds__(128) void prep_kernel(
    const float* __restrict__ cn_fin,
    unsigned short* __restrict__ chiT, unsigned short* __restrict__ cloT,
    float scale0, int use_qsum)
{
    int s = blockIdx.x, c = threadIdx.x;
    float inv = use_qsum ? 1.f / (cn_fin[s * 128 + 118] + 1e-8f) : scale0;
    float v = (c < 118) ? cn_fin[s * 128 + c] * inv : 0.f;
    float a = v * v;
#pragma unroll
    for (int d = 1; d < 64; d <<= 1) a += __shfl_xor(a, d);
    __shared__ float red[2];
    if ((c & 63) == 0) red[c >> 6] = a;
    __syncthreads();
    float tot = red[0] + red[1];
    unsigned short h, lo;
    if (c == 127) {
        float m2 = -0.5f * tot;
        h = f2bf(m2);
        lo = f2bf(m2 - ubf(h));
    } else {
        h = f2bf(v);
        lo = f2bf(v - ubf(h));
    }
    chiT[s * 128 + c] = h;
    cloT[s * 128 + c] = lo;
}

// ---------------------------------------------------------------------------
// dist: Q[s,n] = softmax_s(2*(cent.pf - 0.5|c|^2)) via MFMA, 3-phase hi/lo
// ---------------------------------------------------------------------------
__global__ __launch_bounds__(256) void dist_kernel(
    const unsigned short* __restrict__ chiT, const unsigned short* __restrict__ cloT,
    const unsigned short* __restrict__ pfTh, const unsigned short* __restrict__ pfTl,
    unsigned short* __restrict__ qh, float* __restrict__ qf, int final_mode)
{
    int t = threadIdx.x;
    int w = t >> 6, l = t & 63;
    int n0 = blockIdx.x * 64 + w * 16;
    int lc = l & 15;
    int lg = l >> 4;

    f32x4 acc[16];
#pragma unroll
    for (int i = 0; i < 16; ++i)
#pragma unroll
        for (int j = 0; j < 4; ++j) acc[i][j] = 0.f;

#pragma unroll
    for (int phse = 0; phse < 3; ++phse) {
        const unsigned short* Ap = (phse == 1) ? cloT : chiT;
        const unsigned short* Bp = (phse == 2) ? pfTl : pfTh;
#pragma unroll
        for (int ks = 0; ks < 4; ++ks) {
            int kb = ks * 32 + 8 * lg;
            bf16x8 bfr = *(const bf16x8*)(Bp + (size_t)(n0 + lc) * 128 + kb);
#pragma unroll
            for (int st = 0; st < 16; ++st) {
                bf16x8 afr = *(const bf16x8*)(Ap + (size_t)(st * 16 + lc) * 128 + kb);
                acc[st] = __builtin_amdgcn_mfma_f32_16x16x32_bf16(afr, bfr, acc[st], 0, 0, 0);
            }
        }
    }

    float m = -1e30f;
#pragma unroll
    for (int st = 0; st < 16; ++st)
#pragma unroll
        for (int r = 0; r < 4; ++r) m = fmaxf(m, acc[st][r]);
    m = fmaxf(m, __shfl_xor(m, 16));
    m = fmaxf(m, __shfl_xor(m, 32));

    float ssum = 0.f;
#pragma unroll
    for (int st = 0; st < 16; ++st)
#pragma unroll
        for (int r = 0; r < 4; ++r) {
            float e = __expf(2.f * (acc[st][r] - m));
            acc[st][r] = e;
            ssum += e;
        }
    ssum += __shfl_xor(ssum, 16);
    ssum += __shfl_xor(ssum, 32);
    float inv = 1.f / ssum;

    int n = n0 + lc;
    if (!final_mode) {
#pragma unroll
        for (int st = 0; st < 16; ++st)
#pragma unroll
            for (int r = 0; r < 4; ++r) {
                int s = st * 16 + lg * 4 + r;
                qh[(size_t)s * HW + n] = f2bf(acc[st][r] * inv);
            }
    } else {
#pragma unroll
        for (int st = 0; st < 16; ++st)
#pragma unroll
            for (int r = 0; r < 4; ++r) {
                int s = st * 16 + lg * 4 + r;
                qf[(size_t)s * HW + n] = acc[st][r] * inv;
            }
    }
}

// ---------------------------------------------------------------------------
// cn: cn_fin[s][c] += sum_n Q[s,n]*pf[c,n]; grid 256; atomics (no partials)
// ---------------------------------------------------------------------------
__global__ __launch_bounds__(512) void cn_kernel(
    const unsigned short* __restrict__ qh, const unsigned short* __restrict__ pfch,
    float* __restrict__ cn_fin)
{
    int t = threadIdx.x;
    int w = t >> 6, l = t & 63;
    int lc = l & 15, lg = l >> 4;
    int n0 = blockIdx.x * 256;

    f32x4 acc[16];
#pragma unroll
    for (int i = 0; i < 16; ++i)
#pragma unroll
        for (int j = 0; j < 4; ++j) acc[i][j] = 0.f;

    for (int ks = 0; ks < 8; ++ks) {
        int nb = n0 + ks * 32 + 8 * lg;
        bf16x8 bfr = *(const bf16x8*)(pfch + (size_t)(w * 16 + lc) * HW + nb);
#pragma unroll
        for (int st = 0; st < 16; ++st) {
            bf16x8 afr = *(const bf16x8*)(qh + (size_t)(st * 16 + lc) * HW + nb);
            acc[st] = __builtin_amdgcn_mfma_f32_16x16x32_bf16(afr, bfr, acc[st], 0, 0, 0);
        }
    }

#pragma unroll
    for (int st = 0; st < 16; ++st)
#pragma unroll
        for (int r = 0; r < 4; ++r) {
            int s = st * 16 + lg * 4 + r;
            atomicAdd(&cn_fin[s * 128 + w * 16 + lc], acc[st][r]);
        }
}

// ---------------------------------------------------------------------------
extern "C" void kernel_launch(void* const* d_in, const int* in_sizes, int n_in,
                              void* d_out, int out_size, void* d_ws, size_t ws_size,
                              hipStream_t stream)
{
    const float* x     = (const float*)d_in[0];
    const float* s1k7  = (const float*)d_in[1];
    const float* s1k5  = (const float*)d_in[2];
    const float* s1k3  = (const float*)d_in[3];
    const float* s1g   = (const float*)d_in[5];
    const float* s1be  = (const float*)d_in[6];
    const float* s2k7  = (const float*)d_in[7];
    const float* s2k5  = (const float*)d_in[8];
    const float* s2k3  = (const float*)d_in[9];
    const float* s2g   = (const float*)d_in[11];
    const float* s2be  = (const float*)d_in[12];
    const float* s3k7  = (const float*)d_in[13];
    const float* s3k5  = (const float*)d_in[14];
    const float* s3k3  = (const float*)d_in[15];
    const float* s3g   = (const float*)d_in[17];
    const float* s3be  = (const float*)d_in[18];
    const float* outw  = (const float*)d_in[19];
    const float* outb  = (const float*)d_in[20];

    float* ws = (float*)d_ws;
    size_t off = 0;
    unsigned short* wT1h = (unsigned short*)(ws + off); off += 100352;
    unsigned short* wT1l = (unsigned short*)(ws + off); off += 100352;
    unsigned short* wT2h = (unsigned short*)(ws + off); off += 25088;
    unsigned short* wT2l = (unsigned short*)(ws + off); off += 25088;
    unsigned short* wT3h = (unsigned short*)(ws + off); off += 50176;
    unsigned short* wT3l = (unsigned short*)(ws + off); off += 50176;
    float* stats = ws + off; off += 192;
    float* bn    = ws + off; off += 192;
    float* cn_fin= ws + off; off += 32768;
    unsigned short* chiT = (unsigned short*)(ws + off); off += 16384;
    unsigned short* cloT = (unsigned short*)(ws + off); off += 16384;
    unsigned short* xTh  = (unsigned short*)(ws + off); off += 4194304;
    unsigned short* xTl  = (unsigned short*)(ws + off); off += 4194304;
    unsigned short* pfch = (unsigned short*)(ws + off); off += 4194304;
    unsigned short* a12H = (unsigned short*)(ws + off); off += 2097152;
    unsigned short* a12L = (unsigned short*)(ws + off); off += 2097152;

    // d_out scratch timeline:
    //   yraw   @0, 8MB      (conv stages; dead after stage-3 bna)
    //   a3H/L  @32MB, 8MB   (written stage-3 bna, read by feat; dead after)
    //   qh     @0, 32MB     (dist iterations)
    //   qf     @0, 64MB     (final dist overwrites everything)
    char* ob = (char*)d_out;
    float* yraw = (float*)ob;
    unsigned short* qh = (unsigned short*)ob;
    float* qf = (float*)ob;
    unsigned short* a3H = (unsigned short*)(ob + (size_t)32 * 1024 * 1024);
    unsigned short* a3L = a3H + (size_t)HW * 32;

    hipMemsetAsync(stats, 0, 192 * sizeof(float), stream);
    wmerge_kernel<<<(49 * 32 * 128 + 255) / 256, 256, 0, stream>>>(s1k7, s1k5, s1k3, 103, 128, wT1h, wT1l);
    wmerge_kernel<<<(49 * 32 * 32 + 255) / 256, 256, 0, stream>>>(s2k7, s2k5, s2k3, 32, 32, wT2h, wT2l);
    wmerge_kernel<<<(49 * 32 * 64 + 255) / 256, 256, 0, stream>>>(s3k7, s3k5, s3k3, 64, 64, wT3h, wT3l);

    transpose_kernel<<<1024, 256, 0, stream>>>(x, xTh, xTl, pfch);

    // stage 1
    convm_kernel<<<512, 256, 0, stream>>>(xTh, xTl, 128, wT1h, wT1l, 128, 4, yraw);
    stats_kernel<<<1024, 256, 0, stream>>>(yraw, stats + 0, stats + 32);
    bnp_kernel<<<1, 32, 0, stream>>>(stats + 0, stats + 32, s1g, s1be, bn + 0, bn + 32);
    bna_kernel<<<1024, 256, 0, stream>>>(yraw, bn + 0, bn + 32, a12H, a12L, 64, 0);

    // stage 2
    convm_kernel<<<512, 256, 0, stream>>>(a12H, a12L, 64, wT2h, wT2l, 32, 1, yraw);
    stats_kernel<<<1024, 256, 0, stream>>>(yraw, stats + 64, stats + 96);
    bnp_kernel<<<1, 32, 0, stream>>>(stats + 64, stats + 96, s2g, s2be, bn + 64, bn + 96);
    bna_kernel<<<1024, 256, 0, stream>>>(yraw, bn + 64, bn + 96, a12H, a12L, 64, 32);

    // stage 3
    convm_kernel<<<512, 256, 0, stream>>>(a12H, a12L, 64, wT3h, wT3l, 64, 2, yraw);
    stats_kernel<<<1024, 256, 0, stream>>>(yraw, stats + 128, stats + 160);
    bnp_kernel<<<1, 32, 0, stream>>>(stats + 128, stats + 160, s3g, s3be, bn + 128, bn + 160);
    bna_kernel<<<1024, 256, 0, stream>>>(yraw, bn + 128, bn + 160, a3H, a3L, 32, 0);

    feat_kernel<<<256, 256, 0, stream>>>(a12H, a12L, a3H, a3L, outw, outb, xTh, xTl, pfch);
    c0_kernel<<<256, 256, 0, stream>>>(xTh, xTl, cn_fin);
    prep_kernel<<<256, 128, 0, stream>>>(cn_fin, chiT, cloT, 1.f / 256.f, 0);

    for (int it = 0; it < 5; ++it) {
        dist_kernel<<<1024, 256, 0, stream>>>(chiT, cloT, xTh, xTl, qh, qf, 0);
        hipMemsetAsync(cn_fin, 0, 32768 * sizeof(float), stream);
        cn_kernel<<<256, 512, 0, stream>>>(qh, pfch, cn_fin);
        prep_kernel<<<256, 128, 0, stream>>>(cn_fin, chiT, cloT, 0.f, 1);
    }
    dist_kernel<<<1024, 256, 0, stream>>>(chiT, cloT, xTh, xTl, qh, qf, 1);
}

// Round 8
// 1120.671 us; speedup vs baseline: 1.2911x; 1.1301x over previous
//
#include <hip/hip_runtime.h>

#define HW 65536

typedef short bf16x8 __attribute__((ext_vector_type(8)));
typedef float f32x4 __attribute__((ext_vector_type(4)));
typedef unsigned short u16x8 __attribute__((ext_vector_type(8)));

__device__ inline unsigned short f2bf(float v) {
    unsigned u = __float_as_uint(v);
    unsigned r = (u + 0x7FFF + ((u >> 16) & 1)) >> 16;
    return (unsigned short)r;
}
__device__ inline float ubf(unsigned short h) {
    return __uint_as_float(((unsigned)h) << 16);
}
__device__ inline uint4 pack8(const unsigned short* p) {
    uint4 u;
    u.x = (unsigned)p[0] | ((unsigned)p[1] << 16);
    u.y = (unsigned)p[2] | ((unsigned)p[3] << 16);
    u.z = (unsigned)p[4] | ((unsigned)p[5] << 16);
    u.w = (unsigned)p[6] | ((unsigned)p[7] << 16);
    return u;
}

// ---------------------------------------------------------------------------
// Merge 7/5/3 kernels into one 7x7; emit bf16 hi/lo in A-FRAGMENT LANE ORDER:
// elem index = ((tap*nch + chunk)*2 + octile)*512 + lane*8 + e
// where oc = octile*16 + (lane&15), ci = chunk*32 + (lane>>4)*8 + e.
// So LDS staging is a linear copy and A-frag reads are sW[lane*16B].
// ---------------------------------------------------------------------------
__global__ void wmerge_kernel(const float* __restrict__ k7, const float* __restrict__ k5,
                              const float* __restrict__ k3, int Cin, int nch,
                              unsigned short* __restrict__ wTh, unsigned short* __restrict__ wTl)
{
    int idx = blockIdx.x * 256 + threadIdx.x;
    int total = 49 * nch * 1024;
    if (idx >= total) return;
    int e = idx & 7;
    int lane = (idx >> 3) & 63;
    int octile = (idx >> 9) & 1;
    int chunk = (idx >> 10) % nch;
    int tap = idx / (nch << 10);
    int oc = octile * 16 + (lane & 15);
    int ci = chunk * 32 + (lane >> 4) * 8 + e;
    int ky = tap / 7, kx = tap % 7;
    float v = 0.f;
    if (ci < Cin) {
        v = k7[(oc * Cin + ci) * 49 + tap];
        if (ky >= 1 && ky <= 5 && kx >= 1 && kx <= 5)
            v += k5[(oc * Cin + ci) * 25 + (ky - 1) * 5 + (kx - 1)];
        if (ky >= 2 && ky <= 4 && kx >= 2 && kx <= 4)
            v += k3[(oc * Cin + ci) * 9 + (ky - 2) * 3 + (kx - 2)];
    }
    unsigned short h = f2bf(v);
    wTh[idx] = h;
    wTl[idx] = f2bf(v - ubf(h));
}

// ---------------------------------------------------------------------------
// x [103][HW] fp32 -> xT [n][128] bf16 hi/lo and pfch [c][HW] bf16 hi
// ---------------------------------------------------------------------------
__global__ __launch_bounds__(256) void transpose_kernel(
    const float* __restrict__ x,
    unsigned short* __restrict__ xTh, unsigned short* __restrict__ xTl,
    unsigned short* __restrict__ pfch)
{
    __shared__ float buf[64 * 105];
    int t = threadIdx.x;
    int px0 = blockIdx.x * 64;
    for (int i = t; i < 103 * 64; i += 256) {
        int c = i >> 6, lane = i & 63;
        float v = x[(size_t)c * HW + px0 + lane];
        buf[lane * 105 + c] = v;
        pfch[(size_t)c * HW + px0 + lane] = f2bf(v);
    }
    __syncthreads();
    int px = t >> 2, seg = t & 3;
    unsigned short h[32], l[32];
#pragma unroll
    for (int j = 0; j < 32; ++j) {
        int c = seg * 32 + j;
        float v = (c < 103) ? buf[px * 105 + c] : 0.f;
        h[j] = f2bf(v);
        l[j] = f2bf(v - ubf(h[j]));
    }
    size_t base = (size_t)(px0 + px) * 128 + seg * 32;
#pragma unroll
    for (int k = 0; k < 4; ++k) {
        *(uint4*)(xTh + base + k * 8) = pack8(h + k * 8);
        *(uint4*)(xTl + base + k * 8) = pack8(l + k * 8);
    }
}

// ---------------------------------------------------------------------------
// Implicit-GEMM 7x7 conv, MFMA 16x16x32 bf16, 3-phase hi/lo.
// Weights staged in LDS per 7-tap group (shared by all 4 waves -> 4x less
// L2 weight traffic). Activations in LDS as before. Work split across
// blockIdx.y (z=2): ci-chunk ranges and/or tap ranges per z; partial planes.
// Block: 256 thr = 4 waves; wave: 2 y-rows x 16 px x 32 oc.
// ---------------------------------------------------------------------------
__global__ __launch_bounds__(256) void convm_kernel(
    const unsigned short* __restrict__ actH, const unsigned short* __restrict__ actL,
    int Cs,
    const unsigned short* __restrict__ wTh, const unsigned short* __restrict__ wTl,
    int nchw,
    int c0a, int c1a, int t0a, int t1a,
    int c0b, int c1b, int t0b, int t1b,
    float* __restrict__ ypart)
{
    __shared__ __align__(16) unsigned short sH[14 * 704];
    __shared__ __align__(16) unsigned short sL[14 * 704];
    __shared__ __align__(16) unsigned short sW[7 * 2048];
    int t = threadIdx.x;
    int w = t >> 6, l = t & 63;
    int lc = l & 15, lg = l >> 4;
    int bx = blockIdx.x & 15, byy = blockIdx.x >> 4;
    int x0 = bx * 16, y0 = byy * 8;
    int z = blockIdx.y;
    int ch0 = z ? c0b : c0a, ch1 = z ? c1b : c1a;
    int tap0 = z ? t0b : t0a, tap1 = z ? t1b : t1a;
    float* yp = ypart + (size_t)z * 32 * HW;

    f32x4 a_hh[2][2], a_lh[2][2], a_hl[2][2];   // [oc-tile][row]
#pragma unroll
    for (int ot = 0; ot < 2; ++ot)
#pragma unroll
        for (int rr = 0; rr < 2; ++rr)
#pragma unroll
            for (int r = 0; r < 4; ++r) {
                a_hh[ot][rr][r] = 0.f; a_lh[ot][rr][r] = 0.f; a_hl[ot][rr][r] = 0.f;
            }

    for (int ch = ch0; ch < ch1; ++ch) {
        int ci0 = ch * 32;
        __syncthreads();                // protect sH/sL/sW from prior reads
        for (int i = t; i < 2464; i += 256) {
            int pl = (i >= 1232) ? 1 : 0;
            int j = pl ? i - 1232 : i;
            int row = j / 88;
            int rem = j - row * 88;
            int px = rem >> 2, q = rem & 3;
            int gy = y0 - 3 + row, gx = x0 - 3 + px;
            uint4 v = {0u, 0u, 0u, 0u};
            if (gy >= 0 && gy < 256 && gx >= 0 && gx < 256) {
                const unsigned short* src = pl ? actL : actH;
                v = *(const uint4*)(src + (size_t)(gy * 256 + gx) * Cs + ci0 + q * 8);
            }
            unsigned short* dst = pl ? sL : sH;
            *(uint4*)(dst + row * 704 + q * 176 + px * 8) = v;
        }

        for (int g = tap0; g < tap1; g += 7) {
            int ge = g + 7; if (ge > tap1) ge = tap1;
            if (g > tap0) __syncthreads();      // protect sW from prior group reads
            // stage weights [g, ge): per tap 2048 elems (hi 1024 | lo 1024)
            for (int i = t; i < (ge - g) * 256; i += 256) {
                int tp = i >> 8, r = i & 255;
                const unsigned short* src = (r < 128) ? wTh : wTl;
                *(uint4*)(sW + tp * 2048 + r * 8) =
                    *(const uint4*)(src + ((size_t)((g + tp) * nchw + ch)) * 1024 + (r & 127) * 8);
            }
            __syncthreads();

            for (int tap = g; tap < ge; ++tap) {
                const unsigned short* wb = sW + (tap - g) * 2048 + l * 8;
                bf16x8 ah0 = *(const bf16x8*)(wb);
                bf16x8 ah1 = *(const bf16x8*)(wb + 512);
                bf16x8 al0 = *(const bf16x8*)(wb + 1024);
                bf16x8 al1 = *(const bf16x8*)(wb + 1536);
                int ky = tap / 7;
                int kx = tap - ky * 7;
                bf16x8 xh[2], xl[2];
#pragma unroll
                for (int rr = 0; rr < 2; ++rr) {
                    int off = (w * 2 + rr + ky) * 704 + lg * 176 + (lc + kx) * 8;
                    xh[rr] = *(const bf16x8*)(sH + off);
                    xl[rr] = *(const bf16x8*)(sL + off);
                }
#pragma unroll
                for (int rr = 0; rr < 2; ++rr) {
                    a_hh[0][rr] = __builtin_amdgcn_mfma_f32_16x16x32_bf16(ah0, xh[rr], a_hh[0][rr], 0, 0, 0);
                    a_hh[1][rr] = __builtin_amdgcn_mfma_f32_16x16x32_bf16(ah1, xh[rr], a_hh[1][rr], 0, 0, 0);
                    a_lh[0][rr] = __builtin_amdgcn_mfma_f32_16x16x32_bf16(al0, xh[rr], a_lh[0][rr], 0, 0, 0);
                    a_lh[1][rr] = __builtin_amdgcn_mfma_f32_16x16x32_bf16(al1, xh[rr], a_lh[1][rr], 0, 0, 0);
                    a_hl[0][rr] = __builtin_amdgcn_mfma_f32_16x16x32_bf16(ah0, xl[rr], a_hl[0][rr], 0, 0, 0);
                    a_hl[1][rr] = __builtin_amdgcn_mfma_f32_16x16x32_bf16(ah1, xl[rr], a_hl[1][rr], 0, 0, 0);
                }
            }
        }
    }

#pragma unroll
    for (int ot = 0; ot < 2; ++ot)
#pragma unroll
        for (int rr = 0; rr < 2; ++rr) {
            int n = (y0 + w * 2 + rr) * 256 + x0 + lc;
#pragma unroll
            for (int r = 0; r < 4; ++r) {
                int oc = ot * 16 + lg * 4 + r;
                yp[(size_t)oc * HW + n] = a_hh[ot][rr][r] + a_lh[ot][rr][r] + a_hl[ot][rr][r];
            }
        }
}

// ---------------------------------------------------------------------------
// Sum 2 partial planes -> ysum, with fused per-channel sum/sumsq stats.
// Grid: 1024 (32 c x 32 seg). Block: 256 (8 floats each).
// ---------------------------------------------------------------------------
__global__ __launch_bounds__(256) void reduce2_kernel(
    const float* __restrict__ p0, const float* __restrict__ p1,
    float* __restrict__ y, float* __restrict__ ssum, float* __restrict__ ssq)
{
    int c = blockIdx.x >> 5, seg = blockIdx.x & 31;
    int base = c * HW + seg * 2048 + threadIdx.x * 8;
    float s = 0.f, q = 0.f;
#pragma unroll
    for (int h = 0; h < 2; ++h) {
        int o = base + h * 4;
        float4 a0 = *(const float4*)&p0[o];
        float4 a1 = *(const float4*)&p1[o];
        float4 v;
        v.x = a0.x + a1.x; v.y = a0.y + a1.y;
        v.z = a0.z + a1.z; v.w = a0.w + a1.w;
        *(float4*)&y[o] = v;
        s += v.x + v.y + v.z + v.w;
        q = fmaf(v.x, v.x, q); q = fmaf(v.y, v.y, q);
        q = fmaf(v.z, v.z, q); q = fmaf(v.w, v.w, q);
    }
#pragma unroll
    for (int d = 32; d >= 1; d >>= 1) {
        s += __shfl_down(s, d);
        q += __shfl_down(q, d);
    }
    __shared__ float ls[4], lq[4];
    int w = threadIdx.x >> 6;
    if ((threadIdx.x & 63) == 0) { ls[w] = s; lq[w] = q; }
    __syncthreads();
    if (threadIdx.x == 0) {
        atomicAdd(&ssum[c], ls[0] + ls[1] + ls[2] + ls[3]);
        atomicAdd(&ssq[c], lq[0] + lq[1] + lq[2] + lq[3]);
    }
}

__global__ void bnp_kernel(const float* __restrict__ ssum, const float* __restrict__ ssq,
                           const float* __restrict__ g, const float* __restrict__ beta,
                           float* __restrict__ scl, float* __restrict__ shf)
{
    int c = threadIdx.x;
    float mu  = ssum[c] * (1.f / 65536.f);
    float var = ssq[c] * (1.f / 65536.f) - mu * mu;
    float s = g[c] * rsqrtf(var + 1e-5f);
    scl[c] = s;
    shf[c] = beta[c] - mu * s;
}

// ---------------------------------------------------------------------------
// BN + ReLU + write channel-last bf16 hi/lo
// ---------------------------------------------------------------------------
__global__ __launch_bounds__(256) void bna_kernel(
    const float* __restrict__ yraw, const float* __restrict__ scl, const float* __restrict__ shf,
    unsigned short* __restrict__ aH, unsigned short* __restrict__ aL, int Cs, int slot0)
{
    int t = threadIdx.x;
    int lane = t & 63, cg = t >> 6;
    int px = blockIdx.x * 64 + lane;
    unsigned short h[8], l[8];
#pragma unroll
    for (int j = 0; j < 8; ++j) {
        int c = cg * 8 + j;
        float v = fmaxf(yraw[(size_t)c * HW + px] * scl[c] + shf[c], 0.f);
        h[j] = f2bf(v);
        l[j] = f2bf(v - ubf(h[j]));
    }
    *(uint4*)(aH + (size_t)px * Cs + slot0 + cg * 8) = pack8(h);
    *(uint4*)(aL + (size_t)px * Cs + slot0 + cg * 8) = pack8(l);
}

// ---------------------------------------------------------------------------
// 1x1 conv (96->15) + ReLU; writes pf slots 103..127 of xT and pfch rows
// ---------------------------------------------------------------------------
__global__ __launch_bounds__(256) void feat_kernel(
    const unsigned short* __restrict__ a12H, const unsigned short* __restrict__ a12L,
    const unsigned short* __restrict__ a3H, const unsigned short* __restrict__ a3L,
    const float* __restrict__ w, const float* __restrict__ b,
    unsigned short* __restrict__ xTh, unsigned short* __restrict__ xTl,
    unsigned short* __restrict__ pfch)
{
    int n = blockIdx.x * 256 + threadIdx.x;
    float facc[15];
#pragma unroll
    for (int oc = 0; oc < 15; ++oc) facc[oc] = b[oc];

#pragma unroll
    for (int k = 0; k < 12; ++k) {
        uint4 uh, ul;
        if (k < 8) {
            uh = *(const uint4*)(a12H + (size_t)n * 64 + k * 8);
            ul = *(const uint4*)(a12L + (size_t)n * 64 + k * 8);
        } else {
            uh = *(const uint4*)(a3H + (size_t)n * 32 + (k - 8) * 8);
            ul = *(const uint4*)(a3L + (size_t)n * 32 + (k - 8) * 8);
        }
        unsigned hw_[4] = {uh.x, uh.y, uh.z, uh.w};
        unsigned lw_[4] = {ul.x, ul.y, ul.z, ul.w};
#pragma unroll
        for (int j = 0; j < 8; ++j) {
            unsigned short hh = (unsigned short)(hw_[j >> 1] >> ((j & 1) * 16));
            unsigned short ll = (unsigned short)(lw_[j >> 1] >> ((j & 1) * 16));
            float av = ubf(hh) + ubf(ll);
#pragma unroll
            for (int oc = 0; oc < 15; ++oc)
                facc[oc] = fmaf(av, w[oc * 96 + k * 8 + j], facc[oc]);
        }
    }
    unsigned short fh[16], fl[16];
#pragma unroll
    for (int oc = 0; oc < 15; ++oc) {
        float v = fmaxf(facc[oc], 0.f);
        fh[oc] = f2bf(v);
        fl[oc] = f2bf(v - ubf(fh[oc]));
    }
    fh[15] = 0; fl[15] = 0;

    size_t base = (size_t)n * 128;
    uint4 h0 = *(const uint4*)(xTh + base + 96);
    uint4 l0 = *(const uint4*)(xTl + base + 96);
    h0.w = (h0.w & 0xFFFFu) | ((unsigned)fh[0] << 16);
    l0.w = (l0.w & 0xFFFFu) | ((unsigned)fl[0] << 16);
    *(uint4*)(xTh + base + 96) = h0;
    *(uint4*)(xTl + base + 96) = l0;
    *(uint4*)(xTh + base + 104) = pack8(fh + 1);
    *(uint4*)(xTl + base + 104) = pack8(fl + 1);
    unsigned short t2h[8], t2l[8];
#pragma unroll
    for (int j = 0; j < 8; ++j) {
        t2h[j] = (j < 6) ? fh[9 + j] : (unsigned short)0;
        t2l[j] = (j < 6) ? fl[9 + j] : (unsigned short)0;
    }
    *(uint4*)(xTh + base + 112) = pack8(t2h);
    *(uint4*)(xTl + base + 112) = pack8(t2l);
    unsigned short t3h[8] = {0, 0, 0, 0, 0, 0, 0, 0x3F80};
    unsigned short t3l[8] = {0, 0, 0, 0, 0, 0, 0, 0};
    *(uint4*)(xTh + base + 120) = pack8(t3h);
    *(uint4*)(xTl + base + 120) = pack8(t3l);

#pragma unroll
    for (int k2 = 0; k2 < 15; ++k2)
        pfch[(size_t)(103 + k2) * HW + n] = fh[k2];
    pfch[(size_t)118 * HW + n] = 0x3F80;
#pragma unroll
    for (int c = 119; c < 128; ++c)
        pfch[(size_t)c * HW + n] = 0;
}

// ---------------------------------------------------------------------------
// c0: per-superpixel channel sums -> cn_fin[s][128]
// ---------------------------------------------------------------------------
__global__ __launch_bounds__(256) void c0_kernel(
    const unsigned short* __restrict__ pfTh, const unsigned short* __restrict__ pfTl,
    float* __restrict__ cn_fin)
{
    int s = blockIdx.x;
    int sy = s >> 4, sx = s & 15;
    int t = threadIdx.x;
    int xx = t >> 4;
    int cs = (t & 15) * 8;

    float acc[8];
#pragma unroll
    for (int j = 0; j < 8; ++j) acc[j] = 0.f;

    for (int yy = 0; yy < 16; ++yy) {
        int n = (sy * 16 + yy) * 256 + sx * 16 + xx;
        u16x8 h = *(const u16x8*)(pfTh + (size_t)n * 128 + cs);
        u16x8 l = *(const u16x8*)(pfTl + (size_t)n * 128 + cs);
#pragma unroll
        for (int j = 0; j < 8; ++j)
            acc[j] += ubf(h[j]) + ubf(l[j]);
    }
#pragma unroll
    for (int j = 0; j < 8; ++j) {
        acc[j] += __shfl_xor(acc[j], 16);
        acc[j] += __shfl_xor(acc[j], 32);
    }
    __shared__ float red[4][128];
    int w = t >> 6;
    if ((t & 63) < 16) {
#pragma unroll
        for (int j = 0; j < 8; ++j)
            red[w][(t & 15) * 8 + j] = acc[j];
    }
    __syncthreads();
    if (t < 128)
        cn_fin[s * 128 + t] = red[0][t] + red[1][t] + red[2][t] + red[3][t];
}

// ---------------------------------------------------------------------------
// prep: centroids -> chiT/cloT [s][128]; slot 127 = -0.5*|c|^2
// ---------------------------------------------------------------------------
__global__ __launch_bounds__(128) void prep_kernel(
    const float* __restrict__ cn_fin,
    unsigned short* __restrict__ chiT, unsigned short* __restrict__ cloT,
    float scale0, int use_qsum)
{
    int s = blockIdx.x, c = threadIdx.x;
    float inv = use_qsum ? 1.f / (cn_fin[s * 128 + 118] + 1e-8f) : scale0;
    float v = (c < 118) ? cn_fin[s * 128 + c] * inv : 0.f;
    float a = v * v;
#pragma unroll
    for (int d = 1; d < 64; d <<= 1) a += __shfl_xor(a, d);
    __shared__ float red[2];
    if ((c & 63) == 0) red[c >> 6] = a;
    __syncthreads();
    float tot = red[0] + red[1];
    unsigned short h, lo;
    if (c == 127) {
        float m2 = -0.5f * tot;
        h = f2bf(m2);
        lo = f2bf(m2 - ubf(h));
    } else {
        h = f2bf(v);
        lo = f2bf(v - ubf(h));
    }
    chiT[s * 128 + c] = h;
    cloT[s * 128 + c] = lo;
}

// ---------------------------------------------------------------------------
// dist: Q[s,n] = softmax_s(2*(cent.pf - 0.5|c|^2)); 32 px per wave
// (two 16-px columns share each A fragment -> half the A-traffic).
// Block 256 thr = 4 waves, 128 px per block. Grid 512.
// ---------------------------------------------------------------------------
__global__ __launch_bounds__(256) void dist_kernel(
    const unsigned short* __restrict__ chiT, const unsigned short* __restrict__ cloT,
    const unsigned short* __restrict__ pfTh, const unsigned short* __restrict__ pfTl,
    unsigned short* __restrict__ qh, float* __restrict__ qf, int final_mode)
{
    int t = threadIdx.x;
    int w = t >> 6, l = t & 63;
    int n0 = blockIdx.x * 128 + w * 32;
    int lc = l & 15;
    int lg = l >> 4;

    f32x4 acc[16][2];
#pragma unroll
    for (int i = 0; i < 16; ++i)
#pragma unroll
        for (int hh = 0; hh < 2; ++hh)
#pragma unroll
            for (int j = 0; j < 4; ++j) acc[i][hh][j] = 0.f;

#pragma unroll
    for (int phse = 0; phse < 3; ++phse) {
        const unsigned short* Ap = (phse == 1) ? cloT : chiT;
        const unsigned short* Bp = (phse == 2) ? pfTl : pfTh;
#pragma unroll
        for (int ks = 0; ks < 4; ++ks) {
            int kb = ks * 32 + 8 * lg;
            bf16x8 b0 = *(const bf16x8*)(Bp + (size_t)(n0 + lc) * 128 + kb);
            bf16x8 b1 = *(const bf16x8*)(Bp + (size_t)(n0 + 16 + lc) * 128 + kb);
#pragma unroll
            for (int st = 0; st < 16; ++st) {
                bf16x8 afr = *(const bf16x8*)(Ap + (size_t)(st * 16 + lc) * 128 + kb);
                acc[st][0] = __builtin_amdgcn_mfma_f32_16x16x32_bf16(afr, b0, acc[st][0], 0, 0, 0);
                acc[st][1] = __builtin_amdgcn_mfma_f32_16x16x32_bf16(afr, b1, acc[st][1], 0, 0, 0);
            }
        }
    }

    // softmax per px column (2 per lane), cross-lane over lg via xor 16/32
    float m0 = -1e30f, m1 = -1e30f;
#pragma unroll
    for (int st = 0; st < 16; ++st)
#pragma unroll
        for (int r = 0; r < 4; ++r) {
            m0 = fmaxf(m0, acc[st][0][r]);
            m1 = fmaxf(m1, acc[st][1][r]);
        }
    m0 = fmaxf(m0, __shfl_xor(m0, 16)); m0 = fmaxf(m0, __shfl_xor(m0, 32));
    m1 = fmaxf(m1, __shfl_xor(m1, 16)); m1 = fmaxf(m1, __shfl_xor(m1, 32));

    float s0 = 0.f, s1 = 0.f;
#pragma unroll
    for (int st = 0; st < 16; ++st)
#pragma unroll
        for (int r = 0; r < 4; ++r) {
            float e0 = __expf(2.f * (acc[st][0][r] - m0));
            float e1 = __expf(2.f * (acc[st][1][r] - m1));
            acc[st][0][r] = e0; acc[st][1][r] = e1;
            s0 += e0; s1 += e1;
        }
    s0 += __shfl_xor(s0, 16); s0 += __shfl_xor(s0, 32);
    s1 += __shfl_xor(s1, 16); s1 += __shfl_xor(s1, 32);
    float i0 = 1.f / s0, i1 = 1.f / s1;

    int nA = n0 + lc, nB = n0 + 16 + lc;
    if (!final_mode) {
#pragma unroll
        for (int st = 0; st < 16; ++st)
#pragma unroll
            for (int r = 0; r < 4; ++r) {
                int s = st * 16 + lg * 4 + r;
                qh[(size_t)s * HW + nA] = f2bf(acc[st][0][r] * i0);
                qh[(size_t)s * HW + nB] = f2bf(acc[st][1][r] * i1);
            }
    } else {
#pragma unroll
        for (int st = 0; st < 16; ++st)
#pragma unroll
            for (int r = 0; r < 4; ++r) {
                int s = st * 16 + lg * 4 + r;
                qf[(size_t)s * HW + nA] = acc[st][0][r] * i0;
                qf[(size_t)s * HW + nB] = acc[st][1][r] * i1;
            }
    }
}

// ---------------------------------------------------------------------------
// cn: cn_fin[s][c] += sum_n Q[s,n]*pf[c,n]; 2 c-tiles per wave (each qh
// fragment feeds 2 MFMAs -> half the qh traffic). 4 waves, 128-px K-chunk.
// Grid 512.
// ---------------------------------------------------------------------------
__global__ __launch_bounds__(256) void cn_kernel(
    const unsigned short* __restrict__ qh, const unsigned short* __restrict__ pfch,
    float* __restrict__ cn_fin)
{
    int t = threadIdx.x;
    int w = t >> 6, l = t & 63;
    int lc = l & 15, lg = l >> 4;
    int n0 = blockIdx.x * 128;

    f32x4 acc[16][2];
#pragma unroll
    for (int i = 0; i < 16; ++i)
#pragma unroll
        for (int ct = 0; ct < 2; ++ct)
#pragma unroll
            for (int j = 0; j < 4; ++j) acc[i][ct][j] = 0.f;

    for (int ks = 0; ks < 4; ++ks) {
        int nb = n0 + ks * 32 + 8 * lg;
        bf16x8 b0 = *(const bf16x8*)(pfch + (size_t)(w * 32 + lc) * HW + nb);
        bf16x8 b1 = *(const bf16x8*)(pfch + (size_t)(w * 32 + 16 + lc) * HW + nb);
#pragma unroll
        for (int st = 0; st < 16; ++st) {
            bf16x8 afr = *(const bf16x8*)(qh + (size_t)(st * 16 + lc) * HW + nb);
            acc[st][0] = __builtin_amdgcn_mfma_f32_16x16x32_bf16(afr, b0, acc[st][0], 0, 0, 0);
            acc[st][1] = __builtin_amdgcn_mfma_f32_16x16x32_bf16(afr, b1, acc[st][1], 0, 0, 0);
        }
    }

#pragma unroll
    for (int st = 0; st < 16; ++st)
#pragma unroll
        for (int ct = 0; ct < 2; ++ct)
#pragma unroll
            for (int r = 0; r < 4; ++r) {
                int s = st * 16 + lg * 4 + r;
                int c = w * 32 + ct * 16 + lc;
                atomicAdd(&cn_fin[s * 128 + c], acc[st][ct][r]);
            }
}

// ---------------------------------------------------------------------------
extern "C" void kernel_launch(void* const* d_in, const int* in_sizes, int n_in,
                              void* d_out, int out_size, void* d_ws, size_t ws_size,
                              hipStream_t stream)
{
    const float* x     = (const float*)d_in[0];
    const float* s1k7  = (const float*)d_in[1];
    const float* s1k5  = (const float*)d_in[2];
    const float* s1k3  = (const float*)d_in[3];
    const float* s1g   = (const float*)d_in[5];
    const float* s1be  = (const float*)d_in[6];
    const float* s2k7  = (const float*)d_in[7];
    const float* s2k5  = (const float*)d_in[8];
    const float* s2k3  = (const float*)d_in[9];
    const float* s2g   = (const float*)d_in[11];
    const float* s2be  = (const float*)d_in[12];
    const float* s3k7  = (const float*)d_in[13];
    const float* s3k5  = (const float*)d_in[14];
    const float* s3k3  = (const float*)d_in[15];
    const float* s3g   = (const float*)d_in[17];
    const float* s3be  = (const float*)d_in[18];
    const float* outw  = (const float*)d_in[19];
    const float* outb  = (const float*)d_in[20];

    float* ws = (float*)d_ws;
    size_t off = 0;
    unsigned short* wT1h = (unsigned short*)(ws + off); off += 100352;
    unsigned short* wT1l = (unsigned short*)(ws + off); off += 100352;
    unsigned short* wT2h = (unsigned short*)(ws + off); off += 25088;
    unsigned short* wT2l = (unsigned short*)(ws + off); off += 25088;
    unsigned short* wT3h = (unsigned short*)(ws + off); off += 50176;
    unsigned short* wT3l = (unsigned short*)(ws + off); off += 50176;
    float* stats = ws + off; off += 192;
    float* bn    = ws + off; off += 192;
    float* cn_fin= ws + off; off += 32768;
    unsigned short* chiT = (unsigned short*)(ws + off); off += 16384;
    unsigned short* cloT = (unsigned short*)(ws + off); off += 16384;
    unsigned short* xTh  = (unsigned short*)(ws + off); off += 4194304;
    unsigned short* xTl  = (unsigned short*)(ws + off); off += 4194304;
    unsigned short* pfch = (unsigned short*)(ws + off); off += 4194304;
    unsigned short* a12H = (unsigned short*)(ws + off); off += 2097152;
    unsigned short* a12L = (unsigned short*)(ws + off); off += 2097152;

    // d_out scratch timeline:
    //   p0 @0, p1 @8MB, ysum @16MB   (conv stages; dead before qh)
    //   a3H/L @32MB, 8MB             (stage-3 bna -> feat; dead after)
    //   qh @0, 32MB                  (dist iterations)
    //   qf @0, 64MB                  (final dist overwrites everything)
    char* ob = (char*)d_out;
    float* p0   = (float*)ob;
    float* p1   = (float*)(ob + (size_t)8 * 1024 * 1024);
    float* ysum = (float*)(ob + (size_t)16 * 1024 * 1024);
    unsigned short* qh = (unsigned short*)ob;
    float* qf = (float*)ob;
    unsigned short* a3H = (unsigned short*)(ob + (size_t)32 * 1024 * 1024);
    unsigned short* a3L = a3H + (size_t)HW * 32;

    hipMemsetAsync(stats, 0, 192 * sizeof(float), stream);
    wmerge_kernel<<<(49 * 4 * 1024 + 255) / 256, 256, 0, stream>>>(s1k7, s1k5, s1k3, 103, 4, wT1h, wT1l);
    wmerge_kernel<<<(49 * 1 * 1024 + 255) / 256, 256, 0, stream>>>(s2k7, s2k5, s2k3, 32, 1, wT2h, wT2l);
    wmerge_kernel<<<(49 * 2 * 1024 + 255) / 256, 256, 0, stream>>>(s3k7, s3k5, s3k3, 64, 2, wT3h, wT3l);

    transpose_kernel<<<1024, 256, 0, stream>>>(x, xTh, xTl, pfch);

    // stage 1: z splits ci-chunks {0,1} / {2,3}
    convm_kernel<<<dim3(512, 2), 256, 0, stream>>>(xTh, xTl, 128, wT1h, wT1l, 4,
                                                   0, 2, 0, 49, 2, 4, 0, 49, p0);
    reduce2_kernel<<<1024, 256, 0, stream>>>(p0, p1, ysum, stats + 0, stats + 32);
    bnp_kernel<<<1, 32, 0, stream>>>(stats + 0, stats + 32, s1g, s1be, bn + 0, bn + 32);
    bna_kernel<<<1024, 256, 0, stream>>>(ysum, bn + 0, bn + 32, a12H, a12L, 64, 0);

    // stage 2: z splits taps [0,25) / [25,49)
    convm_kernel<<<dim3(512, 2), 256, 0, stream>>>(a12H, a12L, 64, wT2h, wT2l, 1,
                                                   0, 1, 0, 25, 0, 1, 25, 49, p0);
    reduce2_kernel<<<1024, 256, 0, stream>>>(p0, p1, ysum, stats + 64, stats + 96);
    bnp_kernel<<<1, 32, 0, stream>>>(stats + 64, stats + 96, s2g, s2be, bn + 64, bn + 96);
    bna_kernel<<<1024, 256, 0, stream>>>(ysum, bn + 64, bn + 96, a12H, a12L, 64, 32);

    // stage 3: z splits ci-chunks {0} / {1}
    convm_kernel<<<dim3(512, 2), 256, 0, stream>>>(a12H, a12L, 64, wT3h, wT3l, 2,
                                                   0, 1, 0, 49, 1, 2, 0, 49, p0);
    reduce2_kernel<<<1024, 256, 0, stream>>>(p0, p1, ysum, stats + 128, stats + 160);
    bnp_kernel<<<1, 32, 0, stream>>>(stats + 128, stats + 160, s3g, s3be, bn + 128, bn + 160);
    bna_kernel<<<1024, 256, 0, stream>>>(ysum, bn + 128, bn + 160, a3H, a3L, 32, 0);

    feat_kernel<<<256, 256, 0, stream>>>(a12H, a12L, a3H, a3L, outw, outb, xTh, xTl, pfch);
    c0_kernel<<<256, 256, 0, stream>>>(xTh, xTl, cn_fin);
    prep_kernel<<<256, 128, 0, stream>>>(cn_fin, chiT, cloT, 1.f / 256.f, 0);

    for (int it = 0; it < 5; ++it) {
        dist_kernel<<<512, 256, 0, stream>>>(chiT, cloT, xTh, xTl, qh, qf, 0);
        hipMemsetAsync(cn_fin, 0, 32768 * sizeof(float), stream);
        cn_kernel<<<512, 256, 0, stream>>>(qh, pfch, cn_fin);
        prep_kernel<<<256, 128, 0, stream>>>(cn_fin, chiT, cloT, 0.f, 1);
    }
    dist_kernel<<<512, 256, 0, stream>>>(chiT, cloT, xTh, xTl, qh, qf, 1);
}

// Round 9
// 942.546 us; speedup vs baseline: 1.5351x; 1.1890x over previous
//
#include <hip/hip_runtime.h>

#define HW 65536

typedef short bf16x8 __attribute__((ext_vector_type(8)));
typedef float f32x4 __attribute__((ext_vector_type(4)));
typedef unsigned short u16x8 __attribute__((ext_vector_type(8)));

__device__ inline unsigned short f2bf(float v) {
    unsigned u = __float_as_uint(v);
    unsigned r = (u + 0x7FFF + ((u >> 16) & 1)) >> 16;
    return (unsigned short)r;
}
__device__ inline float ubf(unsigned short h) {
    return __uint_as_float(((unsigned)h) << 16);
}
__device__ inline uint4 pack8(const unsigned short* p) {
    uint4 u;
    u.x = (unsigned)p[0] | ((unsigned)p[1] << 16);
    u.y = (unsigned)p[2] | ((unsigned)p[3] << 16);
    u.z = (unsigned)p[4] | ((unsigned)p[5] << 16);
    u.w = (unsigned)p[6] | ((unsigned)p[7] << 16);
    return u;
}

// ---------------------------------------------------------------------------
// Merge 7/5/3 kernels into one 7x7; emit bf16 hi/lo in A-FRAGMENT LANE ORDER:
// elem index = ((tap*nch + chunk)*2 + octile)*512 + lane*8 + e
// where oc = octile*16 + (lane&15), ci = chunk*32 + (lane>>4)*8 + e.
// ---------------------------------------------------------------------------
__global__ void wmerge_kernel(const float* __restrict__ k7, const float* __restrict__ k5,
                              const float* __restrict__ k3, int Cin, int nch,
                              unsigned short* __restrict__ wTh, unsigned short* __restrict__ wTl)
{
    int idx = blockIdx.x * 256 + threadIdx.x;
    int total = 49 * nch * 1024;
    if (idx >= total) return;
    int e = idx & 7;
    int lane = (idx >> 3) & 63;
    int octile = (idx >> 9) & 1;
    int chunk = (idx >> 10) % nch;
    int tap = idx / (nch << 10);
    int oc = octile * 16 + (lane & 15);
    int ci = chunk * 32 + (lane >> 4) * 8 + e;
    int ky = tap / 7, kx = tap % 7;
    float v = 0.f;
    if (ci < Cin) {
        v = k7[(oc * Cin + ci) * 49 + tap];
        if (ky >= 1 && ky <= 5 && kx >= 1 && kx <= 5)
            v += k5[(oc * Cin + ci) * 25 + (ky - 1) * 5 + (kx - 1)];
        if (ky >= 2 && ky <= 4 && kx >= 2 && kx <= 4)
            v += k3[(oc * Cin + ci) * 9 + (ky - 2) * 3 + (kx - 2)];
    }
    unsigned short h = f2bf(v);
    wTh[idx] = h;
    wTl[idx] = f2bf(v - ubf(h));
}

// ---------------------------------------------------------------------------
// x [103][HW] fp32 -> xT [n][128] bf16 hi/lo and pfch [c][HW] bf16 hi
// ---------------------------------------------------------------------------
__global__ __launch_bounds__(256) void transpose_kernel(
    const float* __restrict__ x,
    unsigned short* __restrict__ xTh, unsigned short* __restrict__ xTl,
    unsigned short* __restrict__ pfch)
{
    __shared__ float buf[64 * 105];
    int t = threadIdx.x;
    int px0 = blockIdx.x * 64;
    for (int i = t; i < 103 * 64; i += 256) {
        int c = i >> 6, lane = i & 63;
        float v = x[(size_t)c * HW + px0 + lane];
        buf[lane * 105 + c] = v;
        pfch[(size_t)c * HW + px0 + lane] = f2bf(v);
    }
    __syncthreads();
    int px = t >> 2, seg = t & 3;
    unsigned short h[32], l[32];
#pragma unroll
    for (int j = 0; j < 32; ++j) {
        int c = seg * 32 + j;
        float v = (c < 103) ? buf[px * 105 + c] : 0.f;
        h[j] = f2bf(v);
        l[j] = f2bf(v - ubf(h[j]));
    }
    size_t base = (size_t)(px0 + px) * 128 + seg * 32;
#pragma unroll
    for (int k = 0; k < 4; ++k) {
        *(uint4*)(xTh + base + k * 8) = pack8(h + k * 8);
        *(uint4*)(xTl + base + k * 8) = pack8(l + k * 8);
    }
}

// ---------------------------------------------------------------------------
// Implicit-GEMM 7x7 conv, MFMA 16x16x32 bf16, 3-phase hi/lo.
// Weights staged in LDS in 3-tap groups (12 KB) -> total LDS 50.5 KB ->
// 3 blocks/CU (vs 2 at 7-tap). Work split across blockIdx.y (z=2).
// Block: 256 thr = 4 waves; wave: 2 y-rows x 16 px x 32 oc.
// ---------------------------------------------------------------------------
__global__ __launch_bounds__(256) void convm_kernel(
    const unsigned short* __restrict__ actH, const unsigned short* __restrict__ actL,
    int Cs,
    const unsigned short* __restrict__ wTh, const unsigned short* __restrict__ wTl,
    int nchw,
    int c0a, int c1a, int t0a, int t1a,
    int c0b, int c1b, int t0b, int t1b,
    float* __restrict__ ypart)
{
    __shared__ __align__(16) unsigned short sH[14 * 704];
    __shared__ __align__(16) unsigned short sL[14 * 704];
    __shared__ __align__(16) unsigned short sW[3 * 2048];
    int t = threadIdx.x;
    int w = t >> 6, l = t & 63;
    int lc = l & 15, lg = l >> 4;
    int bx = blockIdx.x & 15, byy = blockIdx.x >> 4;
    int x0 = bx * 16, y0 = byy * 8;
    int z = blockIdx.y;
    int ch0 = z ? c0b : c0a, ch1 = z ? c1b : c1a;
    int tap0 = z ? t0b : t0a, tap1 = z ? t1b : t1a;
    float* yp = ypart + (size_t)z * 32 * HW;

    f32x4 a_hh[2][2], a_lh[2][2], a_hl[2][2];   // [oc-tile][row]
#pragma unroll
    for (int ot = 0; ot < 2; ++ot)
#pragma unroll
        for (int rr = 0; rr < 2; ++rr)
#pragma unroll
            for (int r = 0; r < 4; ++r) {
                a_hh[ot][rr][r] = 0.f; a_lh[ot][rr][r] = 0.f; a_hl[ot][rr][r] = 0.f;
            }

    for (int ch = ch0; ch < ch1; ++ch) {
        int ci0 = ch * 32;
        __syncthreads();                // protect sH/sL from prior reads
        for (int i = t; i < 2464; i += 256) {
            int pl = (i >= 1232) ? 1 : 0;
            int j = pl ? i - 1232 : i;
            int row = j / 88;
            int rem = j - row * 88;
            int px = rem >> 2, q = rem & 3;
            int gy = y0 - 3 + row, gx = x0 - 3 + px;
            uint4 v = {0u, 0u, 0u, 0u};
            if (gy >= 0 && gy < 256 && gx >= 0 && gx < 256) {
                const unsigned short* src = pl ? actL : actH;
                v = *(const uint4*)(src + (size_t)(gy * 256 + gx) * Cs + ci0 + q * 8);
            }
            unsigned short* dst = pl ? sL : sH;
            *(uint4*)(dst + row * 704 + q * 176 + px * 8) = v;
        }

        for (int g = tap0; g < tap1; g += 3) {
            int ge = g + 3; if (ge > tap1) ge = tap1;
            if (g > tap0) __syncthreads();      // protect sW from prior group reads
            for (int i = t; i < (ge - g) * 256; i += 256) {
                int tp = i >> 8, r = i & 255;
                const unsigned short* src = (r < 128) ? wTh : wTl;
                *(uint4*)(sW + tp * 2048 + r * 8) =
                    *(const uint4*)(src + ((size_t)((g + tp) * nchw + ch)) * 1024 + (r & 127) * 8);
            }
            __syncthreads();

            for (int tap = g; tap < ge; ++tap) {
                const unsigned short* wb = sW + (tap - g) * 2048 + l * 8;
                bf16x8 ah0 = *(const bf16x8*)(wb);
                bf16x8 ah1 = *(const bf16x8*)(wb + 512);
                bf16x8 al0 = *(const bf16x8*)(wb + 1024);
                bf16x8 al1 = *(const bf16x8*)(wb + 1536);
                int ky = tap / 7;
                int kx = tap - ky * 7;
                bf16x8 xh[2], xl[2];
#pragma unroll
                for (int rr = 0; rr < 2; ++rr) {
                    int off = (w * 2 + rr + ky) * 704 + lg * 176 + (lc + kx) * 8;
                    xh[rr] = *(const bf16x8*)(sH + off);
                    xl[rr] = *(const bf16x8*)(sL + off);
                }
#pragma unroll
                for (int rr = 0; rr < 2; ++rr) {
                    a_hh[0][rr] = __builtin_amdgcn_mfma_f32_16x16x32_bf16(ah0, xh[rr], a_hh[0][rr], 0, 0, 0);
                    a_hh[1][rr] = __builtin_amdgcn_mfma_f32_16x16x32_bf16(ah1, xh[rr], a_hh[1][rr], 0, 0, 0);
                    a_lh[0][rr] = __builtin_amdgcn_mfma_f32_16x16x32_bf16(al0, xh[rr], a_lh[0][rr], 0, 0, 0);
                    a_lh[1][rr] = __builtin_amdgcn_mfma_f32_16x16x32_bf16(al1, xh[rr], a_lh[1][rr], 0, 0, 0);
                    a_hl[0][rr] = __builtin_amdgcn_mfma_f32_16x16x32_bf16(ah0, xl[rr], a_hl[0][rr], 0, 0, 0);
                    a_hl[1][rr] = __builtin_amdgcn_mfma_f32_16x16x32_bf16(ah1, xl[rr], a_hl[1][rr], 0, 0, 0);
                }
            }
        }
    }

#pragma unroll
    for (int ot = 0; ot < 2; ++ot)
#pragma unroll
        for (int rr = 0; rr < 2; ++rr) {
            int n = (y0 + w * 2 + rr) * 256 + x0 + lc;
#pragma unroll
            for (int r = 0; r < 4; ++r) {
                int oc = ot * 16 + lg * 4 + r;
                yp[(size_t)oc * HW + n] = a_hh[ot][rr][r] + a_lh[ot][rr][r] + a_hl[ot][rr][r];
            }
        }
}

// ---------------------------------------------------------------------------
// Sum 2 partial planes -> ysum, with fused per-channel sum/sumsq stats.
// ---------------------------------------------------------------------------
__global__ __launch_bounds__(256) void reduce2_kernel(
    const float* __restrict__ p0, const float* __restrict__ p1,
    float* __restrict__ y, float* __restrict__ ssum, float* __restrict__ ssq)
{
    int c = blockIdx.x >> 5, seg = blockIdx.x & 31;
    int base = c * HW + seg * 2048 + threadIdx.x * 8;
    float s = 0.f, q = 0.f;
#pragma unroll
    for (int h = 0; h < 2; ++h) {
        int o = base + h * 4;
        float4 a0 = *(const float4*)&p0[o];
        float4 a1 = *(const float4*)&p1[o];
        float4 v;
        v.x = a0.x + a1.x; v.y = a0.y + a1.y;
        v.z = a0.z + a1.z; v.w = a0.w + a1.w;
        *(float4*)&y[o] = v;
        s += v.x + v.y + v.z + v.w;
        q = fmaf(v.x, v.x, q); q = fmaf(v.y, v.y, q);
        q = fmaf(v.z, v.z, q); q = fmaf(v.w, v.w, q);
    }
#pragma unroll
    for (int d = 32; d >= 1; d >>= 1) {
        s += __shfl_down(s, d);
        q += __shfl_down(q, d);
    }
    __shared__ float ls[4], lq[4];
    int w = threadIdx.x >> 6;
    if ((threadIdx.x & 63) == 0) { ls[w] = s; lq[w] = q; }
    __syncthreads();
    if (threadIdx.x == 0) {
        atomicAdd(&ssum[c], ls[0] + ls[1] + ls[2] + ls[3]);
        atomicAdd(&ssq[c], lq[0] + lq[1] + lq[2] + lq[3]);
    }
}

__global__ void bnp_kernel(const float* __restrict__ ssum, const float* __restrict__ ssq,
                           const float* __restrict__ g, const float* __restrict__ beta,
                           float* __restrict__ scl, float* __restrict__ shf)
{
    int c = threadIdx.x;
    float mu  = ssum[c] * (1.f / 65536.f);
    float var = ssq[c] * (1.f / 65536.f) - mu * mu;
    float s = g[c] * rsqrtf(var + 1e-5f);
    scl[c] = s;
    shf[c] = beta[c] - mu * s;
}

// ---------------------------------------------------------------------------
// BN + ReLU + write channel-last bf16 hi/lo
// ---------------------------------------------------------------------------
__global__ __launch_bounds__(256) void bna_kernel(
    const float* __restrict__ yraw, const float* __restrict__ scl, const float* __restrict__ shf,
    unsigned short* __restrict__ aH, unsigned short* __restrict__ aL, int Cs, int slot0)
{
    int t = threadIdx.x;
    int lane = t & 63, cg = t >> 6;
    int px = blockIdx.x * 64 + lane;
    unsigned short h[8], l[8];
#pragma unroll
    for (int j = 0; j < 8; ++j) {
        int c = cg * 8 + j;
        float v = fmaxf(yraw[(size_t)c * HW + px] * scl[c] + shf[c], 0.f);
        h[j] = f2bf(v);
        l[j] = f2bf(v - ubf(h[j]));
    }
    *(uint4*)(aH + (size_t)px * Cs + slot0 + cg * 8) = pack8(h);
    *(uint4*)(aL + (size_t)px * Cs + slot0 + cg * 8) = pack8(l);
}

// ---------------------------------------------------------------------------
// 1x1 conv (96->15) + ReLU; writes pf slots 103..127 of xT and pfch rows
// ---------------------------------------------------------------------------
__global__ __launch_bounds__(256) void feat_kernel(
    const unsigned short* __restrict__ a12H, const unsigned short* __restrict__ a12L,
    const unsigned short* __restrict__ a3H, const unsigned short* __restrict__ a3L,
    const float* __restrict__ w, const float* __restrict__ b,
    unsigned short* __restrict__ xTh, unsigned short* __restrict__ xTl,
    unsigned short* __restrict__ pfch)
{
    int n = blockIdx.x * 256 + threadIdx.x;
    float facc[15];
#pragma unroll
    for (int oc = 0; oc < 15; ++oc) facc[oc] = b[oc];

#pragma unroll
    for (int k = 0; k < 12; ++k) {
        uint4 uh, ul;
        if (k < 8) {
            uh = *(const uint4*)(a12H + (size_t)n * 64 + k * 8);
            ul = *(const uint4*)(a12L + (size_t)n * 64 + k * 8);
        } else {
            uh = *(const uint4*)(a3H + (size_t)n * 32 + (k - 8) * 8);
            ul = *(const uint4*)(a3L + (size_t)n * 32 + (k - 8) * 8);
        }
        unsigned hw_[4] = {uh.x, uh.y, uh.z, uh.w};
        unsigned lw_[4] = {ul.x, ul.y, ul.z, ul.w};
#pragma unroll
        for (int j = 0; j < 8; ++j) {
            unsigned short hh = (unsigned short)(hw_[j >> 1] >> ((j & 1) * 16));
            unsigned short ll = (unsigned short)(lw_[j >> 1] >> ((j & 1) * 16));
            float av = ubf(hh) + ubf(ll);
#pragma unroll
            for (int oc = 0; oc < 15; ++oc)
                facc[oc] = fmaf(av, w[oc * 96 + k * 8 + j], facc[oc]);
        }
    }
    unsigned short fh[16], fl[16];
#pragma unroll
    for (int oc = 0; oc < 15; ++oc) {
        float v = fmaxf(facc[oc], 0.f);
        fh[oc] = f2bf(v);
        fl[oc] = f2bf(v - ubf(fh[oc]));
    }
    fh[15] = 0; fl[15] = 0;

    size_t base = (size_t)n * 128;
    uint4 h0 = *(const uint4*)(xTh + base + 96);
    uint4 l0 = *(const uint4*)(xTl + base + 96);
    h0.w = (h0.w & 0xFFFFu) | ((unsigned)fh[0] << 16);
    l0.w = (l0.w & 0xFFFFu) | ((unsigned)fl[0] << 16);
    *(uint4*)(xTh + base + 96) = h0;
    *(uint4*)(xTl + base + 96) = l0;
    *(uint4*)(xTh + base + 104) = pack8(fh + 1);
    *(uint4*)(xTl + base + 104) = pack8(fl + 1);
    unsigned short t2h[8], t2l[8];
#pragma unroll
    for (int j = 0; j < 8; ++j) {
        t2h[j] = (j < 6) ? fh[9 + j] : (unsigned short)0;
        t2l[j] = (j < 6) ? fl[9 + j] : (unsigned short)0;
    }
    *(uint4*)(xTh + base + 112) = pack8(t2h);
    *(uint4*)(xTl + base + 112) = pack8(t2l);
    unsigned short t3h[8] = {0, 0, 0, 0, 0, 0, 0, 0x3F80};
    unsigned short t3l[8] = {0, 0, 0, 0, 0, 0, 0, 0};
    *(uint4*)(xTh + base + 120) = pack8(t3h);
    *(uint4*)(xTl + base + 120) = pack8(t3l);

#pragma unroll
    for (int k2 = 0; k2 < 15; ++k2)
        pfch[(size_t)(103 + k2) * HW + n] = fh[k2];
    pfch[(size_t)118 * HW + n] = 0x3F80;
#pragma unroll
    for (int c = 119; c < 128; ++c)
        pfch[(size_t)c * HW + n] = 0;
}

// ---------------------------------------------------------------------------
// c0: per-superpixel channel sums -> cn_fin[s][128]
// ---------------------------------------------------------------------------
__global__ __launch_bounds__(256) void c0_kernel(
    const unsigned short* __restrict__ pfTh, const unsigned short* __restrict__ pfTl,
    float* __restrict__ cn_fin)
{
    int s = blockIdx.x;
    int sy = s >> 4, sx = s & 15;
    int t = threadIdx.x;
    int xx = t >> 4;
    int cs = (t & 15) * 8;

    float acc[8];
#pragma unroll
    for (int j = 0; j < 8; ++j) acc[j] = 0.f;

    for (int yy = 0; yy < 16; ++yy) {
        int n = (sy * 16 + yy) * 256 + sx * 16 + xx;
        u16x8 h = *(const u16x8*)(pfTh + (size_t)n * 128 + cs);
        u16x8 l = *(const u16x8*)(pfTl + (size_t)n * 128 + cs);
#pragma unroll
        for (int j = 0; j < 8; ++j)
            acc[j] += ubf(h[j]) + ubf(l[j]);
    }
#pragma unroll
    for (int j = 0; j < 8; ++j) {
        acc[j] += __shfl_xor(acc[j], 16);
        acc[j] += __shfl_xor(acc[j], 32);
    }
    __shared__ float red[4][128];
    int w = t >> 6;
    if ((t & 63) < 16) {
#pragma unroll
        for (int j = 0; j < 8; ++j)
            red[w][(t & 15) * 8 + j] = acc[j];
    }
    __syncthreads();
    if (t < 128)
        cn_fin[s * 128 + t] = red[0][t] + red[1][t] + red[2][t] + red[3][t];
}

// ---------------------------------------------------------------------------
// prep: centroids -> chiT/cloT [s][128]; slot 127 = -0.5*|c|^2
// ---------------------------------------------------------------------------
__global__ __launch_bounds__(128) void prep_kernel(
    const float* __restrict__ cn_fin,
    unsigned short* __restrict__ chiT, unsigned short* __restrict__ cloT,
    float scale0, int use_qsum)
{
    int s = blockIdx.x, c = threadIdx.x;
    float inv = use_qsum ? 1.f / (cn_fin[s * 128 + 118] + 1e-8f) : scale0;
    float v = (c < 118) ? cn_fin[s * 128 + c] * inv : 0.f;
    float a = v * v;
#pragma unroll
    for (int d = 1; d < 64; d <<= 1) a += __shfl_xor(a, d);
    __shared__ float red[2];
    if ((c & 63) == 0) red[c >> 6] = a;
    __syncthreads();
    float tot = red[0] + red[1];
    unsigned short h, lo;
    if (c == 127) {
        float m2 = -0.5f * tot;
        h = f2bf(m2);
        lo = f2bf(m2 - ubf(h));
    } else {
        h = f2bf(v);
        lo = f2bf(v - ubf(h));
    }
    chiT[s * 128 + c] = h;
    cloT[s * 128 + c] = lo;
}

// ---------------------------------------------------------------------------
// FUSED dist+cn. Phase 1: Q = softmax_s(2*(cent.pf - 0.5|c|^2)) (3-phase
// hi/lo MFMA, 32 px/wave). Phase 2: Q -> LDS in cn-A-fragment order.
// Phase 3: cn_fin[s][c] += Q^T-GEMM over the block's 128 px (atomics).
// final_mode: write fp32 Q to qf and skip phases 2/3.
// Block 256 thr = 4 waves = 128 px. Grid 512. LDS 64 KB -> 2 blocks/CU.
// ---------------------------------------------------------------------------
__global__ __launch_bounds__(256) void distcn_kernel(
    const unsigned short* __restrict__ chiT, const unsigned short* __restrict__ cloT,
    const unsigned short* __restrict__ pfTh, const unsigned short* __restrict__ pfTl,
    const unsigned short* __restrict__ pfch,
    float* __restrict__ cn_fin, float* __restrict__ qf, int final_mode)
{
    __shared__ __align__(16) unsigned short sQ[32768];  // [st][kc][lane][8]
    int t = threadIdx.x;
    int w = t >> 6, l = t & 63;
    int lc = l & 15, lg = l >> 4;
    int nblk = blockIdx.x * 128;
    int n0 = nblk + w * 32;

    f32x4 acc[16][2];
#pragma unroll
    for (int i = 0; i < 16; ++i)
#pragma unroll
        for (int g = 0; g < 2; ++g)
#pragma unroll
            for (int j = 0; j < 4; ++j) acc[i][g][j] = 0.f;

#pragma unroll
    for (int phse = 0; phse < 3; ++phse) {
        const unsigned short* Ap = (phse == 1) ? cloT : chiT;
        const unsigned short* Bp = (phse == 2) ? pfTl : pfTh;
#pragma unroll
        for (int ks = 0; ks < 4; ++ks) {
            int kb = ks * 32 + 8 * lg;
            bf16x8 b0 = *(const bf16x8*)(Bp + (size_t)(n0 + lc) * 128 + kb);
            bf16x8 b1 = *(const bf16x8*)(Bp + (size_t)(n0 + 16 + lc) * 128 + kb);
#pragma unroll
            for (int st = 0; st < 16; ++st) {
                bf16x8 afr = *(const bf16x8*)(Ap + (size_t)(st * 16 + lc) * 128 + kb);
                acc[st][0] = __builtin_amdgcn_mfma_f32_16x16x32_bf16(afr, b0, acc[st][0], 0, 0, 0);
                acc[st][1] = __builtin_amdgcn_mfma_f32_16x16x32_bf16(afr, b1, acc[st][1], 0, 0, 0);
            }
        }
    }

    float m0 = -1e30f, m1 = -1e30f;
#pragma unroll
    for (int st = 0; st < 16; ++st)
#pragma unroll
        for (int r = 0; r < 4; ++r) {
            m0 = fmaxf(m0, acc[st][0][r]);
            m1 = fmaxf(m1, acc[st][1][r]);
        }
    m0 = fmaxf(m0, __shfl_xor(m0, 16)); m0 = fmaxf(m0, __shfl_xor(m0, 32));
    m1 = fmaxf(m1, __shfl_xor(m1, 16)); m1 = fmaxf(m1, __shfl_xor(m1, 32));

    float s0 = 0.f, s1 = 0.f;
#pragma unroll
    for (int st = 0; st < 16; ++st)
#pragma unroll
        for (int r = 0; r < 4; ++r) {
            float e0 = __expf(2.f * (acc[st][0][r] - m0));
            float e1 = __expf(2.f * (acc[st][1][r] - m1));
            acc[st][0][r] = e0; acc[st][1][r] = e1;
            s0 += e0; s1 += e1;
        }
    s0 += __shfl_xor(s0, 16); s0 += __shfl_xor(s0, 32);
    s1 += __shfl_xor(s1, 16); s1 += __shfl_xor(s1, 32);
    float i0 = 1.f / s0, i1 = 1.f / s1;

    if (final_mode) {
        int nA = n0 + lc, nB = n0 + 16 + lc;
#pragma unroll
        for (int st = 0; st < 16; ++st)
#pragma unroll
            for (int r = 0; r < 4; ++r) {
                int s = st * 16 + lg * 4 + r;
                qf[(size_t)s * HW + nA] = acc[st][0][r] * i0;
                qf[(size_t)s * HW + nB] = acc[st][1][r] * i1;
            }
        return;
    }

    // phase 2: Q (bf16) -> LDS in cn-A-fragment order.
    // value (s = st*16+lg*4+r, n_blk = w*32+g*16+lc) goes to
    // idx = ((st*4 + w)*64 + (g*2+(lc>>3))*16 + lg*4 + r)*8 + (lc&7)
#pragma unroll
    for (int st = 0; st < 16; ++st)
#pragma unroll
        for (int g = 0; g < 2; ++g) {
            float iv = g ? i1 : i0;
#pragma unroll
            for (int r = 0; r < 4; ++r) {
                int idx = ((st * 4 + w) * 64 + (g * 2 + (lc >> 3)) * 16 + lg * 4 + r) * 8 + (lc & 7);
                sQ[idx] = f2bf(acc[st][g][r] * iv);
            }
        }
    __syncthreads();

    // phase 3: wave w covers c in [w*32, w*32+32); k over the block's 128 px
    f32x4 a2[16][2];
#pragma unroll
    for (int i = 0; i < 16; ++i)
#pragma unroll
        for (int ct = 0; ct < 2; ++ct)
#pragma unroll
            for (int j = 0; j < 4; ++j) a2[i][ct][j] = 0.f;

#pragma unroll
    for (int kc = 0; kc < 4; ++kc) {
        int nb = nblk + kc * 32 + 8 * lg;
        bf16x8 b0 = *(const bf16x8*)(pfch + (size_t)(w * 32 + lc) * HW + nb);
        bf16x8 b1 = *(const bf16x8*)(pfch + (size_t)(w * 32 + 16 + lc) * HW + nb);
#pragma unroll
        for (int st = 0; st < 16; ++st) {
            bf16x8 afr = *(const bf16x8*)(sQ + ((size_t)(st * 4 + kc) * 64 + l) * 8);
            a2[st][0] = __builtin_amdgcn_mfma_f32_16x16x32_bf16(afr, b0, a2[st][0], 0, 0, 0);
            a2[st][1] = __builtin_amdgcn_mfma_f32_16x16x32_bf16(afr, b1, a2[st][1], 0, 0, 0);
        }
    }

#pragma unroll
    for (int st = 0; st < 16; ++st)
#pragma unroll
        for (int ct = 0; ct < 2; ++ct)
#pragma unroll
            for (int r = 0; r < 4; ++r) {
                int s = st * 16 + lg * 4 + r;
                int c = w * 32 + ct * 16 + lc;
                atomicAdd(&cn_fin[s * 128 + c], a2[st][ct][r]);
            }
}

// ---------------------------------------------------------------------------
extern "C" void kernel_launch(void* const* d_in, const int* in_sizes, int n_in,
                              void* d_out, int out_size, void* d_ws, size_t ws_size,
                              hipStream_t stream)
{
    const float* x     = (const float*)d_in[0];
    const float* s1k7  = (const float*)d_in[1];
    const float* s1k5  = (const float*)d_in[2];
    const float* s1k3  = (const float*)d_in[3];
    const float* s1g   = (const float*)d_in[5];
    const float* s1be  = (const float*)d_in[6];
    const float* s2k7  = (const float*)d_in[7];
    const float* s2k5  = (const float*)d_in[8];
    const float* s2k3  = (const float*)d_in[9];
    const float* s2g   = (const float*)d_in[11];
    const float* s2be  = (const float*)d_in[12];
    const float* s3k7  = (const float*)d_in[13];
    const float* s3k5  = (const float*)d_in[14];
    const float* s3k3  = (const float*)d_in[15];
    const float* s3g   = (const float*)d_in[17];
    const float* s3be  = (const float*)d_in[18];
    const float* outw  = (const float*)d_in[19];
    const float* outb  = (const float*)d_in[20];

    float* ws = (float*)d_ws;
    size_t off = 0;
    unsigned short* wT1h = (unsigned short*)(ws + off); off += 100352;
    unsigned short* wT1l = (unsigned short*)(ws + off); off += 100352;
    unsigned short* wT2h = (unsigned short*)(ws + off); off += 25088;
    unsigned short* wT2l = (unsigned short*)(ws + off); off += 25088;
    unsigned short* wT3h = (unsigned short*)(ws + off); off += 50176;
    unsigned short* wT3l = (unsigned short*)(ws + off); off += 50176;
    float* stats = ws + off; off += 192;
    float* bn    = ws + off; off += 192;
    float* cn_fin= ws + off; off += 32768;
    unsigned short* chiT = (unsigned short*)(ws + off); off += 16384;
    unsigned short* cloT = (unsigned short*)(ws + off); off += 16384;
    unsigned short* xTh  = (unsigned short*)(ws + off); off += 4194304;
    unsigned short* xTl  = (unsigned short*)(ws + off); off += 4194304;
    unsigned short* pfch = (unsigned short*)(ws + off); off += 4194304;
    unsigned short* a12H = (unsigned short*)(ws + off); off += 2097152;
    unsigned short* a12L = (unsigned short*)(ws + off); off += 2097152;

    // d_out scratch timeline:
    //   p0 @0, p1 @8MB, ysum @16MB   (conv stages; dead before final)
    //   a3H/L @32MB, 8MB             (stage-3 bna -> feat; dead after)
    //   qf @0, 64MB                  (final distcn overwrites everything)
    char* ob = (char*)d_out;
    float* p0   = (float*)ob;
    float* p1   = (float*)(ob + (size_t)8 * 1024 * 1024);
    float* ysum = (float*)(ob + (size_t)16 * 1024 * 1024);
    float* qf = (float*)ob;
    unsigned short* a3H = (unsigned short*)(ob + (size_t)32 * 1024 * 1024);
    unsigned short* a3L = a3H + (size_t)HW * 32;

    hipMemsetAsync(stats, 0, 192 * sizeof(float), stream);
    wmerge_kernel<<<(49 * 4 * 1024 + 255) / 256, 256, 0, stream>>>(s1k7, s1k5, s1k3, 103, 4, wT1h, wT1l);
    wmerge_kernel<<<(49 * 1 * 1024 + 255) / 256, 256, 0, stream>>>(s2k7, s2k5, s2k3, 32, 1, wT2h, wT2l);
    wmerge_kernel<<<(49 * 2 * 1024 + 255) / 256, 256, 0, stream>>>(s3k7, s3k5, s3k3, 64, 2, wT3h, wT3l);

    transpose_kernel<<<1024, 256, 0, stream>>>(x, xTh, xTl, pfch);

    // stage 1: z splits ci-chunks {0,1} / {2,3}
    convm_kernel<<<dim3(512, 2), 256, 0, stream>>>(xTh, xTl, 128, wT1h, wT1l, 4,
                                                   0, 2, 0, 49, 2, 4, 0, 49, p0);
    reduce2_kernel<<<1024, 256, 0, stream>>>(p0, p1, ysum, stats + 0, stats + 32);
    bnp_kernel<<<1, 32, 0, stream>>>(stats + 0, stats + 32, s1g, s1be, bn + 0, bn + 32);
    bna_kernel<<<1024, 256, 0, stream>>>(ysum, bn + 0, bn + 32, a12H, a12L, 64, 0);

    // stage 2: z splits taps [0,25) / [25,49)
    convm_kernel<<<dim3(512, 2), 256, 0, stream>>>(a12H, a12L, 64, wT2h, wT2l, 1,
                                                   0, 1, 0, 25, 0, 1, 25, 49, p0);
    reduce2_kernel<<<1024, 256, 0, stream>>>(p0, p1, ysum, stats + 64, stats + 96);
    bnp_kernel<<<1, 32, 0, stream>>>(stats + 64, stats + 96, s2g, s2be, bn + 64, bn + 96);
    bna_kernel<<<1024, 256, 0, stream>>>(ysum, bn + 64, bn + 96, a12H, a12L, 64, 32);

    // stage 3: z splits ci-chunks {0} / {1}
    convm_kernel<<<dim3(512, 2), 256, 0, stream>>>(a12H, a12L, 64, wT3h, wT3l, 2,
                                                   0, 1, 0, 49, 1, 2, 0, 49, p0);
    reduce2_kernel<<<1024, 256, 0, stream>>>(p0, p1, ysum, stats + 128, stats + 160);
    bnp_kernel<<<1, 32, 0, stream>>>(stats + 128, stats + 160, s3g, s3be, bn + 128, bn + 160);
    bna_kernel<<<1024, 256, 0, stream>>>(ysum, bn + 128, bn + 160, a3H, a3L, 32, 0);

    feat_kernel<<<256, 256, 0, stream>>>(a12H, a12L, a3H, a3L, outw, outb, xTh, xTl, pfch);
    c0_kernel<<<256, 256, 0, stream>>>(xTh, xTl, cn_fin);
    prep_kernel<<<256, 128, 0, stream>>>(cn_fin, chiT, cloT, 1.f / 256.f, 0);

    for (int it = 0; it < 5; ++it) {
        hipMemsetAsync(cn_fin, 0, 32768 * sizeof(float), stream);
        distcn_kernel<<<512, 256, 0, stream>>>(chiT, cloT, xTh, xTl, pfch, cn_fin, qf, 0);
        prep_kernel<<<256, 128, 0, stream>>>(cn_fin, chiT, cloT, 0.f, 1);
    }
    distcn_kernel<<<512, 256, 0, stream>>>(chiT, cloT, xTh, xTl, pfch, cn_fin, qf, 1);
}

// Round 10
// 802.807 us; speedup vs baseline: 1.8023x; 1.1741x over previous
//
#include <hip/hip_runtime.h>

#define HW 65536

typedef short bf16x8 __attribute__((ext_vector_type(8)));
typedef float f32x4 __attribute__((ext_vector_type(4)));
typedef unsigned short u16x8 __attribute__((ext_vector_type(8)));

__device__ inline unsigned short f2bf(float v) {
    unsigned u = __float_as_uint(v);
    unsigned r = (u + 0x7FFF + ((u >> 16) & 1)) >> 16;
    return (unsigned short)r;
}
__device__ inline float ubf(unsigned short h) {
    return __uint_as_float(((unsigned)h) << 16);
}
__device__ inline uint4 pack8(const unsigned short* p) {
    uint4 u;
    u.x = (unsigned)p[0] | ((unsigned)p[1] << 16);
    u.y = (unsigned)p[2] | ((unsigned)p[3] << 16);
    u.z = (unsigned)p[4] | ((unsigned)p[5] << 16);
    u.w = (unsigned)p[6] | ((unsigned)p[7] << 16);
    return u;
}

// ---------------------------------------------------------------------------
// Merge 7/5/3 kernels into one 7x7; emit bf16 hi/lo in A-FRAGMENT LANE ORDER.
// ---------------------------------------------------------------------------
__global__ void wmerge_kernel(const float* __restrict__ k7, const float* __restrict__ k5,
                              const float* __restrict__ k3, int Cin, int nch,
                              unsigned short* __restrict__ wTh, unsigned short* __restrict__ wTl)
{
    int idx = blockIdx.x * 256 + threadIdx.x;
    int total = 49 * nch * 1024;
    if (idx >= total) return;
    int e = idx & 7;
    int lane = (idx >> 3) & 63;
    int octile = (idx >> 9) & 1;
    int chunk = (idx >> 10) % nch;
    int tap = idx / (nch << 10);
    int oc = octile * 16 + (lane & 15);
    int ci = chunk * 32 + (lane >> 4) * 8 + e;
    int ky = tap / 7, kx = tap % 7;
    float v = 0.f;
    if (ci < Cin) {
        v = k7[(oc * Cin + ci) * 49 + tap];
        if (ky >= 1 && ky <= 5 && kx >= 1 && kx <= 5)
            v += k5[(oc * Cin + ci) * 25 + (ky - 1) * 5 + (kx - 1)];
        if (ky >= 2 && ky <= 4 && kx >= 2 && kx <= 4)
            v += k3[(oc * Cin + ci) * 9 + (ky - 2) * 3 + (kx - 2)];
    }
    unsigned short h = f2bf(v);
    wTh[idx] = h;
    wTl[idx] = f2bf(v - ubf(h));
}

// ---------------------------------------------------------------------------
// x [103][HW] fp32 -> xT [n][128] bf16 hi/lo and pfch [c][HW] bf16 hi
// ---------------------------------------------------------------------------
__global__ __launch_bounds__(256) void transpose_kernel(
    const float* __restrict__ x,
    unsigned short* __restrict__ xTh, unsigned short* __restrict__ xTl,
    unsigned short* __restrict__ pfch)
{
    __shared__ float buf[64 * 105];
    int t = threadIdx.x;
    int px0 = blockIdx.x * 64;
    for (int i = t; i < 103 * 64; i += 256) {
        int c = i >> 6, lane = i & 63;
        float v = x[(size_t)c * HW + px0 + lane];
        buf[lane * 105 + c] = v;
        pfch[(size_t)c * HW + px0 + lane] = f2bf(v);
    }
    __syncthreads();
    int px = t >> 2, seg = t & 3;
    unsigned short h[32], l[32];
#pragma unroll
    for (int j = 0; j < 32; ++j) {
        int c = seg * 32 + j;
        float v = (c < 103) ? buf[px * 105 + c] : 0.f;
        h[j] = f2bf(v);
        l[j] = f2bf(v - ubf(h[j]));
    }
    size_t base = (size_t)(px0 + px) * 128 + seg * 32;
#pragma unroll
    for (int k = 0; k < 4; ++k) {
        *(uint4*)(xTh + base + k * 8) = pack8(h + k * 8);
        *(uint4*)(xTl + base + k * 8) = pack8(l + k * 8);
    }
}

// ---------------------------------------------------------------------------
// Implicit-GEMM 7x7 conv, MFMA 16x16x32 bf16, 3-phase hi/lo.
// 4 rows per wave (16-row block tile): per tap 12 ds_read feed 24 MFMA.
// Weights in LDS 3-tap ring. Grid (256, 2) with z-split work ranges.
// ---------------------------------------------------------------------------
__global__ __launch_bounds__(256) void convm_kernel(
    const unsigned short* __restrict__ actH, const unsigned short* __restrict__ actL,
    int Cs,
    const unsigned short* __restrict__ wTh, const unsigned short* __restrict__ wTl,
    int nchw,
    int c0a, int c1a, int t0a, int t1a,
    int c0b, int c1b, int t0b, int t1b,
    float* __restrict__ ypart)
{
    __shared__ __align__(16) unsigned short sH[22 * 704];
    __shared__ __align__(16) unsigned short sL[22 * 704];
    __shared__ __align__(16) unsigned short sW[3 * 2048];
    int t = threadIdx.x;
    int w = t >> 6, l = t & 63;
    int lc = l & 15, lg = l >> 4;
    int bx = blockIdx.x & 15, byy = blockIdx.x >> 4;
    int x0 = bx * 16, y0 = byy * 16;
    int z = blockIdx.y;
    int ch0 = z ? c0b : c0a, ch1 = z ? c1b : c1a;
    int tap0 = z ? t0b : t0a, tap1 = z ? t1b : t1a;
    float* yp = ypart + (size_t)z * 32 * HW;

    f32x4 a_hh[2][4], a_lh[2][4], a_hl[2][4];   // [oc-tile][row]
#pragma unroll
    for (int ot = 0; ot < 2; ++ot)
#pragma unroll
        for (int rr = 0; rr < 4; ++rr)
#pragma unroll
            for (int r = 0; r < 4; ++r) {
                a_hh[ot][rr][r] = 0.f; a_lh[ot][rr][r] = 0.f; a_hl[ot][rr][r] = 0.f;
            }

    for (int ch = ch0; ch < ch1; ++ch) {
        int ci0 = ch * 32;
        __syncthreads();                // protect sH/sL from prior reads
        for (int i = t; i < 2 * 22 * 88; i += 256) {
            int pl = (i >= 22 * 88) ? 1 : 0;
            int j = pl ? i - 22 * 88 : i;
            int row = j / 88;
            int rem = j - row * 88;
            int px = rem >> 2, q = rem & 3;
            int gy = y0 - 3 + row, gx = x0 - 3 + px;
            uint4 v = {0u, 0u, 0u, 0u};
            if (gy >= 0 && gy < 256 && gx >= 0 && gx < 256) {
                const unsigned short* src = pl ? actL : actH;
                v = *(const uint4*)(src + (size_t)(gy * 256 + gx) * Cs + ci0 + q * 8);
            }
            unsigned short* dst = pl ? sL : sH;
            *(uint4*)(dst + row * 704 + q * 176 + px * 8) = v;
        }

        for (int g = tap0; g < tap1; g += 3) {
            int ge = g + 3; if (ge > tap1) ge = tap1;
            if (g > tap0) __syncthreads();      // protect sW from prior group reads
            for (int i = t; i < (ge - g) * 256; i += 256) {
                int tp = i >> 8, r = i & 255;
                const unsigned short* src = (r < 128) ? wTh : wTl;
                *(uint4*)(sW + tp * 2048 + r * 8) =
                    *(const uint4*)(src + ((size_t)((g + tp) * nchw + ch)) * 1024 + (r & 127) * 8);
            }
            __syncthreads();

            for (int tap = g; tap < ge; ++tap) {
                const unsigned short* wb = sW + (tap - g) * 2048 + l * 8;
                bf16x8 ah0 = *(const bf16x8*)(wb);
                bf16x8 ah1 = *(const bf16x8*)(wb + 512);
                bf16x8 al0 = *(const bf16x8*)(wb + 1024);
                bf16x8 al1 = *(const bf16x8*)(wb + 1536);
                int ky = tap / 7;
                int kx = tap - ky * 7;
#pragma unroll
                for (int rr = 0; rr < 4; ++rr) {
                    int off = (w * 4 + rr + ky) * 704 + lg * 176 + (lc + kx) * 8;
                    bf16x8 xh = *(const bf16x8*)(sH + off);
                    bf16x8 xl = *(const bf16x8*)(sL + off);
                    a_hh[0][rr] = __builtin_amdgcn_mfma_f32_16x16x32_bf16(ah0, xh, a_hh[0][rr], 0, 0, 0);
                    a_hh[1][rr] = __builtin_amdgcn_mfma_f32_16x16x32_bf16(ah1, xh, a_hh[1][rr], 0, 0, 0);
                    a_lh[0][rr] = __builtin_amdgcn_mfma_f32_16x16x32_bf16(al0, xh, a_lh[0][rr], 0, 0, 0);
                    a_lh[1][rr] = __builtin_amdgcn_mfma_f32_16x16x32_bf16(al1, xh, a_lh[1][rr], 0, 0, 0);
                    a_hl[0][rr] = __builtin_amdgcn_mfma_f32_16x16x32_bf16(ah0, xl, a_hl[0][rr], 0, 0, 0);
                    a_hl[1][rr] = __builtin_amdgcn_mfma_f32_16x16x32_bf16(ah1, xl, a_hl[1][rr], 0, 0, 0);
                }
            }
        }
    }

#pragma unroll
    for (int ot = 0; ot < 2; ++ot)
#pragma unroll
        for (int rr = 0; rr < 4; ++rr) {
            int n = (y0 + w * 4 + rr) * 256 + x0 + lc;
#pragma unroll
            for (int r = 0; r < 4; ++r) {
                int oc = ot * 16 + lg * 4 + r;
                yp[(size_t)oc * HW + n] = a_hh[ot][rr][r] + a_lh[ot][rr][r] + a_hl[ot][rr][r];
            }
        }
}

// ---------------------------------------------------------------------------
// Sum 2 partial planes -> ysum, with fused per-channel sum/sumsq stats.
// ---------------------------------------------------------------------------
__global__ __launch_bounds__(256) void reduce2_kernel(
    const float* __restrict__ p0, const float* __restrict__ p1,
    float* __restrict__ y, float* __restrict__ ssum, float* __restrict__ ssq)
{
    int c = blockIdx.x >> 5, seg = blockIdx.x & 31;
    int base = c * HW + seg * 2048 + threadIdx.x * 8;
    float s = 0.f, q = 0.f;
#pragma unroll
    for (int h = 0; h < 2; ++h) {
        int o = base + h * 4;
        float4 a0 = *(const float4*)&p0[o];
        float4 a1 = *(const float4*)&p1[o];
        float4 v;
        v.x = a0.x + a1.x; v.y = a0.y + a1.y;
        v.z = a0.z + a1.z; v.w = a0.w + a1.w;
        *(float4*)&y[o] = v;
        s += v.x + v.y + v.z + v.w;
        q = fmaf(v.x, v.x, q); q = fmaf(v.y, v.y, q);
        q = fmaf(v.z, v.z, q); q = fmaf(v.w, v.w, q);
    }
#pragma unroll
    for (int d = 32; d >= 1; d >>= 1) {
        s += __shfl_down(s, d);
        q += __shfl_down(q, d);
    }
    __shared__ float ls[4], lq[4];
    int w = threadIdx.x >> 6;
    if ((threadIdx.x & 63) == 0) { ls[w] = s; lq[w] = q; }
    __syncthreads();
    if (threadIdx.x == 0) {
        atomicAdd(&ssum[c], ls[0] + ls[1] + ls[2] + ls[3]);
        atomicAdd(&ssq[c], lq[0] + lq[1] + lq[2] + lq[3]);
    }
}

__global__ void bnp_kernel(const float* __restrict__ ssum, const float* __restrict__ ssq,
                           const float* __restrict__ g, const float* __restrict__ beta,
                           float* __restrict__ scl, float* __restrict__ shf)
{
    int c = threadIdx.x;
    float mu  = ssum[c] * (1.f / 65536.f);
    float var = ssq[c] * (1.f / 65536.f) - mu * mu;
    float s = g[c] * rsqrtf(var + 1e-5f);
    scl[c] = s;
    shf[c] = beta[c] - mu * s;
}

// ---------------------------------------------------------------------------
// BN + ReLU + write channel-last bf16 hi/lo
// ---------------------------------------------------------------------------
__global__ __launch_bounds__(256) void bna_kernel(
    const float* __restrict__ yraw, const float* __restrict__ scl, const float* __restrict__ shf,
    unsigned short* __restrict__ aH, unsigned short* __restrict__ aL, int Cs, int slot0)
{
    int t = threadIdx.x;
    int lane = t & 63, cg = t >> 6;
    int px = blockIdx.x * 64 + lane;
    unsigned short h[8], l[8];
#pragma unroll
    for (int j = 0; j < 8; ++j) {
        int c = cg * 8 + j;
        float v = fmaxf(yraw[(size_t)c * HW + px] * scl[c] + shf[c], 0.f);
        h[j] = f2bf(v);
        l[j] = f2bf(v - ubf(h[j]));
    }
    *(uint4*)(aH + (size_t)px * Cs + slot0 + cg * 8) = pack8(h);
    *(uint4*)(aL + (size_t)px * Cs + slot0 + cg * 8) = pack8(l);
}

// ---------------------------------------------------------------------------
// 1x1 conv (96->15) + ReLU; writes pf slots 103..127 of xT and pfch rows
// ---------------------------------------------------------------------------
__global__ __launch_bounds__(256) void feat_kernel(
    const unsigned short* __restrict__ a12H, const unsigned short* __restrict__ a12L,
    const unsigned short* __restrict__ a3H, const unsigned short* __restrict__ a3L,
    const float* __restrict__ w, const float* __restrict__ b,
    unsigned short* __restrict__ xTh, unsigned short* __restrict__ xTl,
    unsigned short* __restrict__ pfch)
{
    int n = blockIdx.x * 256 + threadIdx.x;
    float facc[15];
#pragma unroll
    for (int oc = 0; oc < 15; ++oc) facc[oc] = b[oc];

#pragma unroll
    for (int k = 0; k < 12; ++k) {
        uint4 uh, ul;
        if (k < 8) {
            uh = *(const uint4*)(a12H + (size_t)n * 64 + k * 8);
            ul = *(const uint4*)(a12L + (size_t)n * 64 + k * 8);
        } else {
            uh = *(const uint4*)(a3H + (size_t)n * 32 + (k - 8) * 8);
            ul = *(const uint4*)(a3L + (size_t)n * 32 + (k - 8) * 8);
        }
        unsigned hw_[4] = {uh.x, uh.y, uh.z, uh.w};
        unsigned lw_[4] = {ul.x, ul.y, ul.z, ul.w};
#pragma unroll
        for (int j = 0; j < 8; ++j) {
            unsigned short hh = (unsigned short)(hw_[j >> 1] >> ((j & 1) * 16));
            unsigned short ll = (unsigned short)(lw_[j >> 1] >> ((j & 1) * 16));
            float av = ubf(hh) + ubf(ll);
#pragma unroll
            for (int oc = 0; oc < 15; ++oc)
                facc[oc] = fmaf(av, w[oc * 96 + k * 8 + j], facc[oc]);
        }
    }
    unsigned short fh[16], fl[16];
#pragma unroll
    for (int oc = 0; oc < 15; ++oc) {
        float v = fmaxf(facc[oc], 0.f);
        fh[oc] = f2bf(v);
        fl[oc] = f2bf(v - ubf(fh[oc]));
    }
    fh[15] = 0; fl[15] = 0;

    size_t base = (size_t)n * 128;
    uint4 h0 = *(const uint4*)(xTh + base + 96);
    uint4 l0 = *(const uint4*)(xTl + base + 96);
    h0.w = (h0.w & 0xFFFFu) | ((unsigned)fh[0] << 16);
    l0.w = (l0.w & 0xFFFFu) | ((unsigned)fl[0] << 16);
    *(uint4*)(xTh + base + 96) = h0;
    *(uint4*)(xTl + base + 96) = l0;
    *(uint4*)(xTh + base + 104) = pack8(fh + 1);
    *(uint4*)(xTl + base + 104) = pack8(fl + 1);
    unsigned short t2h[8], t2l[8];
#pragma unroll
    for (int j = 0; j < 8; ++j) {
        t2h[j] = (j < 6) ? fh[9 + j] : (unsigned short)0;
        t2l[j] = (j < 6) ? fl[9 + j] : (unsigned short)0;
    }
    *(uint4*)(xTh + base + 112) = pack8(t2h);
    *(uint4*)(xTl + base + 112) = pack8(t2l);
    unsigned short t3h[8] = {0, 0, 0, 0, 0, 0, 0, 0x3F80};
    unsigned short t3l[8] = {0, 0, 0, 0, 0, 0, 0, 0};
    *(uint4*)(xTh + base + 120) = pack8(t3h);
    *(uint4*)(xTl + base + 120) = pack8(t3l);

#pragma unroll
    for (int k2 = 0; k2 < 15; ++k2)
        pfch[(size_t)(103 + k2) * HW + n] = fh[k2];
    pfch[(size_t)118 * HW + n] = 0x3F80;
#pragma unroll
    for (int c = 119; c < 128; ++c)
        pfch[(size_t)c * HW + n] = 0;
}

// ---------------------------------------------------------------------------
// c0: per-superpixel channel sums -> cn_fin[s][128]
// ---------------------------------------------------------------------------
__global__ __launch_bounds__(256) void c0_kernel(
    const unsigned short* __restrict__ pfTh, const unsigned short* __restrict__ pfTl,
    float* __restrict__ cn_fin)
{
    int s = blockIdx.x;
    int sy = s >> 4, sx = s & 15;
    int t = threadIdx.x;
    int xx = t >> 4;
    int cs = (t & 15) * 8;

    float acc[8];
#pragma unroll
    for (int j = 0; j < 8; ++j) acc[j] = 0.f;

    for (int yy = 0; yy < 16; ++yy) {
        int n = (sy * 16 + yy) * 256 + sx * 16 + xx;
        u16x8 h = *(const u16x8*)(pfTh + (size_t)n * 128 + cs);
        u16x8 l = *(const u16x8*)(pfTl + (size_t)n * 128 + cs);
#pragma unroll
        for (int j = 0; j < 8; ++j)
            acc[j] += ubf(h[j]) + ubf(l[j]);
    }
#pragma unroll
    for (int j = 0; j < 8; ++j) {
        acc[j] += __shfl_xor(acc[j], 16);
        acc[j] += __shfl_xor(acc[j], 32);
    }
    __shared__ float red[4][128];
    int w = t >> 6;
    if ((t & 63) < 16) {
#pragma unroll
        for (int j = 0; j < 8; ++j)
            red[w][(t & 15) * 8 + j] = acc[j];
    }
    __syncthreads();
    if (t < 128)
        cn_fin[s * 128 + t] = red[0][t] + red[1][t] + red[2][t] + red[3][t];
}

// ---------------------------------------------------------------------------
// prep: centroids -> chiT/cloT [s][128]; slot 127 = -0.5*|c|^2
// ---------------------------------------------------------------------------
__global__ __launch_bounds__(128) void prep_kernel(
    const float* __restrict__ cn_fin,
    unsigned short* __restrict__ chiT, unsigned short* __restrict__ cloT,
    float scale0, int use_qsum)
{
    int s = blockIdx.x, c = threadIdx.x;
    float inv = use_qsum ? 1.f / (cn_fin[s * 128 + 118] + 1e-8f) : scale0;
    float v = (c < 118) ? cn_fin[s * 128 + c] * inv : 0.f;
    float a = v * v;
#pragma unroll
    for (int d = 1; d < 64; d <<= 1) a += __shfl_xor(a, d);
    __shared__ float red[2];
    if ((c & 63) == 0) red[c >> 6] = a;
    __syncthreads();
    float tot = red[0] + red[1];
    unsigned short h, lo;
    if (c == 127) {
        float m2 = -0.5f * tot;
        h = f2bf(m2);
        lo = f2bf(m2 - ubf(h));
    } else {
        h = f2bf(v);
        lo = f2bf(v - ubf(h));
    }
    chiT[s * 128 + c] = h;
    cloT[s * 128 + c] = lo;
}

// ---------------------------------------------------------------------------
// FUSED dist+cn with LDS-staged centroids.
// Phase 1: logits via MFMA; A (chiT/cloT) staged in LDS in two st-halves
// with XOR swizzle (short_idx bits 3-5 ^= s&7) to avoid 16-way conflicts;
// B fragments preloaded to registers once (xTh/xTl each read once).
// Phase 2: Q -> LDS (aliases stage buffer) in cn-A-fragment order.
// Phase 3: cn GEMM over the block's 128 px + atomics.
// Block 256 thr = 4 waves = 128 px. Grid 512. LDS 64 KB -> 2 blocks/CU.
// ---------------------------------------------------------------------------
__global__ __launch_bounds__(256) void distcn_kernel(
    const unsigned short* __restrict__ chiT, const unsigned short* __restrict__ cloT,
    const unsigned short* __restrict__ pfTh, const unsigned short* __restrict__ pfTl,
    const unsigned short* __restrict__ pfch,
    float* __restrict__ cn_fin, float* __restrict__ qf, int final_mode)
{
    __shared__ __align__(16) unsigned short sA[32768];  // 64 KB: A-stage, later sQ
    unsigned short* sQ = sA;
    int t = threadIdx.x;
    int w = t >> 6, l = t & 63;
    int lc = l & 15, lg = l >> 4;
    int nblk = blockIdx.x * 128;
    int n0 = nblk + w * 32;

    // preload all B fragments (each xT element read exactly once)
    bf16x8 bh[4][2], bl[4][2];
#pragma unroll
    for (int ks = 0; ks < 4; ++ks) {
        int kb = ks * 32 + 8 * lg;
        bh[ks][0] = *(const bf16x8*)(pfTh + (size_t)(n0 + lc) * 128 + kb);
        bh[ks][1] = *(const bf16x8*)(pfTh + (size_t)(n0 + 16 + lc) * 128 + kb);
        bl[ks][0] = *(const bf16x8*)(pfTl + (size_t)(n0 + lc) * 128 + kb);
        bl[ks][1] = *(const bf16x8*)(pfTl + (size_t)(n0 + 16 + lc) * 128 + kb);
    }

    f32x4 acc[16][2];
#pragma unroll
    for (int i = 0; i < 16; ++i)
#pragma unroll
        for (int g = 0; g < 2; ++g)
#pragma unroll
            for (int j = 0; j < 4; ++j) acc[i][g][j] = 0.f;

#pragma unroll
    for (int hf = 0; hf < 2; ++hf) {
        __syncthreads();
        // stage s-rows [hf*128, hf*128+128) of chiT (plane 0) and cloT (plane 1)
        for (int i = t; i < 4096; i += 256) {
            int plane = i >> 11;
            int ii = i & 2047;
            int sl = ii >> 4;           // s_loc 0..127
            int j = ii & 15;            // 16B chunk within row
            const unsigned short* src = plane ? cloT : chiT;
            uint4 v = *(const uint4*)(src + (((size_t)(hf * 128 + sl)) << 7) + j * 8);
            int ds = ((sl << 7) + j * 8) ^ ((sl & 7) << 3);
            *(uint4*)(sA + plane * 16384 + ds) = v;
        }
        __syncthreads();

#pragma unroll
        for (int sl8 = 0; sl8 < 8; ++sl8) {
            const int st = hf * 8 + sl8;
#pragma unroll
            for (int ks = 0; ks < 4; ++ks) {
                int e0 = (((sl8 * 16 + lc) << 7) + ks * 32 + lg * 8) ^ ((lc & 7) << 3);
                bf16x8 ah = *(const bf16x8*)(sA + e0);
                bf16x8 al = *(const bf16x8*)(sA + 16384 + e0);
                acc[st][0] = __builtin_amdgcn_mfma_f32_16x16x32_bf16(ah, bh[ks][0], acc[st][0], 0, 0, 0);
                acc[st][0] = __builtin_amdgcn_mfma_f32_16x16x32_bf16(al, bh[ks][0], acc[st][0], 0, 0, 0);
                acc[st][0] = __builtin_amdgcn_mfma_f32_16x16x32_bf16(ah, bl[ks][0], acc[st][0], 0, 0, 0);
                acc[st][1] = __builtin_amdgcn_mfma_f32_16x16x32_bf16(ah, bh[ks][1], acc[st][1], 0, 0, 0);
                acc[st][1] = __builtin_amdgcn_mfma_f32_16x16x32_bf16(al, bh[ks][1], acc[st][1], 0, 0, 0);
                acc[st][1] = __builtin_amdgcn_mfma_f32_16x16x32_bf16(ah, bl[ks][1], acc[st][1], 0, 0, 0);
            }
        }
    }

    float m0 = -1e30f, m1 = -1e30f;
#pragma unroll
    for (int st = 0; st < 16; ++st)
#pragma unroll
        for (int r = 0; r < 4; ++r) {
            m0 = fmaxf(m0, acc[st][0][r]);
            m1 = fmaxf(m1, acc[st][1][r]);
        }
    m0 = fmaxf(m0, __shfl_xor(m0, 16)); m0 = fmaxf(m0, __shfl_xor(m0, 32));
    m1 = fmaxf(m1, __shfl_xor(m1, 16)); m1 = fmaxf(m1, __shfl_xor(m1, 32));

    float s0 = 0.f, s1 = 0.f;
#pragma unroll
    for (int st = 0; st < 16; ++st)
#pragma unroll
        for (int r = 0; r < 4; ++r) {
            float e0 = __expf(2.f * (acc[st][0][r] - m0));
            float e1 = __expf(2.f * (acc[st][1][r] - m1));
            acc[st][0][r] = e0; acc[st][1][r] = e1;
            s0 += e0; s1 += e1;
        }
    s0 += __shfl_xor(s0, 16); s0 += __shfl_xor(s0, 32);
    s1 += __shfl_xor(s1, 16); s1 += __shfl_xor(s1, 32);
    float i0 = 1.f / s0, i1 = 1.f / s1;

    if (final_mode) {
        int nA = n0 + lc, nB = n0 + 16 + lc;
#pragma unroll
        for (int st = 0; st < 16; ++st)
#pragma unroll
            for (int r = 0; r < 4; ++r) {
                int s = st * 16 + lg * 4 + r;
                qf[(size_t)s * HW + nA] = acc[st][0][r] * i0;
                qf[(size_t)s * HW + nB] = acc[st][1][r] * i1;
            }
        return;
    }

    __syncthreads();    // sA stage dead; reuse as sQ

    // phase 2: Q (bf16) -> LDS in cn-A-fragment order.
#pragma unroll
    for (int st = 0; st < 16; ++st)
#pragma unroll
        for (int g = 0; g < 2; ++g) {
            float iv = g ? i1 : i0;
#pragma unroll
            for (int r = 0; r < 4; ++r) {
                int idx = ((st * 4 + w) * 64 + (g * 2 + (lc >> 3)) * 16 + lg * 4 + r) * 8 + (lc & 7);
                sQ[idx] = f2bf(acc[st][g][r] * iv);
            }
        }
    __syncthreads();

    // phase 3: wave w covers c in [w*32, w*32+32); k over the block's 128 px
    f32x4 a2[16][2];
#pragma unroll
    for (int i = 0; i < 16; ++i)
#pragma unroll
        for (int ct = 0; ct < 2; ++ct)
#pragma unroll
            for (int j = 0; j < 4; ++j) a2[i][ct][j] = 0.f;

#pragma unroll
    for (int kc = 0; kc < 4; ++kc) {
        int nb = nblk + kc * 32 + 8 * lg;
        bf16x8 b0 = *(const bf16x8*)(pfch + (size_t)(w * 32 + lc) * HW + nb);
        bf16x8 b1 = *(const bf16x8*)(pfch + (size_t)(w * 32 + 16 + lc) * HW + nb);
#pragma unroll
        for (int st = 0; st < 16; ++st) {
            bf16x8 afr = *(const bf16x8*)(sQ + ((size_t)(st * 4 + kc) * 64 + l) * 8);
            a2[st][0] = __builtin_amdgcn_mfma_f32_16x16x32_bf16(afr, b0, a2[st][0], 0, 0, 0);
            a2[st][1] = __builtin_amdgcn_mfma_f32_16x16x32_bf16(afr, b1, a2[st][1], 0, 0, 0);
        }
    }

#pragma unroll
    for (int st = 0; st < 16; ++st)
#pragma unroll
        for (int ct = 0; ct < 2; ++ct)
#pragma unroll
            for (int r = 0; r < 4; ++r) {
                int s = st * 16 + lg * 4 + r;
                int c = w * 32 + ct * 16 + lc;
                atomicAdd(&cn_fin[s * 128 + c], a2[st][ct][r]);
            }
}

// ---------------------------------------------------------------------------
extern "C" void kernel_launch(void* const* d_in, const int* in_sizes, int n_in,
                              void* d_out, int out_size, void* d_ws, size_t ws_size,
                              hipStream_t stream)
{
    const float* x     = (const float*)d_in[0];
    const float* s1k7  = (const float*)d_in[1];
    const float* s1k5  = (const float*)d_in[2];
    const float* s1k3  = (const float*)d_in[3];
    const float* s1g   = (const float*)d_in[5];
    const float* s1be  = (const float*)d_in[6];
    const float* s2k7  = (const float*)d_in[7];
    const float* s2k5  = (const float*)d_in[8];
    const float* s2k3  = (const float*)d_in[9];
    const float* s2g   = (const float*)d_in[11];
    const float* s2be  = (const float*)d_in[12];
    const float* s3k7  = (const float*)d_in[13];
    const float* s3k5  = (const float*)d_in[14];
    const float* s3k3  = (const float*)d_in[15];
    const float* s3g   = (const float*)d_in[17];
    const float* s3be  = (const float*)d_in[18];
    const float* outw  = (const float*)d_in[19];
    const float* outb  = (const float*)d_in[20];

    float* ws = (float*)d_ws;
    size_t off = 0;
    unsigned short* wT1h = (unsigned short*)(ws + off); off += 100352;
    unsigned short* wT1l = (unsigned short*)(ws + off); off += 100352;
    unsigned short* wT2h = (unsigned short*)(ws + off); off += 25088;
    unsigned short* wT2l = (unsigned short*)(ws + off); off += 25088;
    unsigned short* wT3h = (unsigned short*)(ws + off); off += 50176;
    unsigned short* wT3l = (unsigned short*)(ws + off); off += 50176;
    float* stats = ws + off; off += 192;
    float* bn    = ws + off; off += 192;
    float* cn_fin= ws + off; off += 32768;
    unsigned short* chiT = (unsigned short*)(ws + off); off += 16384;
    unsigned short* cloT = (unsigned short*)(ws + off); off += 16384;
    unsigned short* xTh  = (unsigned short*)(ws + off); off += 4194304;
    unsigned short* xTl  = (unsigned short*)(ws + off); off += 4194304;
    unsigned short* pfch = (unsigned short*)(ws + off); off += 4194304;
    unsigned short* a12H = (unsigned short*)(ws + off); off += 2097152;
    unsigned short* a12L = (unsigned short*)(ws + off); off += 2097152;

    // d_out scratch timeline:
    //   p0 @0, p1 @8MB, ysum @16MB   (conv stages; dead before final)
    //   a3H/L @32MB, 8MB             (stage-3 bna -> feat; dead after)
    //   qf @0, 64MB                  (final distcn overwrites everything)
    char* ob = (char*)d_out;
    float* p0   = (float*)ob;
    float* p1   = (float*)(ob + (size_t)8 * 1024 * 1024);
    float* ysum = (float*)(ob + (size_t)16 * 1024 * 1024);
    float* qf = (float*)ob;
    unsigned short* a3H = (unsigned short*)(ob + (size_t)32 * 1024 * 1024);
    unsigned short* a3L = a3H + (size_t)HW * 32;

    hipMemsetAsync(stats, 0, 192 * sizeof(float), stream);
    wmerge_kernel<<<(49 * 4 * 1024 + 255) / 256, 256, 0, stream>>>(s1k7, s1k5, s1k3, 103, 4, wT1h, wT1l);
    wmerge_kernel<<<(49 * 1 * 1024 + 255) / 256, 256, 0, stream>>>(s2k7, s2k5, s2k3, 32, 1, wT2h, wT2l);
    wmerge_kernel<<<(49 * 2 * 1024 + 255) / 256, 256, 0, stream>>>(s3k7, s3k5, s3k3, 64, 2, wT3h, wT3l);

    transpose_kernel<<<1024, 256, 0, stream>>>(x, xTh, xTl, pfch);

    // stage 1: z splits ci-chunks {0,1} / {2,3}
    convm_kernel<<<dim3(256, 2), 256, 0, stream>>>(xTh, xTl, 128, wT1h, wT1l, 4,
                                                   0, 2, 0, 49, 2, 4, 0, 49, p0);
    reduce2_kernel<<<1024, 256, 0, stream>>>(p0, p1, ysum, stats + 0, stats + 32);
    bnp_kernel<<<1, 32, 0, stream>>>(stats + 0, stats + 32, s1g, s1be, bn + 0, bn + 32);
    bna_kernel<<<1024, 256, 0, stream>>>(ysum, bn + 0, bn + 32, a12H, a12L, 64, 0);

    // stage 2: z splits taps [0,25) / [25,49)
    convm_kernel<<<dim3(256, 2), 256, 0, stream>>>(a12H, a12L, 64, wT2h, wT2l, 1,
                                                   0, 1, 0, 25, 0, 1, 25, 49, p0);
    reduce2_kernel<<<1024, 256, 0, stream>>>(p0, p1, ysum, stats + 64, stats + 96);
    bnp_kernel<<<1, 32, 0, stream>>>(stats + 64, stats + 96, s2g, s2be, bn + 64, bn + 96);
    bna_kernel<<<1024, 256, 0, stream>>>(ysum, bn + 64, bn + 96, a12H, a12L, 64, 32);

    // stage 3: z splits ci-chunks {0} / {1}
    convm_kernel<<<dim3(256, 2), 256, 0, stream>>>(a12H, a12L, 64, wT3h, wT3l, 2,
                                                   0, 1, 0, 49, 1, 2, 0, 49, p0);
    reduce2_kernel<<<1024, 256, 0, stream>>>(p0, p1, ysum, stats + 128, stats + 160);
    bnp_kernel<<<1, 32, 0, stream>>>(stats + 128, stats + 160, s3g, s3be, bn + 128, bn + 160);
    bna_kernel<<<1024, 256, 0, stream>>>(ysum, bn + 128, bn + 160, a3H, a3L, 32, 0);

    feat_kernel<<<256, 256, 0, stream>>>(a12H, a12L, a3H, a3L, outw, outb, xTh, xTl, pfch);
    c0_kernel<<<256, 256, 0, stream>>>(xTh, xTl, cn_fin);
    prep_kernel<<<256, 128, 0, stream>>>(cn_fin, chiT, cloT, 1.f / 256.f, 0);

    for (int it = 0; it < 5; ++it) {
        hipMemsetAsync(cn_fin, 0, 32768 * sizeof(float), stream);
        distcn_kernel<<<512, 256, 0, stream>>>(chiT, cloT, xTh, xTl, pfch, cn_fin, qf, 0);
        prep_kernel<<<256, 128, 0, stream>>>(cn_fin, chiT, cloT, 0.f, 1);
    }
    distcn_kernel<<<512, 256, 0, stream>>>(chiT, cloT, xTh, xTl, pfch, cn_fin, qf, 1);
}

// Round 11
// 679.147 us; speedup vs baseline: 2.1305x; 1.1821x over previous
//
#include <hip/hip_runtime.h>

#define HW 65536

typedef short bf16x8 __attribute__((ext_vector_type(8)));
typedef float f32x4 __attribute__((ext_vector_type(4)));
typedef unsigned short u16x8 __attribute__((ext_vector_type(8)));

__device__ inline unsigned short f2bf(float v) {
    unsigned u = __float_as_uint(v);
    unsigned r = (u + 0x7FFF + ((u >> 16) & 1)) >> 16;
    return (unsigned short)r;
}
__device__ inline float ubf(unsigned short h) {
    return __uint_as_float(((unsigned)h) << 16);
}
__device__ inline uint4 pack8(const unsigned short* p) {
    uint4 u;
    u.x = (unsigned)p[0] | ((unsigned)p[1] << 16);
    u.y = (unsigned)p[2] | ((unsigned)p[3] << 16);
    u.z = (unsigned)p[4] | ((unsigned)p[5] << 16);
    u.w = (unsigned)p[6] | ((unsigned)p[7] << 16);
    return u;
}

// ---------------------------------------------------------------------------
// Merge 7/5/3 kernels into one 7x7; emit bf16 hi/lo in A-FRAGMENT LANE ORDER.
// ---------------------------------------------------------------------------
__global__ void wmerge_kernel(const float* __restrict__ k7, const float* __restrict__ k5,
                              const float* __restrict__ k3, int Cin, int nch,
                              unsigned short* __restrict__ wTh, unsigned short* __restrict__ wTl)
{
    int idx = blockIdx.x * 256 + threadIdx.x;
    int total = 49 * nch * 1024;
    if (idx >= total) return;
    int e = idx & 7;
    int lane = (idx >> 3) & 63;
    int octile = (idx >> 9) & 1;
    int chunk = (idx >> 10) % nch;
    int tap = idx / (nch << 10);
    int oc = octile * 16 + (lane & 15);
    int ci = chunk * 32 + (lane >> 4) * 8 + e;
    int ky = tap / 7, kx = tap % 7;
    float v = 0.f;
    if (ci < Cin) {
        v = k7[(oc * Cin + ci) * 49 + tap];
        if (ky >= 1 && ky <= 5 && kx >= 1 && kx <= 5)
            v += k5[(oc * Cin + ci) * 25 + (ky - 1) * 5 + (kx - 1)];
        if (ky >= 2 && ky <= 4 && kx >= 2 && kx <= 4)
            v += k3[(oc * Cin + ci) * 9 + (ky - 2) * 3 + (kx - 2)];
    }
    unsigned short h = f2bf(v);
    wTh[idx] = h;
    wTl[idx] = f2bf(v - ubf(h));
}

// ---------------------------------------------------------------------------
// x [103][HW] fp32 -> xT [n][128] bf16 hi/lo and pfch [c][HW] bf16 hi
// ---------------------------------------------------------------------------
__global__ __launch_bounds__(256) void transpose_kernel(
    const float* __restrict__ x,
    unsigned short* __restrict__ xTh, unsigned short* __restrict__ xTl,
    unsigned short* __restrict__ pfch)
{
    __shared__ float buf[64 * 105];
    int t = threadIdx.x;
    int px0 = blockIdx.x * 64;
    for (int i = t; i < 103 * 64; i += 256) {
        int c = i >> 6, lane = i & 63;
        float v = x[(size_t)c * HW + px0 + lane];
        buf[lane * 105 + c] = v;
        pfch[(size_t)c * HW + px0 + lane] = f2bf(v);
    }
    __syncthreads();
    int px = t >> 2, seg = t & 3;
    unsigned short h[32], l[32];
#pragma unroll
    for (int j = 0; j < 32; ++j) {
        int c = seg * 32 + j;
        float v = (c < 103) ? buf[px * 105 + c] : 0.f;
        h[j] = f2bf(v);
        l[j] = f2bf(v - ubf(h[j]));
    }
    size_t base = (size_t)(px0 + px) * 128 + seg * 32;
#pragma unroll
    for (int k = 0; k < 4; ++k) {
        *(uint4*)(xTh + base + k * 8) = pack8(h + k * 8);
        *(uint4*)(xTl + base + k * 8) = pack8(l + k * 8);
    }
}

// ---------------------------------------------------------------------------
// Implicit-GEMM 7x7 conv, MFMA 16x16x32 bf16, 3-phase hi/lo.
// 4 rows per wave (16-row block tile). Weights in LDS 3-tap ring.
// Grid (256, 2) with z-split work ranges.
// ---------------------------------------------------------------------------
__global__ __launch_bounds__(256) void convm_kernel(
    const unsigned short* __restrict__ actH, const unsigned short* __restrict__ actL,
    int Cs,
    const unsigned short* __restrict__ wTh, const unsigned short* __restrict__ wTl,
    int nchw,
    int c0a, int c1a, int t0a, int t1a,
    int c0b, int c1b, int t0b, int t1b,
    float* __restrict__ ypart)
{
    __shared__ __align__(16) unsigned short sH[22 * 704];
    __shared__ __align__(16) unsigned short sL[22 * 704];
    __shared__ __align__(16) unsigned short sW[3 * 2048];
    int t = threadIdx.x;
    int w = t >> 6, l = t & 63;
    int lc = l & 15, lg = l >> 4;
    int bx = blockIdx.x & 15, byy = blockIdx.x >> 4;
    int x0 = bx * 16, y0 = byy * 16;
    int z = blockIdx.y;
    int ch0 = z ? c0b : c0a, ch1 = z ? c1b : c1a;
    int tap0 = z ? t0b : t0a, tap1 = z ? t1b : t1a;
    float* yp = ypart + (size_t)z * 32 * HW;

    f32x4 a_hh[2][4], a_lh[2][4], a_hl[2][4];   // [oc-tile][row]
#pragma unroll
    for (int ot = 0; ot < 2; ++ot)
#pragma unroll
        for (int rr = 0; rr < 4; ++rr)
#pragma unroll
            for (int r = 0; r < 4; ++r) {
                a_hh[ot][rr][r] = 0.f; a_lh[ot][rr][r] = 0.f; a_hl[ot][rr][r] = 0.f;
            }

    for (int ch = ch0; ch < ch1; ++ch) {
        int ci0 = ch * 32;
        __syncthreads();                // protect sH/sL from prior reads
        for (int i = t; i < 2 * 22 * 88; i += 256) {
            int pl = (i >= 22 * 88) ? 1 : 0;
            int j = pl ? i - 22 * 88 : i;
            int row = j / 88;
            int rem = j - row * 88;
            int px = rem >> 2, q = rem & 3;
            int gy = y0 - 3 + row, gx = x0 - 3 + px;
            uint4 v = {0u, 0u, 0u, 0u};
            if (gy >= 0 && gy < 256 && gx >= 0 && gx < 256) {
                const unsigned short* src = pl ? actL : actH;
                v = *(const uint4*)(src + (size_t)(gy * 256 + gx) * Cs + ci0 + q * 8);
            }
            unsigned short* dst = pl ? sL : sH;
            *(uint4*)(dst + row * 704 + q * 176 + px * 8) = v;
        }

        for (int g = tap0; g < tap1; g += 3) {
            int ge = g + 3; if (ge > tap1) ge = tap1;
            if (g > tap0) __syncthreads();      // protect sW from prior group reads
            for (int i = t; i < (ge - g) * 256; i += 256) {
                int tp = i >> 8, r = i & 255;
                const unsigned short* src = (r < 128) ? wTh : wTl;
                *(uint4*)(sW + tp * 2048 + r * 8) =
                    *(const uint4*)(src + ((size_t)((g + tp) * nchw + ch)) * 1024 + (r & 127) * 8);
            }
            __syncthreads();

            for (int tap = g; tap < ge; ++tap) {
                const unsigned short* wb = sW + (tap - g) * 2048 + l * 8;
                bf16x8 ah0 = *(const bf16x8*)(wb);
                bf16x8 ah1 = *(const bf16x8*)(wb + 512);
                bf16x8 al0 = *(const bf16x8*)(wb + 1024);
                bf16x8 al1 = *(const bf16x8*)(wb + 1536);
                int ky = tap / 7;
                int kx = tap - ky * 7;
#pragma unroll
                for (int rr = 0; rr < 4; ++rr) {
                    int off = (w * 4 + rr + ky) * 704 + lg * 176 + (lc + kx) * 8;
                    bf16x8 xh = *(const bf16x8*)(sH + off);
                    bf16x8 xl = *(const bf16x8*)(sL + off);
                    a_hh[0][rr] = __builtin_amdgcn_mfma_f32_16x16x32_bf16(ah0, xh, a_hh[0][rr], 0, 0, 0);
                    a_hh[1][rr] = __builtin_amdgcn_mfma_f32_16x16x32_bf16(ah1, xh, a_hh[1][rr], 0, 0, 0);
                    a_lh[0][rr] = __builtin_amdgcn_mfma_f32_16x16x32_bf16(al0, xh, a_lh[0][rr], 0, 0, 0);
                    a_lh[1][rr] = __builtin_amdgcn_mfma_f32_16x16x32_bf16(al1, xh, a_lh[1][rr], 0, 0, 0);
                    a_hl[0][rr] = __builtin_amdgcn_mfma_f32_16x16x32_bf16(ah0, xl, a_hl[0][rr], 0, 0, 0);
                    a_hl[1][rr] = __builtin_amdgcn_mfma_f32_16x16x32_bf16(ah1, xl, a_hl[1][rr], 0, 0, 0);
                }
            }
        }
    }

#pragma unroll
    for (int ot = 0; ot < 2; ++ot)
#pragma unroll
        for (int rr = 0; rr < 4; ++rr) {
            int n = (y0 + w * 4 + rr) * 256 + x0 + lc;
#pragma unroll
            for (int r = 0; r < 4; ++r) {
                int oc = ot * 16 + lg * 4 + r;
                yp[(size_t)oc * HW + n] = a_hh[ot][rr][r] + a_lh[ot][rr][r] + a_hl[ot][rr][r];
            }
        }
}

// ---------------------------------------------------------------------------
// Sum 2 partial planes -> ysum, with fused per-channel sum/sumsq stats.
// ---------------------------------------------------------------------------
__global__ __launch_bounds__(256) void reduce2_kernel(
    const float* __restrict__ p0, const float* __restrict__ p1,
    float* __restrict__ y, float* __restrict__ ssum, float* __restrict__ ssq)
{
    int c = blockIdx.x >> 5, seg = blockIdx.x & 31;
    int base = c * HW + seg * 2048 + threadIdx.x * 8;
    float s = 0.f, q = 0.f;
#pragma unroll
    for (int h = 0; h < 2; ++h) {
        int o = base + h * 4;
        float4 a0 = *(const float4*)&p0[o];
        float4 a1 = *(const float4*)&p1[o];
        float4 v;
        v.x = a0.x + a1.x; v.y = a0.y + a1.y;
        v.z = a0.z + a1.z; v.w = a0.w + a1.w;
        *(float4*)&y[o] = v;
        s += v.x + v.y + v.z + v.w;
        q = fmaf(v.x, v.x, q); q = fmaf(v.y, v.y, q);
        q = fmaf(v.z, v.z, q); q = fmaf(v.w, v.w, q);
    }
#pragma unroll
    for (int d = 32; d >= 1; d >>= 1) {
        s += __shfl_down(s, d);
        q += __shfl_down(q, d);
    }
    __shared__ float ls[4], lq[4];
    int w = threadIdx.x >> 6;
    if ((threadIdx.x & 63) == 0) { ls[w] = s; lq[w] = q; }
    __syncthreads();
    if (threadIdx.x == 0) {
        atomicAdd(&ssum[c], ls[0] + ls[1] + ls[2] + ls[3]);
        atomicAdd(&ssq[c], lq[0] + lq[1] + lq[2] + lq[3]);
    }
}

__global__ void bnp_kernel(const float* __restrict__ ssum, const float* __restrict__ ssq,
                           const float* __restrict__ g, const float* __restrict__ beta,
                           float* __restrict__ scl, float* __restrict__ shf)
{
    int c = threadIdx.x;
    float mu  = ssum[c] * (1.f / 65536.f);
    float var = ssq[c] * (1.f / 65536.f) - mu * mu;
    float s = g[c] * rsqrtf(var + 1e-5f);
    scl[c] = s;
    shf[c] = beta[c] - mu * s;
}

// ---------------------------------------------------------------------------
// BN + ReLU + write channel-last bf16 hi/lo
// ---------------------------------------------------------------------------
__global__ __launch_bounds__(256) void bna_kernel(
    const float* __restrict__ yraw, const float* __restrict__ scl, const float* __restrict__ shf,
    unsigned short* __restrict__ aH, unsigned short* __restrict__ aL, int Cs, int slot0)
{
    int t = threadIdx.x;
    int lane = t & 63, cg = t >> 6;
    int px = blockIdx.x * 64 + lane;
    unsigned short h[8], l[8];
#pragma unroll
    for (int j = 0; j < 8; ++j) {
        int c = cg * 8 + j;
        float v = fmaxf(yraw[(size_t)c * HW + px] * scl[c] + shf[c], 0.f);
        h[j] = f2bf(v);
        l[j] = f2bf(v - ubf(h[j]));
    }
    *(uint4*)(aH + (size_t)px * Cs + slot0 + cg * 8) = pack8(h);
    *(uint4*)(aL + (size_t)px * Cs + slot0 + cg * 8) = pack8(l);
}

// ---------------------------------------------------------------------------
// 1x1 conv (96->15) + ReLU; writes pf slots 103..127 of xT and pfch rows
// ---------------------------------------------------------------------------
__global__ __launch_bounds__(256) void feat_kernel(
    const unsigned short* __restrict__ a12H, const unsigned short* __restrict__ a12L,
    const unsigned short* __restrict__ a3H, const unsigned short* __restrict__ a3L,
    const float* __restrict__ w, const float* __restrict__ b,
    unsigned short* __restrict__ xTh, unsigned short* __restrict__ xTl,
    unsigned short* __restrict__ pfch)
{
    int n = blockIdx.x * 256 + threadIdx.x;
    float facc[15];
#pragma unroll
    for (int oc = 0; oc < 15; ++oc) facc[oc] = b[oc];

#pragma unroll
    for (int k = 0; k < 12; ++k) {
        uint4 uh, ul;
        if (k < 8) {
            uh = *(const uint4*)(a12H + (size_t)n * 64 + k * 8);
            ul = *(const uint4*)(a12L + (size_t)n * 64 + k * 8);
        } else {
            uh = *(const uint4*)(a3H + (size_t)n * 32 + (k - 8) * 8);
            ul = *(const uint4*)(a3L + (size_t)n * 32 + (k - 8) * 8);
        }
        unsigned hw_[4] = {uh.x, uh.y, uh.z, uh.w};
        unsigned lw_[4] = {ul.x, ul.y, ul.z, ul.w};
#pragma unroll
        for (int j = 0; j < 8; ++j) {
            unsigned short hh = (unsigned short)(hw_[j >> 1] >> ((j & 1) * 16));
            unsigned short ll = (unsigned short)(lw_[j >> 1] >> ((j & 1) * 16));
            float av = ubf(hh) + ubf(ll);
#pragma unroll
            for (int oc = 0; oc < 15; ++oc)
                facc[oc] = fmaf(av, w[oc * 96 + k * 8 + j], facc[oc]);
        }
    }
    unsigned short fh[16], fl[16];
#pragma unroll
    for (int oc = 0; oc < 15; ++oc) {
        float v = fmaxf(facc[oc], 0.f);
        fh[oc] = f2bf(v);
        fl[oc] = f2bf(v - ubf(fh[oc]));
    }
    fh[15] = 0; fl[15] = 0;

    size_t base = (size_t)n * 128;
    uint4 h0 = *(const uint4*)(xTh + base + 96);
    uint4 l0 = *(const uint4*)(xTl + base + 96);
    h0.w = (h0.w & 0xFFFFu) | ((unsigned)fh[0] << 16);
    l0.w = (l0.w & 0xFFFFu) | ((unsigned)fl[0] << 16);
    *(uint4*)(xTh + base + 96) = h0;
    *(uint4*)(xTl + base + 96) = l0;
    *(uint4*)(xTh + base + 104) = pack8(fh + 1);
    *(uint4*)(xTl + base + 104) = pack8(fl + 1);
    unsigned short t2h[8], t2l[8];
#pragma unroll
    for (int j = 0; j < 8; ++j) {
        t2h[j] = (j < 6) ? fh[9 + j] : (unsigned short)0;
        t2l[j] = (j < 6) ? fl[9 + j] : (unsigned short)0;
    }
    *(uint4*)(xTh + base + 112) = pack8(t2h);
    *(uint4*)(xTl + base + 112) = pack8(t2l);
    unsigned short t3h[8] = {0, 0, 0, 0, 0, 0, 0, 0x3F80};
    unsigned short t3l[8] = {0, 0, 0, 0, 0, 0, 0, 0};
    *(uint4*)(xTh + base + 120) = pack8(t3h);
    *(uint4*)(xTl + base + 120) = pack8(t3l);

#pragma unroll
    for (int k2 = 0; k2 < 15; ++k2)
        pfch[(size_t)(103 + k2) * HW + n] = fh[k2];
    pfch[(size_t)118 * HW + n] = 0x3F80;
#pragma unroll
    for (int c = 119; c < 128; ++c)
        pfch[(size_t)c * HW + n] = 0;
}

// ---------------------------------------------------------------------------
// c0: per-superpixel channel sums -> cn_fin[s][128]
// ---------------------------------------------------------------------------
__global__ __launch_bounds__(256) void c0_kernel(
    const unsigned short* __restrict__ pfTh, const unsigned short* __restrict__ pfTl,
    float* __restrict__ cn_fin)
{
    int s = blockIdx.x;
    int sy = s >> 4, sx = s & 15;
    int t = threadIdx.x;
    int xx = t >> 4;
    int cs = (t & 15) * 8;

    float acc[8];
#pragma unroll
    for (int j = 0; j < 8; ++j) acc[j] = 0.f;

    for (int yy = 0; yy < 16; ++yy) {
        int n = (sy * 16 + yy) * 256 + sx * 16 + xx;
        u16x8 h = *(const u16x8*)(pfTh + (size_t)n * 128 + cs);
        u16x8 l = *(const u16x8*)(pfTl + (size_t)n * 128 + cs);
#pragma unroll
        for (int j = 0; j < 8; ++j)
            acc[j] += ubf(h[j]) + ubf(l[j]);
    }
#pragma unroll
    for (int j = 0; j < 8; ++j) {
        acc[j] += __shfl_xor(acc[j], 16);
        acc[j] += __shfl_xor(acc[j], 32);
    }
    __shared__ float red[4][128];
    int w = t >> 6;
    if ((t & 63) < 16) {
#pragma unroll
        for (int j = 0; j < 8; ++j)
            red[w][(t & 15) * 8 + j] = acc[j];
    }
    __syncthreads();
    if (t < 128)
        cn_fin[s * 128 + t] = red[0][t] + red[1][t] + red[2][t] + red[3][t];
}

// ---------------------------------------------------------------------------
// reduce_cn: cn_part [512][32768] -> cn_mid [8][32768]
// Grid (128, 8). Block x: 256 consecutive outputs; block y: 64 k-slices.
// ---------------------------------------------------------------------------
__global__ __launch_bounds__(256) void reduce_cn(
    const float* __restrict__ cn_part, float* __restrict__ cn_mid)
{
    int o = blockIdx.x * 256 + threadIdx.x;
    int k0 = blockIdx.y * 64;
    float a = 0.f;
    for (int k = k0; k < k0 + 64; ++k)
        a += cn_part[(size_t)k * 32768 + o];
    cn_mid[(size_t)blockIdx.y * 32768 + o] = a;
}

// ---------------------------------------------------------------------------
// prep: centroids -> chiT/cloT [s][128]; slot 127 = -0.5*|c|^2.
// src has nmid stacked [32768] planes to be summed (1 for c0, 8 for cn_mid).
// ---------------------------------------------------------------------------
__global__ __launch_bounds__(128) void prep_kernel(
    const float* __restrict__ src, int nmid,
    unsigned short* __restrict__ chiT, unsigned short* __restrict__ cloT,
    float scale0, int use_qsum)
{
    int s = blockIdx.x, c = threadIdx.x;
    float v = 0.f, q118 = 0.f;
    for (int m = 0; m < nmid; ++m) {
        v += src[(size_t)m * 32768 + s * 128 + c];
        q118 += src[(size_t)m * 32768 + s * 128 + 118];
    }
    float inv = use_qsum ? 1.f / (q118 + 1e-8f) : scale0;
    v = (c < 118) ? v * inv : 0.f;
    float a = v * v;
#pragma unroll
    for (int d = 1; d < 64; d <<= 1) a += __shfl_xor(a, d);
    __shared__ float red[2];
    if ((c & 63) == 0) red[c >> 6] = a;
    __syncthreads();
    float tot = red[0] + red[1];
    unsigned short h, lo;
    if (c == 127) {
        float m2 = -0.5f * tot;
        h = f2bf(m2);
        lo = f2bf(m2 - ubf(h));
    } else {
        h = f2bf(v);
        lo = f2bf(v - ubf(h));
    }
    chiT[s * 128 + c] = h;
    cloT[s * 128 + c] = lo;
}

// ---------------------------------------------------------------------------
// FUSED dist+cn with LDS-staged centroids.
// Phase 1: logits via MFMA (A staged in LDS, XOR-swizzled; B preloaded).
// Phase 2: Q -> LDS (aliases stage buffer) in cn-A-fragment order.
// Phase 3: cn GEMM over the block's 128 px -> PLAIN STORES to cn_part[block]
// (no atomics: R10 showed 16.7M device-scope atomics = 174 G/s bound).
// final_mode: write fp32 Q to qf, skip phases 2/3.
// Block 256 thr = 4 waves = 128 px. Grid 512. LDS 64 KB -> 2 blocks/CU.
// ---------------------------------------------------------------------------
__global__ __launch_bounds__(256) void distcn_kernel(
    const unsigned short* __restrict__ chiT, const unsigned short* __restrict__ cloT,
    const unsigned short* __restrict__ pfTh, const unsigned short* __restrict__ pfTl,
    const unsigned short* __restrict__ pfch,
    float* __restrict__ cn_part, float* __restrict__ qf, int final_mode)
{
    __shared__ __align__(16) unsigned short sA[32768];  // 64 KB: A-stage, later sQ
    unsigned short* sQ = sA;
    int t = threadIdx.x;
    int w = t >> 6, l = t & 63;
    int lc = l & 15, lg = l >> 4;
    int nblk = blockIdx.x * 128;
    int n0 = nblk + w * 32;

    // preload all B fragments (each xT element read exactly once)
    bf16x8 bh[4][2], bl[4][2];
#pragma unroll
    for (int ks = 0; ks < 4; ++ks) {
        int kb = ks * 32 + 8 * lg;
        bh[ks][0] = *(const bf16x8*)(pfTh + (size_t)(n0 + lc) * 128 + kb);
        bh[ks][1] = *(const bf16x8*)(pfTh + (size_t)(n0 + 16 + lc) * 128 + kb);
        bl[ks][0] = *(const bf16x8*)(pfTl + (size_t)(n0 + lc) * 128 + kb);
        bl[ks][1] = *(const bf16x8*)(pfTl + (size_t)(n0 + 16 + lc) * 128 + kb);
    }

    f32x4 acc[16][2];
#pragma unroll
    for (int i = 0; i < 16; ++i)
#pragma unroll
        for (int g = 0; g < 2; ++g)
#pragma unroll
            for (int j = 0; j < 4; ++j) acc[i][g][j] = 0.f;

#pragma unroll
    for (int hf = 0; hf < 2; ++hf) {
        __syncthreads();
        // stage s-rows [hf*128, hf*128+128) of chiT (plane 0) and cloT (plane 1)
        for (int i = t; i < 4096; i += 256) {
            int plane = i >> 11;
            int ii = i & 2047;
            int sl = ii >> 4;           // s_loc 0..127
            int j = ii & 15;            // 16B chunk within row
            const unsigned short* src = plane ? cloT : chiT;
            uint4 v = *(const uint4*)(src + (((size_t)(hf * 128 + sl)) << 7) + j * 8);
            int ds = ((sl << 7) + j * 8) ^ ((sl & 7) << 3);
            *(uint4*)(sA + plane * 16384 + ds) = v;
        }
        __syncthreads();

#pragma unroll
        for (int sl8 = 0; sl8 < 8; ++sl8) {
            const int st = hf * 8 + sl8;
#pragma unroll
            for (int ks = 0; ks < 4; ++ks) {
                int e0 = (((sl8 * 16 + lc) << 7) + ks * 32 + lg * 8) ^ ((lc & 7) << 3);
                bf16x8 ah = *(const bf16x8*)(sA + e0);
                bf16x8 al = *(const bf16x8*)(sA + 16384 + e0);
                acc[st][0] = __builtin_amdgcn_mfma_f32_16x16x32_bf16(ah, bh[ks][0], acc[st][0], 0, 0, 0);
                acc[st][0] = __builtin_amdgcn_mfma_f32_16x16x32_bf16(al, bh[ks][0], acc[st][0], 0, 0, 0);
                acc[st][0] = __builtin_amdgcn_mfma_f32_16x16x32_bf16(ah, bl[ks][0], acc[st][0], 0, 0, 0);
                acc[st][1] = __builtin_amdgcn_mfma_f32_16x16x32_bf16(ah, bh[ks][1], acc[st][1], 0, 0, 0);
                acc[st][1] = __builtin_amdgcn_mfma_f32_16x16x32_bf16(al, bh[ks][1], acc[st][1], 0, 0, 0);
                acc[st][1] = __builtin_amdgcn_mfma_f32_16x16x32_bf16(ah, bl[ks][1], acc[st][1], 0, 0, 0);
            }
        }
    }

    float m0 = -1e30f, m1 = -1e30f;
#pragma unroll
    for (int st = 0; st < 16; ++st)
#pragma unroll
        for (int r = 0; r < 4; ++r) {
            m0 = fmaxf(m0, acc[st][0][r]);
            m1 = fmaxf(m1, acc[st][1][r]);
        }
    m0 = fmaxf(m0, __shfl_xor(m0, 16)); m0 = fmaxf(m0, __shfl_xor(m0, 32));
    m1 = fmaxf(m1, __shfl_xor(m1, 16)); m1 = fmaxf(m1, __shfl_xor(m1, 32));

    float s0 = 0.f, s1 = 0.f;
#pragma unroll
    for (int st = 0; st < 16; ++st)
#pragma unroll
        for (int r = 0; r < 4; ++r) {
            float e0 = __expf(2.f * (acc[st][0][r] - m0));
            float e1 = __expf(2.f * (acc[st][1][r] - m1));
            acc[st][0][r] = e0; acc[st][1][r] = e1;
            s0 += e0; s1 += e1;
        }
    s0 += __shfl_xor(s0, 16); s0 += __shfl_xor(s0, 32);
    s1 += __shfl_xor(s1, 16); s1 += __shfl_xor(s1, 32);
    float i0 = 1.f / s0, i1 = 1.f / s1;

    if (final_mode) {
        int nA = n0 + lc, nB = n0 + 16 + lc;
#pragma unroll
        for (int st = 0; st < 16; ++st)
#pragma unroll
            for (int r = 0; r < 4; ++r) {
                int s = st * 16 + lg * 4 + r;
                qf[(size_t)s * HW + nA] = acc[st][0][r] * i0;
                qf[(size_t)s * HW + nB] = acc[st][1][r] * i1;
            }
        return;
    }

    __syncthreads();    // sA stage dead; reuse as sQ

    // phase 2: Q (bf16) -> LDS in cn-A-fragment order.
#pragma unroll
    for (int st = 0; st < 16; ++st)
#pragma unroll
        for (int g = 0; g < 2; ++g) {
            float iv = g ? i1 : i0;
#pragma unroll
            for (int r = 0; r < 4; ++r) {
                int idx = ((st * 4 + w) * 64 + (g * 2 + (lc >> 3)) * 16 + lg * 4 + r) * 8 + (lc & 7);
                sQ[idx] = f2bf(acc[st][g][r] * iv);
            }
        }
    __syncthreads();

    // phase 3: wave w covers c in [w*32, w*32+32); k over the block's 128 px
    f32x4 a2[16][2];
#pragma unroll
    for (int i = 0; i < 16; ++i)
#pragma unroll
        for (int ct = 0; ct < 2; ++ct)
#pragma unroll
            for (int j = 0; j < 4; ++j) a2[i][ct][j] = 0.f;

#pragma unroll
    for (int kc = 0; kc < 4; ++kc) {
        int nb = nblk + kc * 32 + 8 * lg;
        bf16x8 b0 = *(const bf16x8*)(pfch + (size_t)(w * 32 + lc) * HW + nb);
        bf16x8 b1 = *(const bf16x8*)(pfch + (size_t)(w * 32 + 16 + lc) * HW + nb);
#pragma unroll
        for (int st = 0; st < 16; ++st) {
            bf16x8 afr = *(const bf16x8*)(sQ + ((size_t)(st * 4 + kc) * 64 + l) * 8);
            a2[st][0] = __builtin_amdgcn_mfma_f32_16x16x32_bf16(afr, b0, a2[st][0], 0, 0, 0);
            a2[st][1] = __builtin_amdgcn_mfma_f32_16x16x32_bf16(afr, b1, a2[st][1], 0, 0, 0);
        }
    }

    float* out = cn_part + (size_t)blockIdx.x * 32768;
#pragma unroll
    for (int st = 0; st < 16; ++st)
#pragma unroll
        for (int ct = 0; ct < 2; ++ct)
#pragma unroll
            for (int r = 0; r < 4; ++r) {
                int s = st * 16 + lg * 4 + r;
                int c = w * 32 + ct * 16 + lc;
                out[s * 128 + c] = a2[st][ct][r];
            }
}

// ---------------------------------------------------------------------------
extern "C" void kernel_launch(void* const* d_in, const int* in_sizes, int n_in,
                              void* d_out, int out_size, void* d_ws, size_t ws_size,
                              hipStream_t stream)
{
    const float* x     = (const float*)d_in[0];
    const float* s1k7  = (const float*)d_in[1];
    const float* s1k5  = (const float*)d_in[2];
    const float* s1k3  = (const float*)d_in[3];
    const float* s1g   = (const float*)d_in[5];
    const float* s1be  = (const float*)d_in[6];
    const float* s2k7  = (const float*)d_in[7];
    const float* s2k5  = (const float*)d_in[8];
    const float* s2k3  = (const float*)d_in[9];
    const float* s2g   = (const float*)d_in[11];
    const float* s2be  = (const float*)d_in[12];
    const float* s3k7  = (const float*)d_in[13];
    const float* s3k5  = (const float*)d_in[14];
    const float* s3k3  = (const float*)d_in[15];
    const float* s3g   = (const float*)d_in[17];
    const float* s3be  = (const float*)d_in[18];
    const float* outw  = (const float*)d_in[19];
    const float* outb  = (const float*)d_in[20];

    float* ws = (float*)d_ws;
    size_t off = 0;
    unsigned short* wT1h = (unsigned short*)(ws + off); off += 100352;
    unsigned short* wT1l = (unsigned short*)(ws + off); off += 100352;
    unsigned short* wT2h = (unsigned short*)(ws + off); off += 25088;
    unsigned short* wT2l = (unsigned short*)(ws + off); off += 25088;
    unsigned short* wT3h = (unsigned short*)(ws + off); off += 50176;
    unsigned short* wT3l = (unsigned short*)(ws + off); off += 50176;
    float* stats = ws + off; off += 192;
    float* bn    = ws + off; off += 192;
    float* cn_fin= ws + off; off += 32768;
    float* cn_mid= ws + off; off += 262144;   // 8 x 32768
    unsigned short* chiT = (unsigned short*)(ws + off); off += 16384;
    unsigned short* cloT = (unsigned short*)(ws + off); off += 16384;
    unsigned short* xTh  = (unsigned short*)(ws + off); off += 4194304;
    unsigned short* xTl  = (unsigned short*)(ws + off); off += 4194304;
    unsigned short* pfch = (unsigned short*)(ws + off); off += 4194304;
    unsigned short* a12H = (unsigned short*)(ws + off); off += 2097152;
    unsigned short* a12L = (unsigned short*)(ws + off); off += 2097152;

    // d_out scratch timeline:
    //   p0 @0, p1 @8MB, ysum @16MB   (conv stages; dead before iterations)
    //   a3H/L @32MB, 8MB             (stage-3 bna -> feat; dead after)
    //   cn_part @0, 64MB             (iterations: 512 x 32768 f32 partials)
    //   qf @0, 64MB                  (final distcn overwrites everything)
    char* ob = (char*)d_out;
    float* p0   = (float*)ob;
    float* p1   = (float*)(ob + (size_t)8 * 1024 * 1024);
    float* ysum = (float*)(ob + (size_t)16 * 1024 * 1024);
    float* cn_part = (float*)ob;
    float* qf = (float*)ob;
    unsigned short* a3H = (unsigned short*)(ob + (size_t)32 * 1024 * 1024);
    unsigned short* a3L = a3H + (size_t)HW * 32;

    hipMemsetAsync(stats, 0, 192 * sizeof(float), stream);
    wmerge_kernel<<<(49 * 4 * 1024 + 255) / 256, 256, 0, stream>>>(s1k7, s1k5, s1k3, 103, 4, wT1h, wT1l);
    wmerge_kernel<<<(49 * 1 * 1024 + 255) / 256, 256, 0, stream>>>(s2k7, s2k5, s2k3, 32, 1, wT2h, wT2l);
    wmerge_kernel<<<(49 * 2 * 1024 + 255) / 256, 256, 0, stream>>>(s3k7, s3k5, s3k3, 64, 2, wT3h, wT3l);

    transpose_kernel<<<1024, 256, 0, stream>>>(x, xTh, xTl, pfch);

    // stage 1: z splits ci-chunks {0,1} / {2,3}
    convm_kernel<<<dim3(256, 2), 256, 0, stream>>>(xTh, xTl, 128, wT1h, wT1l, 4,
                                                   0, 2, 0, 49, 2, 4, 0, 49, p0);
    reduce2_kernel<<<1024, 256, 0, stream>>>(p0, p1, ysum, stats + 0, stats + 32);
    bnp_kernel<<<1, 32, 0, stream>>>(stats + 0, stats + 32, s1g, s1be, bn + 0, bn + 32);
    bna_kernel<<<1024, 256, 0, stream>>>(ysum, bn + 0, bn + 32, a12H, a12L, 64, 0);

    // stage 2: z splits taps [0,25) / [25,49)
    convm_kernel<<<dim3(256, 2), 256, 0, stream>>>(a12H, a12L, 64, wT2h, wT2l, 1,
                                                   0, 1, 0, 25, 0, 1, 25, 49, p0);
    reduce2_kernel<<<1024, 256, 0, stream>>>(p0, p1, ysum, stats + 64, stats + 96);
    bnp_kernel<<<1, 32, 0, stream>>>(stats + 64, stats + 96, s2g, s2be, bn + 64, bn + 96);
    bna_kernel<<<1024, 256, 0, stream>>>(ysum, bn + 64, bn + 96, a12H, a12L, 64, 32);

    // stage 3: z splits ci-chunks {0} / {1}
    convm_kernel<<<dim3(256, 2), 256, 0, stream>>>(a12H, a12L, 64, wT3h, wT3l, 2,
                                                   0, 1, 0, 49, 1, 2, 0, 49, p0);
    reduce2_kernel<<<1024, 256, 0, stream>>>(p0, p1, ysum, stats + 128, stats + 160);
    bnp_kernel<<<1, 32, 0, stream>>>(stats + 128, stats + 160, s3g, s3be, bn + 128, bn + 160);
    bna_kernel<<<1024, 256, 0, stream>>>(ysum, bn + 128, bn + 160, a3H, a3L, 32, 0);

    feat_kernel<<<256, 256, 0, stream>>>(a12H, a12L, a3H, a3L, outw, outb, xTh, xTl, pfch);
    c0_kernel<<<256, 256, 0, stream>>>(xTh, xTl, cn_fin);
    prep_kernel<<<256, 128, 0, stream>>>(cn_fin, 1, chiT, cloT, 1.f / 256.f, 0);

    for (int it = 0; it < 5; ++it) {
        distcn_kernel<<<512, 256, 0, stream>>>(chiT, cloT, xTh, xTl, pfch, cn_part, qf, 0);
        reduce_cn<<<dim3(128, 8), 256, 0, stream>>>(cn_part, cn_mid);
        prep_kernel<<<256, 128, 0, stream>>>(cn_mid, 8, chiT, cloT, 0.f, 1);
    }
    distcn_kernel<<<512, 256, 0, stream>>>(chiT, cloT, xTh, xTl, pfch, cn_part, qf, 1);
}

// Round 12
// 676.123 us; speedup vs baseline: 2.1400x; 1.0045x over previous
//
#include <hip/hip_runtime.h>

#define HW 65536

typedef short bf16x8 __attribute__((ext_vector_type(8)));
typedef float f32x4 __attribute__((ext_vector_type(4)));
typedef unsigned short u16x8 __attribute__((ext_vector_type(8)));

__device__ inline unsigned short f2bf(float v) {
    unsigned u = __float_as_uint(v);
    unsigned r = (u + 0x7FFF + ((u >> 16) & 1)) >> 16;
    return (unsigned short)r;
}
__device__ inline float ubf(unsigned short h) {
    return __uint_as_float(((unsigned)h) << 16);
}
__device__ inline uint4 pack8(const unsigned short* p) {
    uint4 u;
    u.x = (unsigned)p[0] | ((unsigned)p[1] << 16);
    u.y = (unsigned)p[2] | ((unsigned)p[3] << 16);
    u.z = (unsigned)p[4] | ((unsigned)p[5] << 16);
    u.w = (unsigned)p[6] | ((unsigned)p[7] << 16);
    return u;
}

// ---------------------------------------------------------------------------
// Merge 7/5/3 kernels into one 7x7; emit bf16 hi/lo in A-FRAGMENT LANE ORDER.
// ---------------------------------------------------------------------------
__global__ void wmerge_kernel(const float* __restrict__ k7, const float* __restrict__ k5,
                              const float* __restrict__ k3, int Cin, int nch,
                              unsigned short* __restrict__ wTh, unsigned short* __restrict__ wTl)
{
    int idx = blockIdx.x * 256 + threadIdx.x;
    int total = 49 * nch * 1024;
    if (idx >= total) return;
    int e = idx & 7;
    int lane = (idx >> 3) & 63;
    int octile = (idx >> 9) & 1;
    int chunk = (idx >> 10) % nch;
    int tap = idx / (nch << 10);
    int oc = octile * 16 + (lane & 15);
    int ci = chunk * 32 + (lane >> 4) * 8 + e;
    int ky = tap / 7, kx = tap % 7;
    float v = 0.f;
    if (ci < Cin) {
        v = k7[(oc * Cin + ci) * 49 + tap];
        if (ky >= 1 && ky <= 5 && kx >= 1 && kx <= 5)
            v += k5[(oc * Cin + ci) * 25 + (ky - 1) * 5 + (kx - 1)];
        if (ky >= 2 && ky <= 4 && kx >= 2 && kx <= 4)
            v += k3[(oc * Cin + ci) * 9 + (ky - 2) * 3 + (kx - 2)];
    }
    unsigned short h = f2bf(v);
    wTh[idx] = h;
    wTl[idx] = f2bf(v - ubf(h));
}

// ---------------------------------------------------------------------------
// x [103][HW] fp32 -> xT [n][128] bf16 hi/lo and pfch [c][HW] bf16 hi
// ---------------------------------------------------------------------------
__global__ __launch_bounds__(256) void transpose_kernel(
    const float* __restrict__ x,
    unsigned short* __restrict__ xTh, unsigned short* __restrict__ xTl,
    unsigned short* __restrict__ pfch)
{
    __shared__ float buf[64 * 105];
    int t = threadIdx.x;
    int px0 = blockIdx.x * 64;
    for (int i = t; i < 103 * 64; i += 256) {
        int c = i >> 6, lane = i & 63;
        float v = x[(size_t)c * HW + px0 + lane];
        buf[lane * 105 + c] = v;
        pfch[(size_t)c * HW + px0 + lane] = f2bf(v);
    }
    __syncthreads();
    int px = t >> 2, seg = t & 3;
    unsigned short h[32], l[32];
#pragma unroll
    for (int j = 0; j < 32; ++j) {
        int c = seg * 32 + j;
        float v = (c < 103) ? buf[px * 105 + c] : 0.f;
        h[j] = f2bf(v);
        l[j] = f2bf(v - ubf(h[j]));
    }
    size_t base = (size_t)(px0 + px) * 128 + seg * 32;
#pragma unroll
    for (int k = 0; k < 4; ++k) {
        *(uint4*)(xTh + base + k * 8) = pack8(h + k * 8);
        *(uint4*)(xTl + base + k * 8) = pack8(l + k * 8);
    }
}

// ---------------------------------------------------------------------------
// Implicit-GEMM 7x7 conv, MFMA 16x16x32 bf16, 3-phase hi/lo.
// 4 rows per wave (16-row block tile). Weights in LDS 3-tap ring.
// Grid (256, 2) with z-split work ranges. XCD-aware tile swizzle (T1):
// each XCD gets 32 contiguous tiles (2 by-rows) -> halo reuse in its L2.
// ---------------------------------------------------------------------------
__global__ __launch_bounds__(256) void convm_kernel(
    const unsigned short* __restrict__ actH, const unsigned short* __restrict__ actL,
    int Cs,
    const unsigned short* __restrict__ wTh, const unsigned short* __restrict__ wTl,
    int nchw,
    int c0a, int c1a, int t0a, int t1a,
    int c0b, int c1b, int t0b, int t1b,
    float* __restrict__ ypart)
{
    __shared__ __align__(16) unsigned short sH[22 * 704];
    __shared__ __align__(16) unsigned short sL[22 * 704];
    __shared__ __align__(16) unsigned short sW[3 * 2048];
    int t = threadIdx.x;
    int w = t >> 6, l = t & 63;
    int lc = l & 15, lg = l >> 4;
    int bid = blockIdx.x;
    int swz = (bid & 7) * 32 + (bid >> 3);   // bijective: 256 = 8 XCDs x 32
    int bx = swz & 15, byy = swz >> 4;
    int x0 = bx * 16, y0 = byy * 16;
    int z = blockIdx.y;
    int ch0 = z ? c0b : c0a, ch1 = z ? c1b : c1a;
    int tap0 = z ? t0b : t0a, tap1 = z ? t1b : t1a;
    float* yp = ypart + (size_t)z * 32 * HW;

    f32x4 a_hh[2][4], a_lh[2][4], a_hl[2][4];   // [oc-tile][row]
#pragma unroll
    for (int ot = 0; ot < 2; ++ot)
#pragma unroll
        for (int rr = 0; rr < 4; ++rr)
#pragma unroll
            for (int r = 0; r < 4; ++r) {
                a_hh[ot][rr][r] = 0.f; a_lh[ot][rr][r] = 0.f; a_hl[ot][rr][r] = 0.f;
            }

    for (int ch = ch0; ch < ch1; ++ch) {
        int ci0 = ch * 32;
        __syncthreads();                // protect sH/sL from prior reads
        for (int i = t; i < 2 * 22 * 88; i += 256) {
            int pl = (i >= 22 * 88) ? 1 : 0;
            int j = pl ? i - 22 * 88 : i;
            int row = j / 88;
            int rem = j - row * 88;
            int px = rem >> 2, q = rem & 3;
            int gy = y0 - 3 + row, gx = x0 - 3 + px;
            uint4 v = {0u, 0u, 0u, 0u};
            if (gy >= 0 && gy < 256 && gx >= 0 && gx < 256) {
                const unsigned short* src = pl ? actL : actH;
                v = *(const uint4*)(src + (size_t)(gy * 256 + gx) * Cs + ci0 + q * 8);
            }
            unsigned short* dst = pl ? sL : sH;
            *(uint4*)(dst + row * 704 + q * 176 + px * 8) = v;
        }

        for (int g = tap0; g < tap1; g += 3) {
            int ge = g + 3; if (ge > tap1) ge = tap1;
            if (g > tap0) __syncthreads();      // protect sW from prior group reads
            for (int i = t; i < (ge - g) * 256; i += 256) {
                int tp = i >> 8, r = i & 255;
                const unsigned short* src = (r < 128) ? wTh : wTl;
                *(uint4*)(sW + tp * 2048 + r * 8) =
                    *(const uint4*)(src + ((size_t)((g + tp) * nchw + ch)) * 1024 + (r & 127) * 8);
            }
            __syncthreads();

            for (int tap = g; tap < ge; ++tap) {
                const unsigned short* wb = sW + (tap - g) * 2048 + l * 8;
                bf16x8 ah0 = *(const bf16x8*)(wb);
                bf16x8 ah1 = *(const bf16x8*)(wb + 512);
                bf16x8 al0 = *(const bf16x8*)(wb + 1024);
                bf16x8 al1 = *(const bf16x8*)(wb + 1536);
                int ky = tap / 7;
                int kx = tap - ky * 7;
#pragma unroll
                for (int rr = 0; rr < 4; ++rr) {
                    int off = (w * 4 + rr + ky) * 704 + lg * 176 + (lc + kx) * 8;
                    bf16x8 xh = *(const bf16x8*)(sH + off);
                    bf16x8 xl = *(const bf16x8*)(sL + off);
                    a_hh[0][rr] = __builtin_amdgcn_mfma_f32_16x16x32_bf16(ah0, xh, a_hh[0][rr], 0, 0, 0);
                    a_hh[1][rr] = __builtin_amdgcn_mfma_f32_16x16x32_bf16(ah1, xh, a_hh[1][rr], 0, 0, 0);
                    a_lh[0][rr] = __builtin_amdgcn_mfma_f32_16x16x32_bf16(al0, xh, a_lh[0][rr], 0, 0, 0);
                    a_lh[1][rr] = __builtin_amdgcn_mfma_f32_16x16x32_bf16(al1, xh, a_lh[1][rr], 0, 0, 0);
                    a_hl[0][rr] = __builtin_amdgcn_mfma_f32_16x16x32_bf16(ah0, xl, a_hl[0][rr], 0, 0, 0);
                    a_hl[1][rr] = __builtin_amdgcn_mfma_f32_16x16x32_bf16(ah1, xl, a_hl[1][rr], 0, 0, 0);
                }
            }
        }
    }

#pragma unroll
    for (int ot = 0; ot < 2; ++ot)
#pragma unroll
        for (int rr = 0; rr < 4; ++rr) {
            int n = (y0 + w * 4 + rr) * 256 + x0 + lc;
#pragma unroll
            for (int r = 0; r < 4; ++r) {
                int oc = ot * 16 + lg * 4 + r;
                yp[(size_t)oc * HW + n] = a_hh[ot][rr][r] + a_lh[ot][rr][r] + a_hl[ot][rr][r];
            }
        }
}

// ---------------------------------------------------------------------------
// Sum 2 partial planes -> ysum, with fused per-channel sum/sumsq stats.
// ---------------------------------------------------------------------------
__global__ __launch_bounds__(256) void reduce2_kernel(
    const float* __restrict__ p0, const float* __restrict__ p1,
    float* __restrict__ y, float* __restrict__ ssum, float* __restrict__ ssq)
{
    int c = blockIdx.x >> 5, seg = blockIdx.x & 31;
    int base = c * HW + seg * 2048 + threadIdx.x * 8;
    float s = 0.f, q = 0.f;
#pragma unroll
    for (int h = 0; h < 2; ++h) {
        int o = base + h * 4;
        float4 a0 = *(const float4*)&p0[o];
        float4 a1 = *(const float4*)&p1[o];
        float4 v;
        v.x = a0.x + a1.x; v.y = a0.y + a1.y;
        v.z = a0.z + a1.z; v.w = a0.w + a1.w;
        *(float4*)&y[o] = v;
        s += v.x + v.y + v.z + v.w;
        q = fmaf(v.x, v.x, q); q = fmaf(v.y, v.y, q);
        q = fmaf(v.z, v.z, q); q = fmaf(v.w, v.w, q);
    }
#pragma unroll
    for (int d = 32; d >= 1; d >>= 1) {
        s += __shfl_down(s, d);
        q += __shfl_down(q, d);
    }
    __shared__ float ls[4], lq[4];
    int w = threadIdx.x >> 6;
    if ((threadIdx.x & 63) == 0) { ls[w] = s; lq[w] = q; }
    __syncthreads();
    if (threadIdx.x == 0) {
        atomicAdd(&ssum[c], ls[0] + ls[1] + ls[2] + ls[3]);
        atomicAdd(&ssq[c], lq[0] + lq[1] + lq[2] + lq[3]);
    }
}

__global__ void bnp_kernel(const float* __restrict__ ssum, const float* __restrict__ ssq,
                           const float* __restrict__ g, const float* __restrict__ beta,
                           float* __restrict__ scl, float* __restrict__ shf)
{
    int c = threadIdx.x;
    float mu  = ssum[c] * (1.f / 65536.f);
    float var = ssq[c] * (1.f / 65536.f) - mu * mu;
    float s = g[c] * rsqrtf(var + 1e-5f);
    scl[c] = s;
    shf[c] = beta[c] - mu * s;
}

// ---------------------------------------------------------------------------
// BN + ReLU + write channel-last bf16 hi/lo
// ---------------------------------------------------------------------------
__global__ __launch_bounds__(256) void bna_kernel(
    const float* __restrict__ yraw, const float* __restrict__ scl, const float* __restrict__ shf,
    unsigned short* __restrict__ aH, unsigned short* __restrict__ aL, int Cs, int slot0)
{
    int t = threadIdx.x;
    int lane = t & 63, cg = t >> 6;
    int px = blockIdx.x * 64 + lane;
    unsigned short h[8], l[8];
#pragma unroll
    for (int j = 0; j < 8; ++j) {
        int c = cg * 8 + j;
        float v = fmaxf(yraw[(size_t)c * HW + px] * scl[c] + shf[c], 0.f);
        h[j] = f2bf(v);
        l[j] = f2bf(v - ubf(h[j]));
    }
    *(uint4*)(aH + (size_t)px * Cs + slot0 + cg * 8) = pack8(h);
    *(uint4*)(aL + (size_t)px * Cs + slot0 + cg * 8) = pack8(l);
}

// ---------------------------------------------------------------------------
// 1x1 conv (96->15) + ReLU; writes pf slots 103..127 of xT and pfch rows
// ---------------------------------------------------------------------------
__global__ __launch_bounds__(256) void feat_kernel(
    const unsigned short* __restrict__ a12H, const unsigned short* __restrict__ a12L,
    const unsigned short* __restrict__ a3H, const unsigned short* __restrict__ a3L,
    const float* __restrict__ w, const float* __restrict__ b,
    unsigned short* __restrict__ xTh, unsigned short* __restrict__ xTl,
    unsigned short* __restrict__ pfch)
{
    int n = blockIdx.x * 256 + threadIdx.x;
    float facc[15];
#pragma unroll
    for (int oc = 0; oc < 15; ++oc) facc[oc] = b[oc];

#pragma unroll
    for (int k = 0; k < 12; ++k) {
        uint4 uh, ul;
        if (k < 8) {
            uh = *(const uint4*)(a12H + (size_t)n * 64 + k * 8);
            ul = *(const uint4*)(a12L + (size_t)n * 64 + k * 8);
        } else {
            uh = *(const uint4*)(a3H + (size_t)n * 32 + (k - 8) * 8);
            ul = *(const uint4*)(a3L + (size_t)n * 32 + (k - 8) * 8);
        }
        unsigned hw_[4] = {uh.x, uh.y, uh.z, uh.w};
        unsigned lw_[4] = {ul.x, ul.y, ul.z, ul.w};
#pragma unroll
        for (int j = 0; j < 8; ++j) {
            unsigned short hh = (unsigned short)(hw_[j >> 1] >> ((j & 1) * 16));
            unsigned short ll = (unsigned short)(lw_[j >> 1] >> ((j & 1) * 16));
            float av = ubf(hh) + ubf(ll);
#pragma unroll
            for (int oc = 0; oc < 15; ++oc)
                facc[oc] = fmaf(av, w[oc * 96 + k * 8 + j], facc[oc]);
        }
    }
    unsigned short fh[16], fl[16];
#pragma unroll
    for (int oc = 0; oc < 15; ++oc) {
        float v = fmaxf(facc[oc], 0.f);
        fh[oc] = f2bf(v);
        fl[oc] = f2bf(v - ubf(fh[oc]));
    }
    fh[15] = 0; fl[15] = 0;

    size_t base = (size_t)n * 128;
    uint4 h0 = *(const uint4*)(xTh + base + 96);
    uint4 l0 = *(const uint4*)(xTl + base + 96);
    h0.w = (h0.w & 0xFFFFu) | ((unsigned)fh[0] << 16);
    l0.w = (l0.w & 0xFFFFu) | ((unsigned)fl[0] << 16);
    *(uint4*)(xTh + base + 96) = h0;
    *(uint4*)(xTl + base + 96) = l0;
    *(uint4*)(xTh + base + 104) = pack8(fh + 1);
    *(uint4*)(xTl + base + 104) = pack8(fl + 1);
    unsigned short t2h[8], t2l[8];
#pragma unroll
    for (int j = 0; j < 8; ++j) {
        t2h[j] = (j < 6) ? fh[9 + j] : (unsigned short)0;
        t2l[j] = (j < 6) ? fl[9 + j] : (unsigned short)0;
    }
    *(uint4*)(xTh + base + 112) = pack8(t2h);
    *(uint4*)(xTl + base + 112) = pack8(t2l);
    unsigned short t3h[8] = {0, 0, 0, 0, 0, 0, 0, 0x3F80};
    unsigned short t3l[8] = {0, 0, 0, 0, 0, 0, 0, 0};
    *(uint4*)(xTh + base + 120) = pack8(t3h);
    *(uint4*)(xTl + base + 120) = pack8(t3l);

#pragma unroll
    for (int k2 = 0; k2 < 15; ++k2)
        pfch[(size_t)(103 + k2) * HW + n] = fh[k2];
    pfch[(size_t)118 * HW + n] = 0x3F80;
#pragma unroll
    for (int c = 119; c < 128; ++c)
        pfch[(size_t)c * HW + n] = 0;
}

// ---------------------------------------------------------------------------
// c0: per-superpixel channel sums -> cn_fin[s][128]
// ---------------------------------------------------------------------------
__global__ __launch_bounds__(256) void c0_kernel(
    const unsigned short* __restrict__ pfTh, const unsigned short* __restrict__ pfTl,
    float* __restrict__ cn_fin)
{
    int s = blockIdx.x;
    int sy = s >> 4, sx = s & 15;
    int t = threadIdx.x;
    int xx = t >> 4;
    int cs = (t & 15) * 8;

    float acc[8];
#pragma unroll
    for (int j = 0; j < 8; ++j) acc[j] = 0.f;

    for (int yy = 0; yy < 16; ++yy) {
        int n = (sy * 16 + yy) * 256 + sx * 16 + xx;
        u16x8 h = *(const u16x8*)(pfTh + (size_t)n * 128 + cs);
        u16x8 l = *(const u16x8*)(pfTl + (size_t)n * 128 + cs);
#pragma unroll
        for (int j = 0; j < 8; ++j)
            acc[j] += ubf(h[j]) + ubf(l[j]);
    }
#pragma unroll
    for (int j = 0; j < 8; ++j) {
        acc[j] += __shfl_xor(acc[j], 16);
        acc[j] += __shfl_xor(acc[j], 32);
    }
    __shared__ float red[4][128];
    int w = t >> 6;
    if ((t & 63) < 16) {
#pragma unroll
        for (int j = 0; j < 8; ++j)
            red[w][(t & 15) * 8 + j] = acc[j];
    }
    __syncthreads();
    if (t < 128)
        cn_fin[s * 128 + t] = red[0][t] + red[1][t] + red[2][t] + red[3][t];
}

// ---------------------------------------------------------------------------
// reduce_cn: cn_part [512][32768] -> cn_mid [8][32768]
// ---------------------------------------------------------------------------
__global__ __launch_bounds__(256) void reduce_cn(
    const float* __restrict__ cn_part, float* __restrict__ cn_mid)
{
    int o = blockIdx.x * 256 + threadIdx.x;
    int k0 = blockIdx.y * 64;
    float a = 0.f;
    for (int k = k0; k < k0 + 64; ++k)
        a += cn_part[(size_t)k * 32768 + o];
    cn_mid[(size_t)blockIdx.y * 32768 + o] = a;
}

// ---------------------------------------------------------------------------
// prep: centroids -> chiT/cloT [s][128]; slot 127 = -0.5*|c|^2.
// src has nmid stacked [32768] planes to be summed.
// ---------------------------------------------------------------------------
__global__ __launch_bounds__(128) void prep_kernel(
    const float* __restrict__ src, int nmid,
    unsigned short* __restrict__ chiT, unsigned short* __restrict__ cloT,
    float scale0, int use_qsum)
{
    int s = blockIdx.x, c = threadIdx.x;
    float v = 0.f, q118 = 0.f;
    for (int m = 0; m < nmid; ++m) {
        v += src[(size_t)m * 32768 + s * 128 + c];
        q118 += src[(size_t)m * 32768 + s * 128 + 118];
    }
    float inv = use_qsum ? 1.f / (q118 + 1e-8f) : scale0;
    v = (c < 118) ? v * inv : 0.f;
    float a = v * v;
#pragma unroll
    for (int d = 1; d < 64; d <<= 1) a += __shfl_xor(a, d);
    __shared__ float red[2];
    if ((c & 63) == 0) red[c >> 6] = a;
    __syncthreads();
    float tot = red[0] + red[1];
    unsigned short h, lo;
    if (c == 127) {
        float m2 = -0.5f * tot;
        h = f2bf(m2);
        lo = f2bf(m2 - ubf(h));
    } else {
        h = f2bf(v);
        lo = f2bf(v - ubf(h));
    }
    chiT[s * 128 + c] = h;
    cloT[s * 128 + c] = lo;
}

// ---------------------------------------------------------------------------
// FUSED dist+cn, 32 KB LDS (3 blocks/CU target).
// Phase 1: centroid staging in 4 rounds of 64 s-rows (both planes, 32 KB,
// XOR-swizzled); B fragments preloaded once.
// Phase 2/3: split into two s-halves so the Q buffer is 32 KB: write
// sQ-half -> phase-3 GEMM for those 8 s-tiles (a2[8][2] reuses freed acc
// regs) -> plain stores to cn_part[block]; repeat for the other half.
// final_mode: write fp32 Q to qf, skip phases 2/3.
// Block 256 thr = 4 waves = 128 px. Grid 512.
// ---------------------------------------------------------------------------
__global__ __launch_bounds__(256) void distcn_kernel(
    const unsigned short* __restrict__ chiT, const unsigned short* __restrict__ cloT,
    const unsigned short* __restrict__ pfTh, const unsigned short* __restrict__ pfTl,
    const unsigned short* __restrict__ pfch,
    float* __restrict__ cn_part, float* __restrict__ qf, int final_mode)
{
    __shared__ __align__(16) unsigned short sA[16384];  // 32 KB: A-stage / sQ-half
    unsigned short* sQ = sA;
    int t = threadIdx.x;
    int w = t >> 6, l = t & 63;
    int lc = l & 15, lg = l >> 4;
    int nblk = blockIdx.x * 128;
    int n0 = nblk + w * 32;

    // preload all B fragments (each xT element read exactly once)
    bf16x8 bh[4][2], bl[4][2];
#pragma unroll
    for (int ks = 0; ks < 4; ++ks) {
        int kb = ks * 32 + 8 * lg;
        bh[ks][0] = *(const bf16x8*)(pfTh + (size_t)(n0 + lc) * 128 + kb);
        bh[ks][1] = *(const bf16x8*)(pfTh + (size_t)(n0 + 16 + lc) * 128 + kb);
        bl[ks][0] = *(const bf16x8*)(pfTl + (size_t)(n0 + lc) * 128 + kb);
        bl[ks][1] = *(const bf16x8*)(pfTl + (size_t)(n0 + 16 + lc) * 128 + kb);
    }

    f32x4 acc[16][2];
#pragma unroll
    for (int i = 0; i < 16; ++i)
#pragma unroll
        for (int g = 0; g < 2; ++g)
#pragma unroll
            for (int j = 0; j < 4; ++j) acc[i][g][j] = 0.f;

#pragma unroll
    for (int ro = 0; ro < 4; ++ro) {
        __syncthreads();
        // stage s-rows [ro*64, ro*64+64): plane0 = chiT, plane1 = cloT (16 KB each)
        for (int i = t; i < 2048; i += 256) {
            int plane = i >> 10;
            int ii = i & 1023;
            int sl = ii >> 4;           // s_loc 0..63
            int j = ii & 15;            // 16B chunk within row
            const unsigned short* src = plane ? cloT : chiT;
            uint4 v = *(const uint4*)(src + (((size_t)(ro * 64 + sl)) << 7) + j * 8);
            int ds = ((sl << 7) + j * 8) ^ ((sl & 7) << 3);
            *(uint4*)(sA + plane * 8192 + ds) = v;
        }
        __syncthreads();

#pragma unroll
        for (int s4 = 0; s4 < 4; ++s4) {
            const int st = ro * 4 + s4;
#pragma unroll
            for (int ks = 0; ks < 4; ++ks) {
                int e0 = (((s4 * 16 + lc) << 7) + ks * 32 + lg * 8) ^ ((lc & 7) << 3);
                bf16x8 ah = *(const bf16x8*)(sA + e0);
                bf16x8 al = *(const bf16x8*)(sA + 8192 + e0);
                acc[st][0] = __builtin_amdgcn_mfma_f32_16x16x32_bf16(ah, bh[ks][0], acc[st][0], 0, 0, 0);
                acc[st][0] = __builtin_amdgcn_mfma_f32_16x16x32_bf16(al, bh[ks][0], acc[st][0], 0, 0, 0);
                acc[st][0] = __builtin_amdgcn_mfma_f32_16x16x32_bf16(ah, bl[ks][0], acc[st][0], 0, 0, 0);
                acc[st][1] = __builtin_amdgcn_mfma_f32_16x16x32_bf16(ah, bh[ks][1], acc[st][1], 0, 0, 0);
                acc[st][1] = __builtin_amdgcn_mfma_f32_16x16x32_bf16(al, bh[ks][1], acc[st][1], 0, 0, 0);
                acc[st][1] = __builtin_amdgcn_mfma_f32_16x16x32_bf16(ah, bl[ks][1], acc[st][1], 0, 0, 0);
            }
        }
    }

    float m0 = -1e30f, m1 = -1e30f;
#pragma unroll
    for (int st = 0; st < 16; ++st)
#pragma unroll
        for (int r = 0; r < 4; ++r) {
            m0 = fmaxf(m0, acc[st][0][r]);
            m1 = fmaxf(m1, acc[st][1][r]);
        }
    m0 = fmaxf(m0, __shfl_xor(m0, 16)); m0 = fmaxf(m0, __shfl_xor(m0, 32));
    m1 = fmaxf(m1, __shfl_xor(m1, 16)); m1 = fmaxf(m1, __shfl_xor(m1, 32));

    float s0 = 0.f, s1 = 0.f;
#pragma unroll
    for (int st = 0; st < 16; ++st)
#pragma unroll
        for (int r = 0; r < 4; ++r) {
            float e0 = __expf(2.f * (acc[st][0][r] - m0));
            float e1 = __expf(2.f * (acc[st][1][r] - m1));
            acc[st][0][r] = e0; acc[st][1][r] = e1;
            s0 += e0; s1 += e1;
        }
    s0 += __shfl_xor(s0, 16); s0 += __shfl_xor(s0, 32);
    s1 += __shfl_xor(s1, 16); s1 += __shfl_xor(s1, 32);
    float i0 = 1.f / s0, i1 = 1.f / s1;

    if (final_mode) {
        int nA = n0 + lc, nB = n0 + 16 + lc;
#pragma unroll
        for (int st = 0; st < 16; ++st)
#pragma unroll
            for (int r = 0; r < 4; ++r) {
                int s = st * 16 + lg * 4 + r;
                qf[(size_t)s * HW + nA] = acc[st][0][r] * i0;
                qf[(size_t)s * HW + nB] = acc[st][1][r] * i1;
            }
        return;
    }

    // phases 2/3 in two s-halves (sQ-half = 128 s x 128 px bf16 = 32 KB)
#pragma unroll
    for (int h = 0; h < 2; ++h) {
        __syncthreads();    // previous sA contents (stage or sQ-half) dead
#pragma unroll
        for (int st8 = 0; st8 < 8; ++st8) {
            const int st = h * 8 + st8;
#pragma unroll
            for (int g = 0; g < 2; ++g) {
                float iv = g ? i1 : i0;
#pragma unroll
                for (int r = 0; r < 4; ++r) {
                    int idx = ((st8 * 4 + w) * 64 + (g * 2 + (lc >> 3)) * 16 + lg * 4 + r) * 8 + (lc & 7);
                    sQ[idx] = f2bf(acc[st][g][r] * iv);
                }
            }
        }
        __syncthreads();

        // phase 3 for this half: wave w covers c in [w*32, w*32+32)
        f32x4 a2[8][2];
#pragma unroll
        for (int i = 0; i < 8; ++i)
#pragma unroll
            for (int ct = 0; ct < 2; ++ct)
#pragma unroll
                for (int j = 0; j < 4; ++j) a2[i][ct][j] = 0.f;

#pragma unroll
        for (int kc = 0; kc < 4; ++kc) {
            int nb = nblk + kc * 32 + 8 * lg;
            bf16x8 b0 = *(const bf16x8*)(pfch + (size_t)(w * 32 + lc) * HW + nb);
            bf16x8 b1 = *(const bf16x8*)(pfch + (size_t)(w * 32 + 16 + lc) * HW + nb);
#pragma unroll
            for (int st8 = 0; st8 < 8; ++st8) {
                bf16x8 afr = *(const bf16x8*)(sQ + ((size_t)(st8 * 4 + kc) * 64 + l) * 8);
                a2[st8][0] = __builtin_amdgcn_mfma_f32_16x16x32_bf16(afr, b0, a2[st8][0], 0, 0, 0);
                a2[st8][1] = __builtin_amdgcn_mfma_f32_16x16x32_bf16(afr, b1, a2[st8][1], 0, 0, 0);
            }
        }

        float* out = cn_part + (size_t)blockIdx.x * 32768;
#pragma unroll
        for (int st8 = 0; st8 < 8; ++st8)
#pragma unroll
            for (int ct = 0; ct < 2; ++ct)
#pragma unroll
                for (int r = 0; r < 4; ++r) {
                    int s = (h * 8 + st8) * 16 + lg * 4 + r;
                    int c = w * 32 + ct * 16 + lc;
                    out[s * 128 + c] = a2[st8][ct][r];
                }
    }
}

// ---------------------------------------------------------------------------
extern "C" void kernel_launch(void* const* d_in, const int* in_sizes, int n_in,
                              void* d_out, int out_size, void* d_ws, size_t ws_size,
                              hipStream_t stream)
{
    const float* x     = (const float*)d_in[0];
    const float* s1k7  = (const float*)d_in[1];
    const float* s1k5  = (const float*)d_in[2];
    const float* s1k3  = (const float*)d_in[3];
    const float* s1g   = (const float*)d_in[5];
    const float* s1be  = (const float*)d_in[6];
    const float* s2k7  = (const float*)d_in[7];
    const float* s2k5  = (const float*)d_in[8];
    const float* s2k3  = (const float*)d_in[9];
    const float* s2g   = (const float*)d_in[11];
    const float* s2be  = (const float*)d_in[12];
    const float* s3k7  = (const float*)d_in[13];
    const float* s3k5  = (const float*)d_in[14];
    const float* s3k3  = (const float*)d_in[15];
    const float* s3g   = (const float*)d_in[17];
    const float* s3be  = (const float*)d_in[18];
    const float* outw  = (const float*)d_in[19];
    const float* outb  = (const float*)d_in[20];

    float* ws = (float*)d_ws;
    size_t off = 0;
    unsigned short* wT1h = (unsigned short*)(ws + off); off += 100352;
    unsigned short* wT1l = (unsigned short*)(ws + off); off += 100352;
    unsigned short* wT2h = (unsigned short*)(ws + off); off += 25088;
    unsigned short* wT2l = (unsigned short*)(ws + off); off += 25088;
    unsigned short* wT3h = (unsigned short*)(ws + off); off += 50176;
    unsigned short* wT3l = (unsigned short*)(ws + off); off += 50176;
    float* stats = ws + off; off += 192;
    float* bn    = ws + off; off += 192;
    float* cn_fin= ws + off; off += 32768;
    float* cn_mid= ws + off; off += 262144;   // 8 x 32768
    unsigned short* chiT = (unsigned short*)(ws + off); off += 16384;
    unsigned short* cloT = (unsigned short*)(ws + off); off += 16384;
    unsigned short* xTh  = (unsigned short*)(ws + off); off += 4194304;
    unsigned short* xTl  = (unsigned short*)(ws + off); off += 4194304;
    unsigned short* pfch = (unsigned short*)(ws + off); off += 4194304;
    unsigned short* a12H = (unsigned short*)(ws + off); off += 2097152;
    unsigned short* a12L = (unsigned short*)(ws + off); off += 2097152;

    // d_out scratch timeline:
    //   p0 @0, p1 @8MB, ysum @16MB   (conv stages; dead before iterations)
    //   a3H/L @32MB, 8MB             (stage-3 bna -> feat; dead after)
    //   cn_part @0, 64MB             (iterations: 512 x 32768 f32 partials)
    //   qf @0, 64MB                  (final distcn overwrites everything)
    char* ob = (char*)d_out;
    float* p0   = (float*)ob;
    float* p1   = (float*)(ob + (size_t)8 * 1024 * 1024);
    float* ysum = (float*)(ob + (size_t)16 * 1024 * 1024);
    float* cn_part = (float*)ob;
    float* qf = (float*)ob;
    unsigned short* a3H = (unsigned short*)(ob + (size_t)32 * 1024 * 1024);
    unsigned short* a3L = a3H + (size_t)HW * 32;

    hipMemsetAsync(stats, 0, 192 * sizeof(float), stream);
    wmerge_kernel<<<(49 * 4 * 1024 + 255) / 256, 256, 0, stream>>>(s1k7, s1k5, s1k3, 103, 4, wT1h, wT1l);
    wmerge_kernel<<<(49 * 1 * 1024 + 255) / 256, 256, 0, stream>>>(s2k7, s2k5, s2k3, 32, 1, wT2h, wT2l);
    wmerge_kernel<<<(49 * 2 * 1024 + 255) / 256, 256, 0, stream>>>(s3k7, s3k5, s3k3, 64, 2, wT3h, wT3l);

    transpose_kernel<<<1024, 256, 0, stream>>>(x, xTh, xTl, pfch);

    // stage 1: z splits ci-chunks {0,1} / {2,3}
    convm_kernel<<<dim3(256, 2), 256, 0, stream>>>(xTh, xTl, 128, wT1h, wT1l, 4,
                                                   0, 2, 0, 49, 2, 4, 0, 49, p0);
    reduce2_kernel<<<1024, 256, 0, stream>>>(p0, p1, ysum, stats + 0, stats + 32);
    bnp_kernel<<<1, 32, 0, stream>>>(stats + 0, stats + 32, s1g, s1be, bn + 0, bn + 32);
    bna_kernel<<<1024, 256, 0, stream>>>(ysum, bn + 0, bn + 32, a12H, a12L, 64, 0);

    // stage 2: z splits taps [0,25) / [25,49)
    convm_kernel<<<dim3(256, 2), 256, 0, stream>>>(a12H, a12L, 64, wT2h, wT2l, 1,
                                                   0, 1, 0, 25, 0, 1, 25, 49, p0);
    reduce2_kernel<<<1024, 256, 0, stream>>>(p0, p1, ysum, stats + 64, stats + 96);
    bnp_kernel<<<1, 32, 0, stream>>>(stats + 64, stats + 96, s2g, s2be, bn + 64, bn + 96);
    bna_kernel<<<1024, 256, 0, stream>>>(ysum, bn + 64, bn + 96, a12H, a12L, 64, 32);

    // stage 3: z splits ci-chunks {0} / {1}
    convm_kernel<<<dim3(256, 2), 256, 0, stream>>>(a12H, a12L, 64, wT3h, wT3l, 2,
                                                   0, 1, 0, 49, 1, 2, 0, 49, p0);
    reduce2_kernel<<<1024, 256, 0, stream>>>(p0, p1, ysum, stats + 128, stats + 160);
    bnp_kernel<<<1, 32, 0, stream>>>(stats + 128, stats + 160, s3g, s3be, bn + 128, bn + 160);
    bna_kernel<<<1024, 256, 0, stream>>>(ysum, bn + 128, bn + 160, a3H, a3L, 32, 0);

    feat_kernel<<<256, 256, 0, stream>>>(a12H, a12L, a3H, a3L, outw, outb, xTh, xTl, pfch);
    c0_kernel<<<256, 256, 0, stream>>>(xTh, xTl, cn_fin);
    prep_kernel<<<256, 128, 0, stream>>>(cn_fin, 1, chiT, cloT, 1.f / 256.f, 0);

    for (int it = 0; it < 5; ++it) {
        distcn_kernel<<<512, 256, 0, stream>>>(chiT, cloT, xTh, xTl, pfch, cn_part, qf, 0);
        reduce_cn<<<dim3(128, 8), 256, 0, stream>>>(cn_part, cn_mid);
        prep_kernel<<<256, 128, 0, stream>>>(cn_mid, 8, chiT, cloT, 0.f, 1);
    }
    distcn_kernel<<<512, 256, 0, stream>>>(chiT, cloT, xTh, xTl, pfch, cn_part, qf, 1);
}